// Round 1
// baseline (3296.263 us; speedup 1.0000x reference)
//
#include <hip/hip_runtime.h>
#include <math.h>

constexpr int BB = 4;       // batch
constexpr int SS = 1000;    // seq len
constexpr int INDIM = 5;
constexpr int EE = 256;     // embed
constexpr int LL = 6;       // layers
constexpr int HH = 8;       // heads
constexpr int DHH = 32;     // head dim
constexpr int NLM = 50;     // landmarks
constexpr int FFD = 1024;   // ff hidden

// ---------------------------------------------------------------------------
// Persistence features: top-50 landmarks -> Laplacian -> f64 Jacobi eigh -> 6 feats
// ---------------------------------------------------------------------------
__global__ __launch_bounds__(256) void ph_kernel(
    const float* __restrict__ seq, const float* __restrict__ ph_fw,
    const float* __restrict__ ph_db, const float* __restrict__ ph_law,
    const float* __restrict__ ph_lab, float* __restrict__ pf)
{
  const int b = blockIdx.x;
  const int tid = threadIdx.x;
  __shared__ float sc[1024];
  __shared__ int   si[1024];
  __shared__ float sm[SS];
  __shared__ float lx[NLM], ly[NLM];
  __shared__ double matA[NLM][NLM];
  __shared__ double matV[NLM][NLM];
  __shared__ double rc[25], rs_[25];
  __shared__ int    rp[25], rq[25];
  __shared__ double red[256];
  __shared__ double evs[NLM];
  __shared__ int    evi[NLM];

  const float law0 = ph_law[0], law1 = ph_law[1], labv = ph_lab[0];
  for (int s = tid; s < 1024; s += 256) {
    if (s < SS) {
      const float* p = seq + ((size_t)b * SS + s) * INDIM;
      float m = (p[0] + p[1] + p[2] + p[3] + p[4]) * 0.2f;
      sm[s] = m;
      sc[s] = (float)s * law0 + m * law1 + labv;
    } else {
      sc[s] = -INFINITY;
    }
    si[s] = s;
  }
  __syncthreads();
  // bitonic sort, descending by score, ties -> ascending index (matches top_k)
  for (int k = 2; k <= 1024; k <<= 1) {
    for (int j = k >> 1; j > 0; j >>= 1) {
      for (int i = tid; i < 1024; i += 256) {
        int ixj = i ^ j;
        if (ixj > i) {
          float va = sc[i], vb = sc[ixj];
          int ia = si[i], ib = si[ixj];
          bool aBefore = (va > vb) || (va == vb && ia < ib);
          bool dirDesc = ((i & k) == 0);
          if (aBefore != dirDesc) { sc[i] = vb; sc[ixj] = va; si[i] = ib; si[ixj] = ia; }
        }
      }
      __syncthreads();
    }
  }
  if (tid < NLM) {
    int id = si[tid];
    lx[tid] = (float)id;
    ly[tid] = sm[id];
  }
  __syncthreads();
  // K matrix in f32 (matches reference arithmetic), Laplacian assembled in f64
  const float fwv = fabsf(ph_fw[0]);
  const float dbv = ph_db[0];
  for (int t = tid; t < NLM * NLM; t += 256) {
    int i = t / NLM, j = t % NLM;
    float dx = lx[i] - lx[j], dy = ly[i] - ly[j];
    float d2 = dx * dx + dy * dy;
    float dist = (d2 > 0.f) ? sqrtf(d2) : 0.f;
    float Kv = expf(-(dist * fwv + dbv));
    matA[i][j] = -(double)Kv;
  }
  __syncthreads();
  if (tid < NLM) {
    double rsum = 0.0;
    for (int j = 0; j < NLM; ++j) rsum -= matA[tid][j];   // = sum_j K_ij in f64
    matA[tid][tid] += rsum;  // diag = rowsum - K_ii; row sums cancel exactly
  }
  for (int t = tid; t < NLM * NLM; t += 256)
    matV[t / NLM][t % NLM] = (t / NLM == t % NLM) ? 1.0 : 0.0;
  __syncthreads();

  // parallel-order cyclic Jacobi (round-robin tournament, 25 disjoint pairs/round)
  for (int sweep = 0; sweep < 14; ++sweep) {
    double acc = 0.0;
    for (int t = tid; t < NLM * NLM; t += 256) {
      int i = t / NLM, j = t % NLM;
      if (i != j) { double v = matA[i][j]; acc += v * v; }
    }
    red[tid] = acc;
    __syncthreads();
    for (int w = 128; w > 0; w >>= 1) { if (tid < w) red[tid] += red[tid + w]; __syncthreads(); }
    double offn = red[0];
    __syncthreads();
    if (offn < 1e-22) break;
    for (int r = 0; r < NLM - 1; ++r) {
      if (tid < 25) {
        int p, q;
        if (tid == 0) { p = NLM - 1; q = r; }
        else {
          p = (r + tid) % (NLM - 1);
          q = (r - tid + (NLM - 1)) % (NLM - 1);
        }
        if (p > q) { int tt = p; p = q; q = tt; }
        rp[tid] = p; rq[tid] = q;
        double app = matA[p][p], aqq = matA[q][q], apq = matA[p][q];
        double c = 1.0, s = 0.0;
        if (fabs(apq) > 1e-300) {
          double tau = (aqq - app) / (2.0 * apq);
          double tth = ((tau >= 0.0) ? 1.0 : -1.0) / (fabs(tau) + sqrt(1.0 + tau * tau));
          c = 1.0 / sqrt(1.0 + tth * tth);
          s = tth * c;
        }
        rc[tid] = c; rs_[tid] = s;
      }
      __syncthreads();
      // row update: B = J^T A (rows of distinct pairs are disjoint)
      for (int t = tid; t < 25 * NLM; t += 256) {
        int kk = t / NLM, j = t % NLM;
        int p = rp[kk], q = rq[kk];
        double c = rc[kk], s = rs_[kk];
        double ap = matA[p][j], aq = matA[q][j];
        matA[p][j] = c * ap - s * aq;
        matA[q][j] = s * ap + c * aq;
      }
      __syncthreads();
      // col update: A = B J ; and eigenvector accumulation V = V J
      for (int t = tid; t < 2 * 25 * NLM; t += 256) {
        int half = t / (25 * NLM);
        int t2 = t % (25 * NLM);
        int kk = t2 / NLM, i = t2 % NLM;
        int p = rp[kk], q = rq[kk];
        double c = rc[kk], s = rs_[kk];
        if (half == 0) {
          double ap = matA[i][p], aq = matA[i][q];
          matA[i][p] = c * ap - s * aq;
          matA[i][q] = s * ap + c * aq;
        } else {
          double vp = matV[i][p], vq = matV[i][q];
          matV[i][p] = c * vp - s * vq;
          matV[i][q] = s * vp + c * vq;
        }
      }
      __syncthreads();
    }
  }

  if (tid < NLM) { evs[tid] = matA[tid][tid]; evi[tid] = tid; }
  __syncthreads();
  // odd-even transposition sort ascending
  for (int ph = 0; ph < NLM; ++ph) {
    if (tid < 25) {
      int i = (ph & 1) + 2 * tid;
      if (i + 1 < NLM && evs[i] > evs[i + 1]) {
        double tv = evs[i]; evs[i] = evs[i + 1]; evs[i + 1] = tv;
        int ti = evi[i]; evi[i] = evi[i + 1]; evi[i + 1] = ti;
      }
    }
    __syncthreads();
  }
  if (tid == 0) {
    double n0 = 0.0, s0 = 0.0;
    for (int i = 0; i < NLM; ++i)
      if (evs[i] < 1e-6) { n0 += 1.0; s0 += fabs(evs[i]); }
    double gap = evs[1] - evs[0];
    int c1 = evi[1];
    double mean = 0.0;
    for (int i = 0; i < NLM; ++i) mean += matV[i][c1];
    mean /= NLM;
    double var = 0.0;
    for (int i = 0; i < NLM; ++i) { double d = matV[i][c1] - mean; var += d * d; }
    var /= (NLM - 1);
    double m4 = (evs[2] + evs[3] + evs[4] + evs[5]) * 0.25;
    double v4 = 0.0;
    for (int i = 2; i < 6; ++i) { double d = evs[i] - m4; v4 += d * d; }
    v4 /= 3.0;
    float* o = pf + b * 6;
    o[0] = (float)n0;
    o[1] = (float)s0;
    o[2] = (float)gap;
    o[3] = (float)sqrt(var);
    o[4] = (float)m4;
    o[5] = (float)sqrt(v4);
  }
}

// ---------------------------------------------------------------------------
// Per-(layer,batch) scalar attention temperature from persistence features
// ---------------------------------------------------------------------------
__global__ __launch_bounds__(256) void temp_kernel(
    const float* __restrict__ pf, const float* __restrict__ w1, const float* __restrict__ b1,
    const float* __restrict__ w2, const float* __restrict__ b2, float* __restrict__ ts)
{
  const int l = blockIdx.x / BB, b = blockIdx.x % BB, tid = threadIdx.x;
  __shared__ float pfl[6];
  __shared__ float h[128];
  __shared__ float red[256];
  if (tid < 6) pfl[tid] = pf[b * 6 + tid];
  __syncthreads();
  if (tid < 128) {
    const float* w = w1 + ((size_t)l * 128 + tid) * 6;
    float a = b1[(size_t)l * 128 + tid];
#pragma unroll
    for (int i = 0; i < 6; ++i) a += w[i] * pfl[i];
    h[tid] = fmaxf(a, 0.f);
  }
  __syncthreads();
  const float* w = w2 + ((size_t)l * EE + tid) * 128;
  float a = b2[(size_t)l * EE + tid];
  for (int i = 0; i < 128; ++i) a += w[i] * h[i];
  float sg = 1.f / (1.f + expf(-a));
  red[tid] = sg; __syncthreads();
  for (int wd = 128; wd > 0; wd >>= 1) { if (tid < wd) red[tid] += red[tid + wd]; __syncthreads(); }
  if (tid == 0) ts[l * BB + b] = red[0] * (1.f / EE);
}

// ---------------------------------------------------------------------------
// Embedding MLP + LN + positional encoding; one row per block
// ---------------------------------------------------------------------------
__global__ __launch_bounds__(256) void embed_kernel(
    const float* __restrict__ seq, const float* __restrict__ w1, const float* __restrict__ b1,
    const float* __restrict__ w2, const float* __restrict__ b2,
    const float* __restrict__ g, const float* __restrict__ be,
    const float* __restrict__ pos, float* __restrict__ X)
{
  const int row = blockIdx.x;
  const int s = row % SS;
  const int tid = threadIdx.x;
  __shared__ float sv[INDIM];
  __shared__ float h[128];
  __shared__ float red[256];
  if (tid < INDIM) sv[tid] = seq[(size_t)row * INDIM + tid];
  __syncthreads();
  if (tid < 128) {
    const float* w = w1 + tid * INDIM;
    float a = b1[tid];
#pragma unroll
    for (int i = 0; i < INDIM; ++i) a += w[i] * sv[i];
    h[tid] = fmaxf(a, 0.f);
  }
  __syncthreads();
  const float* w = w2 + (size_t)tid * 128;
  float a = b2[tid];
  for (int i = 0; i < 128; ++i) a += w[i] * h[i];
  red[tid] = a; __syncthreads();
  for (int wd = 128; wd > 0; wd >>= 1) { if (tid < wd) red[tid] += red[tid + wd]; __syncthreads(); }
  float mean = red[0] * (1.f / EE);
  __syncthreads();
  float d = a - mean;
  red[tid] = d * d; __syncthreads();
  for (int wd = 128; wd > 0; wd >>= 1) { if (tid < wd) red[tid] += red[tid + wd]; __syncthreads(); }
  float var = red[0] * (1.f / EE);
  X[(size_t)row * EE + tid] = d * rsqrtf(var + 1e-5f) * g[tid] + be[tid] + pos[(size_t)s * EE + tid];
}

// ---------------------------------------------------------------------------
// Tiled f32 GEMM: C = A[MxK] @ W[NxK]^T + bias, optional exact GELU epilogue.
// blockIdx.z selects among up to 3 (W,bias,C) triples (QKV fusion).
// ---------------------------------------------------------------------------
template <int ACT>
__global__ __launch_bounds__(256) void gemm3_kernel(
    const float* __restrict__ Ain,
    const float* __restrict__ W0, const float* __restrict__ W1, const float* __restrict__ W2,
    const float* __restrict__ bb0, const float* __restrict__ bb1, const float* __restrict__ bb2,
    float* __restrict__ C0, float* __restrict__ C1, float* __restrict__ C2,
    int M, int N, int K)
{
  const int z = blockIdx.z;
  const float* W = (z == 0) ? W0 : (z == 1) ? W1 : W2;
  const float* bias = (z == 0) ? bb0 : (z == 1) ? bb1 : bb2;
  float* C = (z == 0) ? C0 : (z == 1) ? C1 : C2;
  __shared__ __align__(16) float As[16][68];
  __shared__ __align__(16) float Ws[16][68];
  const int m0 = blockIdx.x * 64, n0 = blockIdx.y * 64;
  const int tid = threadIdx.x;
  const int lr = tid >> 2;
  const int lc = (tid & 3) << 2;
  const int tx = tid & 15, ty = tid >> 4;
  float acc[4][4] = {};
  for (int k0 = 0; k0 < K; k0 += 16) {
    float4 av = make_float4(0.f, 0.f, 0.f, 0.f);
    int am = m0 + lr;
    if (am < M) av = *(const float4*)(Ain + (size_t)am * K + k0 + lc);
    As[lc + 0][lr] = av.x; As[lc + 1][lr] = av.y; As[lc + 2][lr] = av.z; As[lc + 3][lr] = av.w;
    float4 wv = *(const float4*)(W + (size_t)(n0 + lr) * K + k0 + lc);
    Ws[lc + 0][lr] = wv.x; Ws[lc + 1][lr] = wv.y; Ws[lc + 2][lr] = wv.z; Ws[lc + 3][lr] = wv.w;
    __syncthreads();
#pragma unroll
    for (int kk = 0; kk < 16; ++kk) {
      float4 a4 = *(const float4*)(&As[kk][ty << 2]);
      float4 b4 = *(const float4*)(&Ws[kk][tx << 2]);
      acc[0][0] += a4.x * b4.x; acc[0][1] += a4.x * b4.y; acc[0][2] += a4.x * b4.z; acc[0][3] += a4.x * b4.w;
      acc[1][0] += a4.y * b4.x; acc[1][1] += a4.y * b4.y; acc[1][2] += a4.y * b4.z; acc[1][3] += a4.y * b4.w;
      acc[2][0] += a4.z * b4.x; acc[2][1] += a4.z * b4.y; acc[2][2] += a4.z * b4.z; acc[2][3] += a4.z * b4.w;
      acc[3][0] += a4.w * b4.x; acc[3][1] += a4.w * b4.y; acc[3][2] += a4.w * b4.z; acc[3][3] += a4.w * b4.w;
    }
    __syncthreads();
  }
#pragma unroll
  for (int i = 0; i < 4; ++i) {
    int row = m0 + (ty << 2) + i;
    if (row >= M) continue;
#pragma unroll
    for (int j = 0; j < 4; ++j) {
      int col = n0 + (tx << 2) + j;
      float v = acc[i][j] + bias[col];
      if (ACT == 1) v = 0.5f * v * (1.f + erff(v * 0.70710678118654752440f));
      C[(size_t)row * N + col] = v;
    }
  }
}

// ---------------------------------------------------------------------------
// Flash-style attention with per-sample scalar temperature
// grid: (qtile=16, head=8, batch=4); block 256
// ---------------------------------------------------------------------------
__global__ __launch_bounds__(256) void attn_kernel(
    const float* __restrict__ Qm, const float* __restrict__ Km, const float* __restrict__ Vm,
    const float* __restrict__ ts, float* __restrict__ Om, int l)
{
  const int qt = blockIdx.x, h = blockIdx.y, b = blockIdx.z;
  const int tid = threadIdx.x;
  const float scale = ts[l * BB + b] * 0.17677669529663688110f;  // ts / sqrt(32)
  __shared__ float Qs[64][33];
  __shared__ float Ks[64][33];
  __shared__ float Vs[64][33];
  __shared__ float Ps[64][65];
  __shared__ float mrow[64], lrow[64], fac[64];
  const int q0 = qt * 64;
  for (int t = tid; t < 64 * DHH; t += 256) {
    int r = t >> 5, d = t & 31;
    int qrow = q0 + r;
    Qs[r][d] = (qrow < SS) ? Qm[((size_t)(b * SS + qrow)) * EE + h * DHH + d] : 0.f;
  }
  if (tid < 64) { mrow[tid] = -INFINITY; lrow[tid] = 0.f; }
  const int tx = tid & 31, ty = tid >> 5;
  float Oacc[8] = {0.f, 0.f, 0.f, 0.f, 0.f, 0.f, 0.f, 0.f};
  __syncthreads();
  for (int k0 = 0; k0 < SS; k0 += 64) {
    int kn = SS - k0; if (kn > 64) kn = 64;
    for (int t = tid; t < 64 * DHH; t += 256) {
      int r = t >> 5, d = t & 31;
      float kv = 0.f, vv = 0.f;
      if (r < kn) {
        size_t base = ((size_t)(b * SS + k0 + r)) * EE + h * DHH + d;
        kv = Km[base]; vv = Vm[base];
      }
      Ks[r][d] = kv; Vs[r][d] = vv;
    }
    __syncthreads();
    for (int t = tid; t < 64 * 64; t += 256) {
      int r = t >> 6, c = t & 63;
      float a = 0.f;
#pragma unroll
      for (int d = 0; d < DHH; ++d) a += Qs[r][d] * Ks[c][d];
      Ps[r][c] = (c < kn) ? a * scale : -INFINITY;
    }
    __syncthreads();
    if (tid < 64) {
      float mo = mrow[tid];
      float mx = mo;
      for (int c = 0; c < 64; ++c) mx = fmaxf(mx, Ps[tid][c]);
      float f = expf(mo - mx);
      mrow[tid] = mx; fac[tid] = f; lrow[tid] *= f;
    }
    __syncthreads();
    for (int t = tid; t < 64 * 64; t += 256) {
      int r = t >> 6, c = t & 63;
      Ps[r][c] = expf(Ps[r][c] - mrow[r]);
    }
    __syncthreads();
    if (tid < 64) {
      float sacc = 0.f;
      for (int c = 0; c < 64; ++c) sacc += Ps[tid][c];
      lrow[tid] += sacc;
    }
#pragma unroll
    for (int i = 0; i < 8; ++i) {
      int r = (ty << 3) + i;
      float a = Oacc[i] * fac[r];
      for (int c = 0; c < 64; ++c) a += Ps[r][c] * Vs[c][tx];
      Oacc[i] = a;
    }
    __syncthreads();
  }
#pragma unroll
  for (int i = 0; i < 8; ++i) {
    int r = (ty << 3) + i;
    int qrow = q0 + r;
    if (qrow < SS) Om[((size_t)(b * SS + qrow)) * EE + h * DHH + tx] = Oacc[i] / lrow[r];
  }
}

// ---------------------------------------------------------------------------
// x = LN(x + t), one row per block
// ---------------------------------------------------------------------------
__global__ __launch_bounds__(256) void addln_kernel(
    float* __restrict__ X, const float* __restrict__ T,
    const float* __restrict__ g, const float* __restrict__ be)
{
  const int row = blockIdx.x, tid = threadIdx.x;
  __shared__ float red[256];
  float v = X[(size_t)row * EE + tid] + T[(size_t)row * EE + tid];
  red[tid] = v; __syncthreads();
  for (int w = 128; w > 0; w >>= 1) { if (tid < w) red[tid] += red[tid + w]; __syncthreads(); }
  float mean = red[0] * (1.f / EE);
  __syncthreads();
  float d = v - mean;
  red[tid] = d * d; __syncthreads();
  for (int w = 128; w > 0; w >>= 1) { if (tid < w) red[tid] += red[tid + w]; __syncthreads(); }
  float var = red[0] * (1.f / EE);
  X[(size_t)row * EE + tid] = d * rsqrtf(var + 1e-5f) * g[tid] + be[tid];
}

// ---------------------------------------------------------------------------
// Attention-weighted pooling + LN + classifier; one batch per block
// ---------------------------------------------------------------------------
__global__ __launch_bounds__(256) void final_kernel(
    const float* __restrict__ X, const float* __restrict__ g, const float* __restrict__ be,
    const float* __restrict__ w1, const float* __restrict__ b1,
    const float* __restrict__ w2, const float* __restrict__ b2,
    float* __restrict__ out)
{
  const int b = blockIdx.x, tid = threadIdx.x;
  __shared__ float rs[SS];
  __shared__ float red[256];
  __shared__ float pooled[EE];
  __shared__ float h[128];
  for (int s = tid; s < SS; s += 256) {
    const float* xr = X + ((size_t)(b * SS + s)) * EE;
    float a = 0.f;
    for (int e = 0; e < EE; ++e) a += xr[e];
    rs[s] = a;
  }
  __syncthreads();
  float mx = -INFINITY;
  for (int s = tid; s < SS; s += 256) mx = fmaxf(mx, rs[s]);
  red[tid] = mx; __syncthreads();
  for (int w = 128; w > 0; w >>= 1) { if (tid < w) red[tid] = fmaxf(red[tid], red[tid + w]); __syncthreads(); }
  mx = red[0]; __syncthreads();
  float sme = 0.f;
  for (int s = tid; s < SS; s += 256) { float e2 = expf(rs[s] - mx); rs[s] = e2; sme += e2; }
  red[tid] = sme; __syncthreads();
  for (int w = 128; w > 0; w >>= 1) { if (tid < w) red[tid] += red[tid + w]; __syncthreads(); }
  float tot = red[0]; __syncthreads();
  float acc = 0.f;
  for (int s = 0; s < SS; ++s) acc += X[((size_t)(b * SS + s)) * EE + tid] * rs[s];
  acc /= tot;
  red[tid] = acc; __syncthreads();
  for (int w = 128; w > 0; w >>= 1) { if (tid < w) red[tid] += red[tid + w]; __syncthreads(); }
  float mean = red[0] * (1.f / EE); __syncthreads();
  float d = acc - mean;
  red[tid] = d * d; __syncthreads();
  for (int w = 128; w > 0; w >>= 1) { if (tid < w) red[tid] += red[tid + w]; __syncthreads(); }
  float var = red[0] * (1.f / EE);
  pooled[tid] = d * rsqrtf(var + 1e-5f) * g[tid] + be[tid];
  __syncthreads();
  if (tid < 128) {
    const float* w = w1 + (size_t)tid * EE;
    float a = b1[tid];
    for (int e = 0; e < EE; ++e) a += w[e] * pooled[e];
    h[tid] = fmaxf(a, 0.f);
  }
  __syncthreads();
  if (tid < 2) {
    const float* w = w2 + (size_t)tid * 128;
    float a = b2[tid];
    for (int j = 0; j < 128; ++j) a += w[j] * h[j];
    out[b * 2 + tid] = a;
  }
}

// ---------------------------------------------------------------------------
extern "C" void kernel_launch(void* const* d_in, const int* in_sizes, int n_in,
                              void* d_out, int out_size, void* d_ws, size_t ws_size,
                              hipStream_t stream) {
  (void)in_sizes; (void)n_in; (void)out_size; (void)ws_size;
  const float* seq    = (const float*)d_in[0];
  const float* ph_fw  = (const float*)d_in[1];
  const float* ph_db  = (const float*)d_in[2];
  const float* ph_law = (const float*)d_in[3];
  const float* ph_lab = (const float*)d_in[4];
  const float* emb_w1 = (const float*)d_in[5];
  const float* emb_b1 = (const float*)d_in[6];
  const float* emb_w2 = (const float*)d_in[7];
  const float* emb_b2 = (const float*)d_in[8];
  const float* eln_g  = (const float*)d_in[9];
  const float* eln_b  = (const float*)d_in[10];
  const float* pos    = (const float*)d_in[11];
  const float* qw     = (const float*)d_in[12];
  const float* qb     = (const float*)d_in[13];
  const float* kw     = (const float*)d_in[14];
  const float* kb     = (const float*)d_in[15];
  const float* vw     = (const float*)d_in[16];
  const float* vb     = (const float*)d_in[17];
  const float* pw1    = (const float*)d_in[18];
  const float* pb1    = (const float*)d_in[19];
  const float* pw2    = (const float*)d_in[20];
  const float* pb2    = (const float*)d_in[21];
  const float* ow     = (const float*)d_in[22];
  const float* obv    = (const float*)d_in[23];
  const float* lng    = (const float*)d_in[24];
  const float* lnb    = (const float*)d_in[25];
  const float* fw1    = (const float*)d_in[26];
  const float* fb1    = (const float*)d_in[27];
  const float* fw2    = (const float*)d_in[28];
  const float* fb2    = (const float*)d_in[29];
  const float* clng   = (const float*)d_in[30];
  const float* clnb   = (const float*)d_in[31];
  const float* cw1    = (const float*)d_in[32];
  const float* cb1    = (const float*)d_in[33];
  const float* cw2    = (const float*)d_in[34];
  const float* cb2    = (const float*)d_in[35];

  float* ws  = (float*)d_ws;
  float* pf  = ws;            // 24 floats
  float* tsv = ws + 32;       // 24 floats
  const size_t SL = (size_t)4096 * 256;  // one activation slot (4000 rows padded)
  float* X    = ws + 256;
  float* TMP  = X + SL;
  float* Qp   = TMP + SL;
  float* Kp   = Qp + SL;
  float* Vp   = Kp + SL;
  float* ATTp = Vp + SL;
  float* HIDp = ATTp + SL;    // occupies 4*SL (4000 x 1024)
  const int M = BB * SS;      // 4000

  ph_kernel<<<BB, 256, 0, stream>>>(seq, ph_fw, ph_db, ph_law, ph_lab, pf);
  temp_kernel<<<LL * BB, 256, 0, stream>>>(pf, pw1, pb1, pw2, pb2, tsv);
  embed_kernel<<<M, 256, 0, stream>>>(seq, emb_w1, emb_b1, emb_w2, emb_b2, eln_g, eln_b, pos, X);

  for (int l = 0; l < LL; ++l) {
    const size_t wo = (size_t)l * EE * EE;
    // QKV projections (z = 0,1,2)
    gemm3_kernel<0><<<dim3(63, EE / 64, 3), 256, 0, stream>>>(
        X, qw + wo, kw + wo, vw + wo, qb + l * EE, kb + l * EE, vb + l * EE,
        Qp, Kp, Vp, M, EE, EE);
    attn_kernel<<<dim3(16, HH, BB), 256, 0, stream>>>(Qp, Kp, Vp, tsv, ATTp, l);
    gemm3_kernel<0><<<dim3(63, EE / 64, 1), 256, 0, stream>>>(
        ATTp, ow + wo, ow + wo, ow + wo, obv + l * EE, obv + l * EE, obv + l * EE,
        TMP, TMP, TMP, M, EE, EE);
    addln_kernel<<<M, 256, 0, stream>>>(X, TMP, lng + l * EE, lnb + l * EE);
    gemm3_kernel<1><<<dim3(63, FFD / 64, 1), 256, 0, stream>>>(
        X, fw1 + (size_t)l * FFD * EE, fw1 + (size_t)l * FFD * EE, fw1 + (size_t)l * FFD * EE,
        fb1 + (size_t)l * FFD, fb1 + (size_t)l * FFD, fb1 + (size_t)l * FFD,
        HIDp, HIDp, HIDp, M, FFD, EE);
    gemm3_kernel<0><<<dim3(63, EE / 64, 1), 256, 0, stream>>>(
        HIDp, fw2 + (size_t)l * EE * FFD, fw2 + (size_t)l * EE * FFD, fw2 + (size_t)l * EE * FFD,
        fb2 + l * EE, fb2 + l * EE, fb2 + l * EE,
        TMP, TMP, TMP, M, EE, FFD);
    addln_kernel<<<M, 256, 0, stream>>>(X, TMP, lng + l * EE, lnb + l * EE);
  }

  final_kernel<<<BB, 256, 0, stream>>>(X, clng, clnb, cw1, cb1, cw2, cb2, (float*)d_out);
}

// Round 2
// 2703.363 us; speedup vs baseline: 1.2193x; 1.2193x over previous
//
#include <hip/hip_runtime.h>
#include <math.h>

constexpr int BB = 4;       // batch
constexpr int SS = 1000;    // seq len
constexpr int INDIM = 5;
constexpr int EE = 256;     // embed
constexpr int LL = 6;       // layers
constexpr int HH = 8;       // heads
constexpr int DHH = 32;     // head dim
constexpr int NLM = 50;     // landmarks
constexpr int FFD = 1024;   // ff hidden

typedef short short8 __attribute__((ext_vector_type(8)));
typedef float f32x4 __attribute__((ext_vector_type(4)));

__device__ inline unsigned short f2b(float f) {
  union { float f; unsigned u; } v; v.f = f;
  unsigned u = v.u;
  unsigned r = u + 0x7FFFu + ((u >> 16) & 1u);  // round-to-nearest-even
  return (unsigned short)(r >> 16);
}

// ---------------------------------------------------------------------------
// Persistence features: top-50 landmarks -> Laplacian -> f64 Jacobi eigh -> 6 feats
// 2 barriers/round: row update done by ONE lane per pair (no intra-phase race),
// col+V update parallel across all 256 threads.
// ---------------------------------------------------------------------------
__global__ __launch_bounds__(256) void ph_kernel(
    const float* __restrict__ seq, const float* __restrict__ ph_fw,
    const float* __restrict__ ph_db, const float* __restrict__ ph_law,
    const float* __restrict__ ph_lab, float* __restrict__ pf)
{
  const int b = blockIdx.x;
  const int tid = threadIdx.x;
  __shared__ float sc[1024];
  __shared__ int   si[1024];
  __shared__ float sm[SS];
  __shared__ float lx[NLM], ly[NLM];
  __shared__ double matA[NLM][NLM];
  __shared__ double matV[NLM][NLM];
  __shared__ double rc[25], rs_[25];
  __shared__ int    rp[25], rq[25];
  __shared__ double red[256];
  __shared__ double evs[NLM];
  __shared__ int    evi[NLM];

  const float law0 = ph_law[0], law1 = ph_law[1], labv = ph_lab[0];
  for (int s = tid; s < 1024; s += 256) {
    if (s < SS) {
      const float* p = seq + ((size_t)b * SS + s) * INDIM;
      float m = (p[0] + p[1] + p[2] + p[3] + p[4]) * 0.2f;
      sm[s] = m;
      sc[s] = (float)s * law0 + m * law1 + labv;
    } else {
      sc[s] = -INFINITY;
    }
    si[s] = s;
  }
  __syncthreads();
  // bitonic sort, descending by score, ties -> ascending index (matches top_k)
  for (int k = 2; k <= 1024; k <<= 1) {
    for (int j = k >> 1; j > 0; j >>= 1) {
      for (int i = tid; i < 1024; i += 256) {
        int ixj = i ^ j;
        if (ixj > i) {
          float va = sc[i], vb = sc[ixj];
          int ia = si[i], ib = si[ixj];
          bool aBefore = (va > vb) || (va == vb && ia < ib);
          bool dirDesc = ((i & k) == 0);
          if (aBefore != dirDesc) { sc[i] = vb; sc[ixj] = va; si[i] = ib; si[ixj] = ia; }
        }
      }
      __syncthreads();
    }
  }
  if (tid < NLM) {
    int id = si[tid];
    lx[tid] = (float)id;
    ly[tid] = sm[id];
  }
  __syncthreads();
  const float fwv = fabsf(ph_fw[0]);
  const float dbv = ph_db[0];
  for (int t = tid; t < NLM * NLM; t += 256) {
    int i = t / NLM, j = t % NLM;
    float dx = lx[i] - lx[j], dy = ly[i] - ly[j];
    float d2 = dx * dx + dy * dy;
    float dist = (d2 > 0.f) ? sqrtf(d2) : 0.f;
    float Kv = expf(-(dist * fwv + dbv));
    matA[i][j] = -(double)Kv;
  }
  __syncthreads();
  if (tid < NLM) {
    double rsum = 0.0;
    for (int j = 0; j < NLM; ++j) rsum -= matA[tid][j];
    matA[tid][tid] += rsum;  // row sums cancel exactly in f64
  }
  for (int t = tid; t < NLM * NLM; t += 256)
    matV[t / NLM][t % NLM] = (t / NLM == t % NLM) ? 1.0 : 0.0;
  __syncthreads();

  for (int sweep = 0; sweep < 12; ++sweep) {
    // convergence check (one reduction per sweep)
    double acc = 0.0;
    for (int t = tid; t < NLM * NLM; t += 256) {
      int i = t / NLM, j = t % NLM;
      if (i != j) { double v = matA[i][j]; acc += v * v; }
    }
    red[tid] = acc;
    __syncthreads();
    for (int w = 128; w > 0; w >>= 1) { if (tid < w) red[tid] += red[tid + w]; __syncthreads(); }
    double offn = red[0];
    __syncthreads();
    if (offn < 1e-18) break;
    for (int r = 0; r < NLM - 1; ++r) {
      // Phase A: one lane per pair computes rotation + does both row updates.
      if (tid < 25) {
        int p, q;
        if (tid == 0) { p = NLM - 1; q = r; }
        else {
          p = (r + tid) % (NLM - 1);
          q = (r - tid + (NLM - 1)) % (NLM - 1);
        }
        if (p > q) { int tt = p; p = q; q = tt; }
        rp[tid] = p; rq[tid] = q;
        double app = matA[p][p], aqq = matA[q][q], apq = matA[p][q];
        double c = 1.0, s = 0.0;
        if (fabs(apq) > 1e-300) {
          double tau = (aqq - app) / (2.0 * apq);
          double tth = ((tau >= 0.0) ? 1.0 : -1.0) / (fabs(tau) + sqrt(1.0 + tau * tau));
          c = 1.0 / sqrt(1.0 + tth * tth);
          s = tth * c;
        }
        rc[tid] = c; rs_[tid] = s;
        for (int j = 0; j < NLM; ++j) {
          double ap = matA[p][j], aq = matA[q][j];
          matA[p][j] = c * ap - s * aq;
          matA[q][j] = s * ap + c * aq;
        }
      }
      __syncthreads();
      // Phase B: col update on A and V (disjoint columns across pairs)
      for (int t = tid; t < 2 * 25 * NLM; t += 256) {
        int half = t / (25 * NLM);
        int t2 = t % (25 * NLM);
        int kk = t2 / NLM, i = t2 % NLM;
        int p = rp[kk], q = rq[kk];
        double c = rc[kk], s = rs_[kk];
        if (half == 0) {
          double ap = matA[i][p], aq = matA[i][q];
          matA[i][p] = c * ap - s * aq;
          matA[i][q] = s * ap + c * aq;
        } else {
          double vp = matV[i][p], vq = matV[i][q];
          matV[i][p] = c * vp - s * vq;
          matV[i][q] = s * vp + c * vq;
        }
      }
      __syncthreads();
    }
  }

  if (tid < NLM) { evs[tid] = matA[tid][tid]; evi[tid] = tid; }
  __syncthreads();
  for (int ph = 0; ph < NLM; ++ph) {
    if (tid < 25) {
      int i = (ph & 1) + 2 * tid;
      if (i + 1 < NLM && evs[i] > evs[i + 1]) {
        double tv = evs[i]; evs[i] = evs[i + 1]; evs[i + 1] = tv;
        int ti = evi[i]; evi[i] = evi[i + 1]; evi[i + 1] = ti;
      }
    }
    __syncthreads();
  }
  if (tid == 0) {
    double n0 = 0.0, s0 = 0.0;
    for (int i = 0; i < NLM; ++i)
      if (evs[i] < 1e-6) { n0 += 1.0; s0 += fabs(evs[i]); }
    double gap = evs[1] - evs[0];
    int c1 = evi[1];
    double mean = 0.0;
    for (int i = 0; i < NLM; ++i) mean += matV[i][c1];
    mean /= NLM;
    double var = 0.0;
    for (int i = 0; i < NLM; ++i) { double d = matV[i][c1] - mean; var += d * d; }
    var /= (NLM - 1);
    double m4 = (evs[2] + evs[3] + evs[4] + evs[5]) * 0.25;
    double v4 = 0.0;
    for (int i = 2; i < 6; ++i) { double d = evs[i] - m4; v4 += d * d; }
    v4 /= 3.0;
    float* o = pf + b * 6;
    o[0] = (float)n0;
    o[1] = (float)s0;
    o[2] = (float)gap;
    o[3] = (float)sqrt(var);
    o[4] = (float)m4;
    o[5] = (float)sqrt(v4);
  }
}

// ---------------------------------------------------------------------------
// Per-(layer,batch) scalar attention temperature
// ---------------------------------------------------------------------------
__global__ __launch_bounds__(256) void temp_kernel(
    const float* __restrict__ pf, const float* __restrict__ w1, const float* __restrict__ b1,
    const float* __restrict__ w2, const float* __restrict__ b2, float* __restrict__ ts)
{
  const int l = blockIdx.x / BB, b = blockIdx.x % BB, tid = threadIdx.x;
  __shared__ float pfl[6];
  __shared__ float h[128];
  __shared__ float red[256];
  if (tid < 6) pfl[tid] = pf[b * 6 + tid];
  __syncthreads();
  if (tid < 128) {
    const float* w = w1 + ((size_t)l * 128 + tid) * 6;
    float a = b1[(size_t)l * 128 + tid];
#pragma unroll
    for (int i = 0; i < 6; ++i) a += w[i] * pfl[i];
    h[tid] = fmaxf(a, 0.f);
  }
  __syncthreads();
  const float* w = w2 + ((size_t)l * EE + tid) * 128;
  float a = b2[(size_t)l * EE + tid];
  for (int i = 0; i < 128; ++i) a += w[i] * h[i];
  float sg = 1.f / (1.f + expf(-a));
  red[tid] = sg; __syncthreads();
  for (int wd = 128; wd > 0; wd >>= 1) { if (tid < wd) red[tid] += red[tid + wd]; __syncthreads(); }
  if (tid == 0) ts[l * BB + b] = red[0] * (1.f / EE);
}

// ---------------------------------------------------------------------------
// Embedding MLP + LN + positional encoding; one row per block
// ---------------------------------------------------------------------------
__global__ __launch_bounds__(256) void embed_kernel(
    const float* __restrict__ seq, const float* __restrict__ w1, const float* __restrict__ b1,
    const float* __restrict__ w2, const float* __restrict__ b2,
    const float* __restrict__ g, const float* __restrict__ be,
    const float* __restrict__ pos, float* __restrict__ X)
{
  const int row = blockIdx.x;
  const int s = row % SS;
  const int tid = threadIdx.x;
  __shared__ float sv[INDIM];
  __shared__ float h[128];
  __shared__ float red[256];
  if (tid < INDIM) sv[tid] = seq[(size_t)row * INDIM + tid];
  __syncthreads();
  if (tid < 128) {
    const float* w = w1 + tid * INDIM;
    float a = b1[tid];
#pragma unroll
    for (int i = 0; i < INDIM; ++i) a += w[i] * sv[i];
    h[tid] = fmaxf(a, 0.f);
  }
  __syncthreads();
  const float* w = w2 + (size_t)tid * 128;
  float a = b2[tid];
  for (int i = 0; i < 128; ++i) a += w[i] * h[i];
  red[tid] = a; __syncthreads();
  for (int wd = 128; wd > 0; wd >>= 1) { if (tid < wd) red[tid] += red[tid + wd]; __syncthreads(); }
  float mean = red[0] * (1.f / EE);
  __syncthreads();
  float d = a - mean;
  red[tid] = d * d; __syncthreads();
  for (int wd = 128; wd > 0; wd >>= 1) { if (tid < wd) red[tid] += red[tid + wd]; __syncthreads(); }
  float var = red[0] * (1.f / EE);
  X[(size_t)row * EE + tid] = d * rsqrtf(var + 1e-5f) * g[tid] + be[tid] + pos[(size_t)s * EE + tid];
}

// ---------------------------------------------------------------------------
// bf16 MFMA GEMM: C = A[MxK] @ W[NxK]^T + bias (f32 in/out, bf16 compute).
// Tile 128x64xBK32, 4 waves (2x2), per-wave 64x32 via 16x16x32 MFMA.
// LDS rows padded to 40 ushorts (80 B): frag b128 reads land on 8 distinct
// banks per 16 lanes -> 2-way (free). blockIdx.z selects among 3 weight sets.
// ---------------------------------------------------------------------------
template <int ACT>
__global__ __launch_bounds__(256) void gemm3_mfma(
    const float* __restrict__ Ain,
    const float* __restrict__ W0, const float* __restrict__ W1, const float* __restrict__ W2,
    const float* __restrict__ bb0, const float* __restrict__ bb1, const float* __restrict__ bb2,
    float* __restrict__ C0, float* __restrict__ C1, float* __restrict__ C2,
    int M, int N, int K)
{
  const int z = blockIdx.z;
  const float* W = (z == 0) ? W0 : (z == 1) ? W1 : W2;
  const float* bias = (z == 0) ? bb0 : (z == 1) ? bb1 : bb2;
  float* C = (z == 0) ? C0 : (z == 1) ? C1 : C2;
  __shared__ __align__(16) unsigned short As[128][40];
  __shared__ __align__(16) unsigned short Bs[64][40];
  const int m0 = blockIdx.x * 128, n0 = blockIdx.y * 64;
  const int tid = threadIdx.x;
  const int lane = tid & 63, wave = tid >> 6;
  const int wm = wave >> 1, wn = wave & 1;
  const int l15 = lane & 15, l4 = lane >> 4;
  const int srow = tid >> 3, skg = tid & 7;

  f32x4 acc[4][2];
#pragma unroll
  for (int mf = 0; mf < 4; ++mf)
#pragma unroll
    for (int nf = 0; nf < 2; ++nf) acc[mf][nf] = (f32x4){0.f, 0.f, 0.f, 0.f};

  for (int k0 = 0; k0 < K; k0 += 32) {
    __syncthreads();
#pragma unroll
    for (int rr = 0; rr < 4; ++rr) {
      int row = srow + rr * 32;   // A rows are padded in ws; OOB rows read garbage, never stored
      float4 av = *(const float4*)(Ain + (size_t)(m0 + row) * K + k0 + skg * 4);
      *(ushort4*)(&As[row][skg * 4]) = make_ushort4(f2b(av.x), f2b(av.y), f2b(av.z), f2b(av.w));
    }
#pragma unroll
    for (int rr = 0; rr < 2; ++rr) {
      int row = srow + rr * 32;
      if (row < 64) {
        float4 wv = *(const float4*)(W + (size_t)(n0 + row) * K + k0 + skg * 4);
        *(ushort4*)(&Bs[row][skg * 4]) = make_ushort4(f2b(wv.x), f2b(wv.y), f2b(wv.z), f2b(wv.w));
      }
    }
    __syncthreads();
    short8 bf[2];
#pragma unroll
    for (int nf = 0; nf < 2; ++nf)
      bf[nf] = *(const short8*)(&Bs[wn * 32 + nf * 16 + l15][l4 * 8]);
#pragma unroll
    for (int mf = 0; mf < 4; ++mf) {
      short8 af = *(const short8*)(&As[wm * 64 + mf * 16 + l15][l4 * 8]);
#pragma unroll
      for (int nf = 0; nf < 2; ++nf)
        acc[mf][nf] = __builtin_amdgcn_mfma_f32_16x16x32_bf16(af, bf[nf], acc[mf][nf], 0, 0, 0);
    }
  }
#pragma unroll
  for (int nf = 0; nf < 2; ++nf) {
    int col = n0 + wn * 32 + nf * 16 + l15;
    float bv = bias[col];
#pragma unroll
    for (int mf = 0; mf < 4; ++mf) {
#pragma unroll
      for (int r = 0; r < 4; ++r) {
        int row = m0 + wm * 64 + mf * 16 + l4 * 4 + r;
        if (row < M) {
          float v = acc[mf][nf][r] + bv;
          if (ACT == 1) v = 0.5f * v * (1.f + erff(v * 0.70710678118654752440f));
          C[(size_t)row * N + col] = v;
        }
      }
    }
  }
}

// ---------------------------------------------------------------------------
// bf16 MFMA flash attention, per-sample scalar temperature.
// grid (qtile=16, head=8, batch=4), 256 thr = 4 waves x 16 q-rows.
// S = Q K^T (4 MFMAs, K-dim = D = 32); online softmax in registers via
// 16-lane shfl_xor; P -> wave-private LDS (bf16, transposed read); PV with
// V stored d-major (Vt) so B-frags are contiguous along kv.
// ---------------------------------------------------------------------------
__global__ __launch_bounds__(256) void attn_mfma(
    const float* __restrict__ Qm, const float* __restrict__ Km, const float* __restrict__ Vm,
    const float* __restrict__ ts, float* __restrict__ Om, int l)
{
  const int qt = blockIdx.x, h = blockIdx.y, b = blockIdx.z;
  const int tid = threadIdx.x;
  const int lane = tid & 63, wave = tid >> 6;
  const int l15 = lane & 15, l4 = lane >> 4;
  const float scale = ts[l * BB + b] * 0.17677669529663688110f;  // ts / sqrt(32)
  __shared__ __align__(16) unsigned short Ks[64][40];
  __shared__ __align__(16) unsigned short Vt[32][72];
  __shared__ __align__(16) unsigned short Pw[4][16][72];
  const int q0 = qt * 64 + wave * 16;

  // Q fragment (A-operand): lane row = l15, d = l4*8 + j
  short8 qf;
  {
    unsigned short qb_[8] = {0, 0, 0, 0, 0, 0, 0, 0};
    int qrow = q0 + l15;
    if (qrow < SS) {
      const float* qp = Qm + ((size_t)(b * SS + qrow)) * EE + h * DHH + l4 * 8;
      float4 a = *(const float4*)qp;
      float4 c = *(const float4*)(qp + 4);
      qb_[0] = f2b(a.x); qb_[1] = f2b(a.y); qb_[2] = f2b(a.z); qb_[3] = f2b(a.w);
      qb_[4] = f2b(c.x); qb_[5] = f2b(c.y); qb_[6] = f2b(c.z); qb_[7] = f2b(c.w);
    }
#pragma unroll
    for (int i = 0; i < 8; ++i) qf[i] = (short)qb_[i];
  }

  float mrun[4] = {-INFINITY, -INFINITY, -INFINITY, -INFINITY};
  float lrun[4] = {0.f, 0.f, 0.f, 0.f};
  f32x4 Oacc[2];
  Oacc[0] = (f32x4){0.f, 0.f, 0.f, 0.f};
  Oacc[1] = (f32x4){0.f, 0.f, 0.f, 0.f};

  for (int k0 = 0; k0 < SS; k0 += 64) {
    int kn = SS - k0; if (kn > 64) kn = 64;
    __syncthreads();
    // stage K [64][32] natural layout
    {
      int row = tid >> 3, kg = tid & 7;
#pragma unroll
      for (int rr = 0; rr < 2; ++rr) {
        int r2 = row + rr * 32;
        float4 kv = make_float4(0.f, 0.f, 0.f, 0.f);
        if (r2 < kn)
          kv = *(const float4*)(Km + ((size_t)(b * SS + k0 + r2)) * EE + h * DHH + kg * 4);
        *(ushort4*)(&Ks[r2][kg * 4]) = make_ushort4(f2b(kv.x), f2b(kv.y), f2b(kv.z), f2b(kv.w));
      }
    }
    // stage V transposed: Vt[d][kv]
    {
      int d = tid & 31, kb = tid >> 5;
      unsigned short uu[8];
#pragma unroll
      for (int i = 0; i < 8; ++i) {
        int kv = kb * 8 + i;
        float vv = (kv < kn) ? Vm[((size_t)(b * SS + k0 + kv)) * EE + h * DHH + d] : 0.f;
        uu[i] = f2b(vv);
      }
      *(ushort4*)(&Vt[d][kb * 8])     = make_ushort4(uu[0], uu[1], uu[2], uu[3]);
      *(ushort4*)(&Vt[d][kb * 8 + 4]) = make_ushort4(uu[4], uu[5], uu[6], uu[7]);
    }
    __syncthreads();

    // S = Q K^T : C layout row=l4*4+r (q), col=nf*16+l15 (kv)
    f32x4 sa[4];
#pragma unroll
    for (int nf = 0; nf < 4; ++nf) {
      short8 kf = *(const short8*)(&Ks[nf * 16 + l15][l4 * 8]);
      f32x4 zz = (f32x4){0.f, 0.f, 0.f, 0.f};
      sa[nf] = __builtin_amdgcn_mfma_f32_16x16x32_bf16(qf, kf, zz, 0, 0, 0);
    }
#pragma unroll
    for (int nf = 0; nf < 4; ++nf) {
      bool valid = (nf * 16 + l15) < kn;
#pragma unroll
      for (int r = 0; r < 4; ++r)
        sa[nf][r] = valid ? sa[nf][r] * scale : -INFINITY;
    }
    // online softmax per row
    float pv[4][4];
#pragma unroll
    for (int r = 0; r < 4; ++r) {
      float tmax = fmaxf(fmaxf(sa[0][r], sa[1][r]), fmaxf(sa[2][r], sa[3][r]));
#pragma unroll
      for (int m = 1; m < 16; m <<= 1) tmax = fmaxf(tmax, __shfl_xor(tmax, m, 64));
      float mnew = fmaxf(mrun[r], tmax);
      float fac = expf(mrun[r] - mnew);
      float rsum = 0.f;
#pragma unroll
      for (int nf = 0; nf < 4; ++nf) {
        float p = expf(sa[nf][r] - mnew);
        pv[nf][r] = p;
        rsum += p;
      }
#pragma unroll
      for (int m = 1; m < 16; m <<= 1) rsum += __shfl_xor(rsum, m, 64);
      lrun[r] = lrun[r] * fac + rsum;
      mrun[r] = mnew;
      Oacc[0][r] *= fac;
      Oacc[1][r] *= fac;
    }
    // P -> wave-private LDS (bf16), transposed consumption
#pragma unroll
    for (int nf = 0; nf < 4; ++nf)
#pragma unroll
      for (int r = 0; r < 4; ++r)
        Pw[wave][l4 * 4 + r][nf * 16 + l15] = f2b(pv[nf][r]);
    asm volatile("s_waitcnt lgkmcnt(0)" ::: "memory");
    __builtin_amdgcn_sched_barrier(0);
    // PV: O[16 q][32 d] += P[16][64] V[64][32]
#pragma unroll
    for (int ka = 0; ka < 2; ++ka) {
      short8 pa = *(const short8*)(&Pw[wave][l15][ka * 32 + l4 * 8]);
#pragma unroll
      for (int df = 0; df < 2; ++df) {
        short8 vf = *(const short8*)(&Vt[df * 16 + l15][ka * 32 + l4 * 8]);
        Oacc[df] = __builtin_amdgcn_mfma_f32_16x16x32_bf16(pa, vf, Oacc[df], 0, 0, 0);
      }
    }
  }
#pragma unroll
  for (int df = 0; df < 2; ++df)
#pragma unroll
    for (int r = 0; r < 4; ++r) {
      int qrow = q0 + l4 * 4 + r;
      if (qrow < SS)
        Om[((size_t)(b * SS + qrow)) * EE + h * DHH + df * 16 + l15] = Oacc[df][r] / lrun[r];
    }
}

// ---------------------------------------------------------------------------
// x = LN(x + t), one row per block
// ---------------------------------------------------------------------------
__global__ __launch_bounds__(256) void addln_kernel(
    float* __restrict__ X, const float* __restrict__ T,
    const float* __restrict__ g, const float* __restrict__ be)
{
  const int row = blockIdx.x, tid = threadIdx.x;
  __shared__ float red[256];
  float v = X[(size_t)row * EE + tid] + T[(size_t)row * EE + tid];
  red[tid] = v; __syncthreads();
  for (int w = 128; w > 0; w >>= 1) { if (tid < w) red[tid] += red[tid + w]; __syncthreads(); }
  float mean = red[0] * (1.f / EE);
  __syncthreads();
  float d = v - mean;
  red[tid] = d * d; __syncthreads();
  for (int w = 128; w > 0; w >>= 1) { if (tid < w) red[tid] += red[tid + w]; __syncthreads(); }
  float var = red[0] * (1.f / EE);
  X[(size_t)row * EE + tid] = d * rsqrtf(var + 1e-5f) * g[tid] + be[tid];
}

// ---------------------------------------------------------------------------
// Attention-weighted pooling + LN + classifier; one batch per block
// ---------------------------------------------------------------------------
__global__ __launch_bounds__(256) void final_kernel(
    const float* __restrict__ X, const float* __restrict__ g, const float* __restrict__ be,
    const float* __restrict__ w1, const float* __restrict__ b1,
    const float* __restrict__ w2, const float* __restrict__ b2,
    float* __restrict__ out)
{
  const int b = blockIdx.x, tid = threadIdx.x;
  __shared__ float rs[SS];
  __shared__ float red[256];
  __shared__ float pooled[EE];
  __shared__ float h[128];
  for (int s = tid; s < SS; s += 256) {
    const float* xr = X + ((size_t)(b * SS + s)) * EE;
    float a = 0.f;
    for (int e = 0; e < EE; ++e) a += xr[e];
    rs[s] = a;
  }
  __syncthreads();
  float mx = -INFINITY;
  for (int s = tid; s < SS; s += 256) mx = fmaxf(mx, rs[s]);
  red[tid] = mx; __syncthreads();
  for (int w = 128; w > 0; w >>= 1) { if (tid < w) red[tid] = fmaxf(red[tid], red[tid + w]); __syncthreads(); }
  mx = red[0]; __syncthreads();
  float sme = 0.f;
  for (int s = tid; s < SS; s += 256) { float e2 = expf(rs[s] - mx); rs[s] = e2; sme += e2; }
  red[tid] = sme; __syncthreads();
  for (int w = 128; w > 0; w >>= 1) { if (tid < w) red[tid] += red[tid + w]; __syncthreads(); }
  float tot = red[0]; __syncthreads();
  float acc = 0.f;
  for (int s = 0; s < SS; ++s) acc += X[((size_t)(b * SS + s)) * EE + tid] * rs[s];
  acc /= tot;
  red[tid] = acc; __syncthreads();
  for (int w = 128; w > 0; w >>= 1) { if (tid < w) red[tid] += red[tid + w]; __syncthreads(); }
  float mean = red[0] * (1.f / EE); __syncthreads();
  float d = acc - mean;
  red[tid] = d * d; __syncthreads();
  for (int w = 128; w > 0; w >>= 1) { if (tid < w) red[tid] += red[tid + w]; __syncthreads(); }
  float var = red[0] * (1.f / EE);
  pooled[tid] = d * rsqrtf(var + 1e-5f) * g[tid] + be[tid];
  __syncthreads();
  if (tid < 128) {
    const float* w = w1 + (size_t)tid * EE;
    float a = b1[tid];
    for (int e = 0; e < EE; ++e) a += w[e] * pooled[e];
    h[tid] = fmaxf(a, 0.f);
  }
  __syncthreads();
  if (tid < 2) {
    const float* w = w2 + (size_t)tid * 128;
    float a = b2[tid];
    for (int j = 0; j < 128; ++j) a += w[j] * h[j];
    out[b * 2 + tid] = a;
  }
}

// ---------------------------------------------------------------------------
extern "C" void kernel_launch(void* const* d_in, const int* in_sizes, int n_in,
                              void* d_out, int out_size, void* d_ws, size_t ws_size,
                              hipStream_t stream) {
  (void)in_sizes; (void)n_in; (void)out_size; (void)ws_size;
  const float* seq    = (const float*)d_in[0];
  const float* ph_fw  = (const float*)d_in[1];
  const float* ph_db  = (const float*)d_in[2];
  const float* ph_law = (const float*)d_in[3];
  const float* ph_lab = (const float*)d_in[4];
  const float* emb_w1 = (const float*)d_in[5];
  const float* emb_b1 = (const float*)d_in[6];
  const float* emb_w2 = (const float*)d_in[7];
  const float* emb_b2 = (const float*)d_in[8];
  const float* eln_g  = (const float*)d_in[9];
  const float* eln_b  = (const float*)d_in[10];
  const float* pos    = (const float*)d_in[11];
  const float* qw     = (const float*)d_in[12];
  const float* qb     = (const float*)d_in[13];
  const float* kw     = (const float*)d_in[14];
  const float* kb     = (const float*)d_in[15];
  const float* vw     = (const float*)d_in[16];
  const float* vb     = (const float*)d_in[17];
  const float* pw1    = (const float*)d_in[18];
  const float* pb1    = (const float*)d_in[19];
  const float* pw2    = (const float*)d_in[20];
  const float* pb2    = (const float*)d_in[21];
  const float* ow     = (const float*)d_in[22];
  const float* obv    = (const float*)d_in[23];
  const float* lng    = (const float*)d_in[24];
  const float* lnb    = (const float*)d_in[25];
  const float* fw1    = (const float*)d_in[26];
  const float* fb1    = (const float*)d_in[27];
  const float* fw2    = (const float*)d_in[28];
  const float* fb2    = (const float*)d_in[29];
  const float* clng   = (const float*)d_in[30];
  const float* clnb   = (const float*)d_in[31];
  const float* cw1    = (const float*)d_in[32];
  const float* cb1    = (const float*)d_in[33];
  const float* cw2    = (const float*)d_in[34];
  const float* cb2    = (const float*)d_in[35];

  float* ws  = (float*)d_ws;
  float* pf  = ws;            // 24 floats
  float* tsv = ws + 32;       // 24 floats
  const size_t SL = (size_t)4096 * 256;  // one activation slot (4000 rows padded)
  float* X    = ws + 256;
  float* TMP  = X + SL;
  float* Qp   = TMP + SL;
  float* Kp   = Qp + SL;
  float* Vp   = Kp + SL;
  float* ATTp = Vp + SL;
  float* HIDp = ATTp + SL;    // 4*SL (4096 x 1024)
  const int M = BB * SS;      // 4000

  ph_kernel<<<BB, 256, 0, stream>>>(seq, ph_fw, ph_db, ph_law, ph_lab, pf);
  temp_kernel<<<LL * BB, 256, 0, stream>>>(pf, pw1, pb1, pw2, pb2, tsv);
  embed_kernel<<<M, 256, 0, stream>>>(seq, emb_w1, emb_b1, emb_w2, emb_b2, eln_g, eln_b, pos, X);

  const int GM = (M + 127) / 128;  // 32
  for (int l = 0; l < LL; ++l) {
    const size_t wo = (size_t)l * EE * EE;
    gemm3_mfma<0><<<dim3(GM, EE / 64, 3), 256, 0, stream>>>(
        X, qw + wo, kw + wo, vw + wo, qb + l * EE, kb + l * EE, vb + l * EE,
        Qp, Kp, Vp, M, EE, EE);
    attn_mfma<<<dim3(16, HH, BB), 256, 0, stream>>>(Qp, Kp, Vp, tsv, ATTp, l);
    gemm3_mfma<0><<<dim3(GM, EE / 64, 1), 256, 0, stream>>>(
        ATTp, ow + wo, ow + wo, ow + wo, obv + l * EE, obv + l * EE, obv + l * EE,
        TMP, TMP, TMP, M, EE, EE);
    addln_kernel<<<M, 256, 0, stream>>>(X, TMP, lng + l * EE, lnb + l * EE);
    gemm3_mfma<1><<<dim3(GM, FFD / 64, 1), 256, 0, stream>>>(
        X, fw1 + (size_t)l * FFD * EE, fw1 + (size_t)l * FFD * EE, fw1 + (size_t)l * FFD * EE,
        fb1 + (size_t)l * FFD, fb1 + (size_t)l * FFD, fb1 + (size_t)l * FFD,
        HIDp, HIDp, HIDp, M, FFD, EE);
    gemm3_mfma<0><<<dim3(GM, EE / 64, 1), 256, 0, stream>>>(
        HIDp, fw2 + (size_t)l * EE * FFD, fw2 + (size_t)l * EE * FFD, fw2 + (size_t)l * EE * FFD,
        fb2 + l * EE, fb2 + l * EE, fb2 + l * EE,
        TMP, TMP, TMP, M, EE, FFD);
    addln_kernel<<<M, 256, 0, stream>>>(X, TMP, lng + l * EE, lnb + l * EE);
  }

  final_kernel<<<BB, 256, 0, stream>>>(X, clng, clnb, cw1, cb1, cw2, cb2, (float*)d_out);
}

// Round 3
// 1851.645 us; speedup vs baseline: 1.7802x; 1.4600x over previous
//
#include <hip/hip_runtime.h>
#include <math.h>

constexpr int BB = 4;       // batch
constexpr int SS = 1000;    // seq len
constexpr int INDIM = 5;
constexpr int EE = 256;     // embed
constexpr int LL = 6;       // layers
constexpr int HH = 8;       // heads
constexpr int DHH = 32;     // head dim
constexpr int NLM = 50;     // landmarks
constexpr int FFD = 1024;   // ff hidden

typedef short short8 __attribute__((ext_vector_type(8)));
typedef float f32x4 __attribute__((ext_vector_type(4)));

__device__ inline unsigned short f2b(float f) {
  union { float f; unsigned u; } v; v.f = f;
  unsigned u = v.u;
  unsigned r = u + 0x7FFFu + ((u >> 16) & 1u);  // round-to-nearest-even
  return (unsigned short)(r >> 16);
}

__device__ inline double wred_sum(double v) {
#pragma unroll
  for (int m = 1; m < 64; m <<= 1) v += __shfl_xor(v, m, 64);
  return v;
}
__device__ inline double wred_min(double v) {
#pragma unroll
  for (int m = 1; m < 64; m <<= 1) v = fmin(v, __shfl_xor(v, m, 64));
  return v;
}
__device__ inline double wred_max(double v) {
#pragma unroll
  for (int m = 1; m < 64; m <<= 1) v = fmax(v, __shfl_xor(v, m, 64));
  return v;
}

// ---------------------------------------------------------------------------
// Persistence features. Top-50 landmarks (bitonic, 256 thr) -> f64 Laplacian ->
// single-wave Householder tridiagonalization -> per-lane Sturm bisection (all
// 50 eigenvalues in parallel) -> inverse iteration + reflector back-transform
// for the Fiedler vector. No barriers inside the eig phase (wave lockstep).
// ---------------------------------------------------------------------------
__global__ __launch_bounds__(256) void ph_kernel(
    const float* __restrict__ seq, const float* __restrict__ ph_fw,
    const float* __restrict__ ph_db, const float* __restrict__ ph_law,
    const float* __restrict__ ph_lab, float* __restrict__ pf)
{
  const int b = blockIdx.x;
  const int tid = threadIdx.x;
  __shared__ float sc[1024];
  __shared__ int   si[1024];
  __shared__ float sm[SS];
  __shared__ float lx[NLM], ly[NLM];
  __shared__ double matA[NLM][51];   // stride 51 doubles: 4-way bank aliasing on column reads
  __shared__ double vv[64], ww[64];
  __shared__ double dar[NLM], ear[NLM], e2a[NLM], tauA[NLM], evs[NLM];
  __shared__ double gdl[NLM], gdd[NLM], gdu[NLM], gdu2[NLM], gz[NLM];
  __shared__ double fied[NLM];

  const float law0 = ph_law[0], law1 = ph_law[1], labv = ph_lab[0];
  for (int s = tid; s < 1024; s += 256) {
    if (s < SS) {
      const float* p = seq + ((size_t)b * SS + s) * INDIM;
      float m = (p[0] + p[1] + p[2] + p[3] + p[4]) * 0.2f;
      sm[s] = m;
      sc[s] = (float)s * law0 + m * law1 + labv;
    } else {
      sc[s] = -INFINITY;
    }
    si[s] = s;
  }
  __syncthreads();
  // bitonic sort, descending by score, ties -> ascending index (matches top_k)
  for (int k = 2; k <= 1024; k <<= 1) {
    for (int j = k >> 1; j > 0; j >>= 1) {
      for (int i = tid; i < 1024; i += 256) {
        int ixj = i ^ j;
        if (ixj > i) {
          float va = sc[i], vb = sc[ixj];
          int ia = si[i], ib = si[ixj];
          bool aBefore = (va > vb) || (va == vb && ia < ib);
          bool dirDesc = ((i & k) == 0);
          if (aBefore != dirDesc) { sc[i] = vb; sc[ixj] = va; si[i] = ib; si[ixj] = ia; }
        }
      }
      __syncthreads();
    }
  }
  if (tid < NLM) {
    int id = si[tid];
    lx[tid] = (float)id;
    ly[tid] = sm[id];
  }
  __syncthreads();
  const float fwv = fabsf(ph_fw[0]);
  const float dbv = ph_db[0];
  for (int t = tid; t < NLM * NLM; t += 256) {
    int i = t / NLM, j = t % NLM;
    float dx = lx[i] - lx[j], dy = ly[i] - ly[j];
    float d2 = dx * dx + dy * dy;
    float dist = (d2 > 0.f) ? sqrtf(d2) : 0.f;
    float Kv = expf(-(dist * fwv + dbv));
    matA[i][j] = -(double)Kv;
  }
  __syncthreads();
  if (tid < NLM) {
    double rsum = 0.0;
    for (int j = 0; j < NLM; ++j) rsum -= matA[tid][j];
    matA[tid][tid] += rsum;  // row sums cancel exactly in f64 -> lambda0 ~ 1e-15
  }
  __syncthreads();

  if (tid >= 64) return;  // waves 1..3 done; wave 0 runs the eigensolve barrier-free
  const int lane = tid;

  // ---- Householder tridiagonalization (LAPACK dlarfg convention) ----
  for (int k = 0; k <= NLM - 3; ++k) {
    const int m = NLM - 1 - k;       // reflector length
    const int r = k + 1 + lane;      // my row
    double x = (lane < m) ? matA[r][k] : 0.0;
    double x0 = __shfl(x, 0, 64);
    double sigma = wred_sum((lane >= 1 && lane < m) ? x * x : 0.0);
    double beta, tau, scale;
    if (sigma == 0.0) { beta = x0; tau = 0.0; scale = 0.0; }
    else {
      double nrm = sqrt(x0 * x0 + sigma);
      beta = (x0 >= 0.0) ? -nrm : nrm;
      tau = (beta - x0) / beta;
      scale = 1.0 / (x0 - beta);
    }
    double v = (lane == 0) ? 1.0 : x * scale;
    if (lane < m) { vv[lane] = v; matA[r][k] = v; }   // keep v for back-transform
    if (lane == 0) { ear[k] = beta; tauA[k] = tau; }
    __builtin_amdgcn_wave_barrier();
    // p = tau * A v (trailing block, one row per lane)
    double p = 0.0;
    if (lane < m) {
      const double* Ar = &matA[r][k + 1];
      for (int j = 0; j < m; ++j) p += Ar[j] * vv[j];
      p *= tau;
    }
    double dotvp = wred_sum((lane < m) ? v * p : 0.0);
    double w = p - 0.5 * tau * dotvp * v;
    if (lane < m) ww[lane] = w;
    __builtin_amdgcn_wave_barrier();
    // A -= v w^T + w v^T
    if (lane < m) {
      double* Ar = &matA[r][k + 1];
      for (int j = 0; j < m; ++j) Ar[j] -= v * ww[j] + w * vv[j];
    }
    __builtin_amdgcn_wave_barrier();
  }
  if (lane < NLM) dar[lane] = matA[lane][lane];
  if (lane == 0) ear[NLM - 2] = matA[NLM - 1][NLM - 2];
  __builtin_amdgcn_wave_barrier();
  if (lane < NLM - 1) e2a[lane] = ear[lane] * ear[lane];
  __builtin_amdgcn_wave_barrier();

  // ---- Gershgorin bounds ----
  double lo_i = 1e300, hi_i = -1e300;
  if (lane < NLM) {
    double rl = (lane > 0) ? fabs(ear[lane - 1]) : 0.0;
    double rr = (lane < NLM - 1) ? fabs(ear[lane]) : 0.0;
    lo_i = dar[lane] - rl - rr;
    hi_i = dar[lane] + rl + rr;
  }
  double glo = wred_min(lo_i), ghi = wred_max(hi_i);

  // ---- bisection: lane k finds the k-th smallest eigenvalue ----
  if (lane < NLM) {
    double lo = glo, hi = ghi;
    for (int it = 0; it < 60; ++it) {
      double mid = 0.5 * (lo + hi);
      int cnt = 0;
      double q = dar[0] - mid;
      if (q < 0.0) cnt++;
      for (int i = 1; i < NLM; ++i) {
        double denom = (q == 0.0) ? -1e-280 : q;
        q = dar[i] - mid - e2a[i - 1] / denom;
        if (q < 0.0) cnt++;
      }
      if (cnt >= lane + 1) hi = mid; else lo = mid;
    }
    evs[lane] = 0.5 * (lo + hi);
  }
  __builtin_amdgcn_wave_barrier();

  // ---- Fiedler vector: inverse iteration on tridiagonal (lane 0 serial) ----
  if (lane == 0) {
    double shift = evs[1];
    unsigned rs = 12345u;
    for (int i = 0; i < NLM; ++i) {
      rs = rs * 1103515245u + 12345u;
      gz[i] = ((double)((rs >> 8) & 0xFFFF)) / 65536.0 - 0.5;
    }
    for (int iter = 0; iter < 2; ++iter) {
      for (int i = 0; i < NLM; ++i) gdd[i] = dar[i] - shift;
      for (int i = 0; i < NLM - 1; ++i) { gdl[i] = ear[i]; gdu[i] = ear[i]; }
      // gtsv: LU with partial pivoting
      for (int i = 0; i < NLM - 1; ++i) {
        if (fabs(gdd[i]) >= fabs(gdl[i])) {
          if (gdd[i] == 0.0) gdd[i] = 1e-280;
          double fact = gdl[i] / gdd[i];
          gdd[i + 1] -= fact * gdu[i];
          gz[i + 1] -= fact * gz[i];
          if (i < NLM - 2) gdu2[i] = 0.0;
        } else {
          double fact = gdd[i] / gdl[i];
          gdd[i] = gdl[i];
          double tmp = gdd[i + 1];
          gdd[i + 1] = gdu[i] - fact * tmp;
          if (i < NLM - 2) { gdu2[i] = gdu[i + 1]; gdu[i + 1] = -fact * gdu2[i]; }
          gdu[i] = tmp;
          double tz = gz[i]; gz[i] = gz[i + 1]; gz[i + 1] = tz - fact * gz[i];
        }
      }
      if (gdd[NLM - 1] == 0.0) gdd[NLM - 1] = 1e-280;
      gz[NLM - 1] /= gdd[NLM - 1];
      gz[NLM - 2] = (gz[NLM - 2] - gdu[NLM - 2] * gz[NLM - 1]) / gdd[NLM - 2];
      for (int i = NLM - 3; i >= 0; --i)
        gz[i] = (gz[i] - gdu[i] * gz[i + 1] - gdu2[i] * gz[i + 2]) / gdd[i];
      double nr = 0.0;
      for (int i = 0; i < NLM; ++i) nr += gz[i] * gz[i];
      nr = sqrt(nr);
      for (int i = 0; i < NLM; ++i) gz[i] /= nr;
    }
  }
  __builtin_amdgcn_wave_barrier();
  if (lane < NLM) fied[lane] = gz[lane];
  __builtin_amdgcn_wave_barrier();
  // back-transform: x = H_0 ... H_47 y, applied right-to-left
  for (int k = NLM - 3; k >= 0; --k) {
    const int m = NLM - 1 - k;
    double v = 0.0, xi = 0.0;
    if (lane < m) { v = matA[k + 1 + lane][k]; xi = fied[k + 1 + lane]; }
    double dot = wred_sum(v * xi);
    double t = tauA[k];
    if (lane < m) fied[k + 1 + lane] = xi - t * dot * v;
    __builtin_amdgcn_wave_barrier();
  }

  if (lane == 0) {
    double n0 = 0.0, s0 = 0.0;
    for (int i = 0; i < NLM; ++i)
      if (evs[i] < 1e-6) { n0 += 1.0; s0 += fabs(evs[i]); }
    double gap = evs[1] - evs[0];
    double mean = 0.0;
    for (int i = 0; i < NLM; ++i) mean += fied[i];
    mean /= NLM;
    double var = 0.0;
    for (int i = 0; i < NLM; ++i) { double d = fied[i] - mean; var += d * d; }
    var /= (NLM - 1);
    double m4 = (evs[2] + evs[3] + evs[4] + evs[5]) * 0.25;
    double v4 = 0.0;
    for (int i = 2; i < 6; ++i) { double d = evs[i] - m4; v4 += d * d; }
    v4 /= 3.0;
    float* o = pf + b * 6;
    o[0] = (float)n0;
    o[1] = (float)s0;
    o[2] = (float)gap;
    o[3] = (float)sqrt(var);
    o[4] = (float)m4;
    o[5] = (float)sqrt(v4);
  }
}

// ---------------------------------------------------------------------------
// Per-(layer,batch) scalar attention temperature
// ---------------------------------------------------------------------------
__global__ __launch_bounds__(256) void temp_kernel(
    const float* __restrict__ pf, const float* __restrict__ w1, const float* __restrict__ b1,
    const float* __restrict__ w2, const float* __restrict__ b2, float* __restrict__ ts)
{
  const int l = blockIdx.x / BB, b = blockIdx.x % BB, tid = threadIdx.x;
  __shared__ float pfl[6];
  __shared__ float h[128];
  __shared__ float red[256];
  if (tid < 6) pfl[tid] = pf[b * 6 + tid];
  __syncthreads();
  if (tid < 128) {
    const float* w = w1 + ((size_t)l * 128 + tid) * 6;
    float a = b1[(size_t)l * 128 + tid];
#pragma unroll
    for (int i = 0; i < 6; ++i) a += w[i] * pfl[i];
    h[tid] = fmaxf(a, 0.f);
  }
  __syncthreads();
  const float* w = w2 + ((size_t)l * EE + tid) * 128;
  float a = b2[(size_t)l * EE + tid];
  for (int i = 0; i < 128; ++i) a += w[i] * h[i];
  float sg = 1.f / (1.f + expf(-a));
  red[tid] = sg; __syncthreads();
  for (int wd = 128; wd > 0; wd >>= 1) { if (tid < wd) red[tid] += red[tid + wd]; __syncthreads(); }
  if (tid == 0) ts[l * BB + b] = red[0] * (1.f / EE);
}

// ---------------------------------------------------------------------------
// Embedding MLP + LN + positional encoding; one row per block
// ---------------------------------------------------------------------------
__global__ __launch_bounds__(256) void embed_kernel(
    const float* __restrict__ seq, const float* __restrict__ w1, const float* __restrict__ b1,
    const float* __restrict__ w2, const float* __restrict__ b2,
    const float* __restrict__ g, const float* __restrict__ be,
    const float* __restrict__ pos, float* __restrict__ X)
{
  const int row = blockIdx.x;
  const int s = row % SS;
  const int tid = threadIdx.x;
  __shared__ float sv[INDIM];
  __shared__ float h[128];
  __shared__ float red[256];
  if (tid < INDIM) sv[tid] = seq[(size_t)row * INDIM + tid];
  __syncthreads();
  if (tid < 128) {
    const float* w = w1 + tid * INDIM;
    float a = b1[tid];
#pragma unroll
    for (int i = 0; i < INDIM; ++i) a += w[i] * sv[i];
    h[tid] = fmaxf(a, 0.f);
  }
  __syncthreads();
  const float* w = w2 + (size_t)tid * 128;
  float a = b2[tid];
  for (int i = 0; i < 128; ++i) a += w[i] * h[i];
  red[tid] = a; __syncthreads();
  for (int wd = 128; wd > 0; wd >>= 1) { if (tid < wd) red[tid] += red[tid + wd]; __syncthreads(); }
  float mean = red[0] * (1.f / EE);
  __syncthreads();
  float d = a - mean;
  red[tid] = d * d; __syncthreads();
  for (int wd = 128; wd > 0; wd >>= 1) { if (tid < wd) red[tid] += red[tid + wd]; __syncthreads(); }
  float var = red[0] * (1.f / EE);
  X[(size_t)row * EE + tid] = d * rsqrtf(var + 1e-5f) * g[tid] + be[tid] + pos[(size_t)s * EE + tid];
}

// ---------------------------------------------------------------------------
// bf16 MFMA GEMM: C = A[MxK] @ W[NxK]^T + bias (f32 in/out, bf16 compute).
// Tile 128x64xBK32, 4 waves (2x2), per-wave 64x32 via 16x16x32 MFMA.
// ---------------------------------------------------------------------------
template <int ACT>
__global__ __launch_bounds__(256) void gemm3_mfma(
    const float* __restrict__ Ain,
    const float* __restrict__ W0, const float* __restrict__ W1, const float* __restrict__ W2,
    const float* __restrict__ bb0, const float* __restrict__ bb1, const float* __restrict__ bb2,
    float* __restrict__ C0, float* __restrict__ C1, float* __restrict__ C2,
    int M, int N, int K)
{
  const int z = blockIdx.z;
  const float* W = (z == 0) ? W0 : (z == 1) ? W1 : W2;
  const float* bias = (z == 0) ? bb0 : (z == 1) ? bb1 : bb2;
  float* C = (z == 0) ? C0 : (z == 1) ? C1 : C2;
  __shared__ __align__(16) unsigned short As[128][40];
  __shared__ __align__(16) unsigned short Bs[64][40];
  const int m0 = blockIdx.x * 128, n0 = blockIdx.y * 64;
  const int tid = threadIdx.x;
  const int lane = tid & 63, wave = tid >> 6;
  const int wm = wave >> 1, wn = wave & 1;
  const int l15 = lane & 15, l4 = lane >> 4;
  const int srow = tid >> 3, skg = tid & 7;

  f32x4 acc[4][2];
#pragma unroll
  for (int mf = 0; mf < 4; ++mf)
#pragma unroll
    for (int nf = 0; nf < 2; ++nf) acc[mf][nf] = (f32x4){0.f, 0.f, 0.f, 0.f};

  for (int k0 = 0; k0 < K; k0 += 32) {
    __syncthreads();
#pragma unroll
    for (int rr = 0; rr < 4; ++rr) {
      int row = srow + rr * 32;
      float4 av = *(const float4*)(Ain + (size_t)(m0 + row) * K + k0 + skg * 4);
      *(ushort4*)(&As[row][skg * 4]) = make_ushort4(f2b(av.x), f2b(av.y), f2b(av.z), f2b(av.w));
    }
#pragma unroll
    for (int rr = 0; rr < 2; ++rr) {
      int row = srow + rr * 32;
      if (row < 64) {
        float4 wv = *(const float4*)(W + (size_t)(n0 + row) * K + k0 + skg * 4);
        *(ushort4*)(&Bs[row][skg * 4]) = make_ushort4(f2b(wv.x), f2b(wv.y), f2b(wv.z), f2b(wv.w));
      }
    }
    __syncthreads();
    short8 bf[2];
#pragma unroll
    for (int nf = 0; nf < 2; ++nf)
      bf[nf] = *(const short8*)(&Bs[wn * 32 + nf * 16 + l15][l4 * 8]);
#pragma unroll
    for (int mf = 0; mf < 4; ++mf) {
      short8 af = *(const short8*)(&As[wm * 64 + mf * 16 + l15][l4 * 8]);
#pragma unroll
      for (int nf = 0; nf < 2; ++nf)
        acc[mf][nf] = __builtin_amdgcn_mfma_f32_16x16x32_bf16(af, bf[nf], acc[mf][nf], 0, 0, 0);
    }
  }
#pragma unroll
  for (int nf = 0; nf < 2; ++nf) {
    int col = n0 + wn * 32 + nf * 16 + l15;
    float bv = bias[col];
#pragma unroll
    for (int mf = 0; mf < 4; ++mf) {
#pragma unroll
      for (int r = 0; r < 4; ++r) {
        int row = m0 + wm * 64 + mf * 16 + l4 * 4 + r;
        if (row < M) {
          float v = acc[mf][nf][r] + bv;
          if (ACT == 1) v = 0.5f * v * (1.f + erff(v * 0.70710678118654752440f));
          C[(size_t)row * N + col] = v;
        }
      }
    }
  }
}

// ---------------------------------------------------------------------------
// bf16 MFMA flash attention, per-sample scalar temperature.
// ---------------------------------------------------------------------------
__global__ __launch_bounds__(256) void attn_mfma(
    const float* __restrict__ Qm, const float* __restrict__ Km, const float* __restrict__ Vm,
    const float* __restrict__ ts, float* __restrict__ Om, int l)
{
  const int qt = blockIdx.x, h = blockIdx.y, b = blockIdx.z;
  const int tid = threadIdx.x;
  const int lane = tid & 63, wave = tid >> 6;
  const int l15 = lane & 15, l4 = lane >> 4;
  const float scale = ts[l * BB + b] * 0.17677669529663688110f;  // ts / sqrt(32)
  __shared__ __align__(16) unsigned short Ks[64][40];
  __shared__ __align__(16) unsigned short Vt[32][72];
  __shared__ __align__(16) unsigned short Pw[4][16][72];
  const int q0 = qt * 64 + wave * 16;

  short8 qf;
  {
    unsigned short qb_[8] = {0, 0, 0, 0, 0, 0, 0, 0};
    int qrow = q0 + l15;
    if (qrow < SS) {
      const float* qp = Qm + ((size_t)(b * SS + qrow)) * EE + h * DHH + l4 * 8;
      float4 a = *(const float4*)qp;
      float4 c = *(const float4*)(qp + 4);
      qb_[0] = f2b(a.x); qb_[1] = f2b(a.y); qb_[2] = f2b(a.z); qb_[3] = f2b(a.w);
      qb_[4] = f2b(c.x); qb_[5] = f2b(c.y); qb_[6] = f2b(c.z); qb_[7] = f2b(c.w);
    }
#pragma unroll
    for (int i = 0; i < 8; ++i) qf[i] = (short)qb_[i];
  }

  float mrun[4] = {-INFINITY, -INFINITY, -INFINITY, -INFINITY};
  float lrun[4] = {0.f, 0.f, 0.f, 0.f};
  f32x4 Oacc[2];
  Oacc[0] = (f32x4){0.f, 0.f, 0.f, 0.f};
  Oacc[1] = (f32x4){0.f, 0.f, 0.f, 0.f};

  for (int k0 = 0; k0 < SS; k0 += 64) {
    int kn = SS - k0; if (kn > 64) kn = 64;
    __syncthreads();
    {
      int row = tid >> 3, kg = tid & 7;
#pragma unroll
      for (int rr = 0; rr < 2; ++rr) {
        int r2 = row + rr * 32;
        float4 kv = make_float4(0.f, 0.f, 0.f, 0.f);
        if (r2 < kn)
          kv = *(const float4*)(Km + ((size_t)(b * SS + k0 + r2)) * EE + h * DHH + kg * 4);
        *(ushort4*)(&Ks[r2][kg * 4]) = make_ushort4(f2b(kv.x), f2b(kv.y), f2b(kv.z), f2b(kv.w));
      }
    }
    {
      int d = tid & 31, kb = tid >> 5;
      unsigned short uu[8];
#pragma unroll
      for (int i = 0; i < 8; ++i) {
        int kv = kb * 8 + i;
        float vv2 = (kv < kn) ? Vm[((size_t)(b * SS + k0 + kv)) * EE + h * DHH + d] : 0.f;
        uu[i] = f2b(vv2);
      }
      *(ushort4*)(&Vt[d][kb * 8])     = make_ushort4(uu[0], uu[1], uu[2], uu[3]);
      *(ushort4*)(&Vt[d][kb * 8 + 4]) = make_ushort4(uu[4], uu[5], uu[6], uu[7]);
    }
    __syncthreads();

    f32x4 sa[4];
#pragma unroll
    for (int nf = 0; nf < 4; ++nf) {
      short8 kf = *(const short8*)(&Ks[nf * 16 + l15][l4 * 8]);
      f32x4 zz = (f32x4){0.f, 0.f, 0.f, 0.f};
      sa[nf] = __builtin_amdgcn_mfma_f32_16x16x32_bf16(qf, kf, zz, 0, 0, 0);
    }
#pragma unroll
    for (int nf = 0; nf < 4; ++nf) {
      bool valid = (nf * 16 + l15) < kn;
#pragma unroll
      for (int r = 0; r < 4; ++r)
        sa[nf][r] = valid ? sa[nf][r] * scale : -INFINITY;
    }
    float pv[4][4];
#pragma unroll
    for (int r = 0; r < 4; ++r) {
      float tmax = fmaxf(fmaxf(sa[0][r], sa[1][r]), fmaxf(sa[2][r], sa[3][r]));
#pragma unroll
      for (int m = 1; m < 16; m <<= 1) tmax = fmaxf(tmax, __shfl_xor(tmax, m, 64));
      float mnew = fmaxf(mrun[r], tmax);
      float fac = expf(mrun[r] - mnew);
      float rsum = 0.f;
#pragma unroll
      for (int nf = 0; nf < 4; ++nf) {
        float p = expf(sa[nf][r] - mnew);
        pv[nf][r] = p;
        rsum += p;
      }
#pragma unroll
      for (int m = 1; m < 16; m <<= 1) rsum += __shfl_xor(rsum, m, 64);
      lrun[r] = lrun[r] * fac + rsum;
      mrun[r] = mnew;
      Oacc[0][r] *= fac;
      Oacc[1][r] *= fac;
    }
#pragma unroll
    for (int nf = 0; nf < 4; ++nf)
#pragma unroll
      for (int r = 0; r < 4; ++r)
        Pw[wave][l4 * 4 + r][nf * 16 + l15] = f2b(pv[nf][r]);
    asm volatile("s_waitcnt lgkmcnt(0)" ::: "memory");
    __builtin_amdgcn_sched_barrier(0);
#pragma unroll
    for (int ka = 0; ka < 2; ++ka) {
      short8 pa = *(const short8*)(&Pw[wave][l15][ka * 32 + l4 * 8]);
#pragma unroll
      for (int df = 0; df < 2; ++df) {
        short8 vf = *(const short8*)(&Vt[df * 16 + l15][ka * 32 + l4 * 8]);
        Oacc[df] = __builtin_amdgcn_mfma_f32_16x16x32_bf16(pa, vf, Oacc[df], 0, 0, 0);
      }
    }
  }
#pragma unroll
  for (int df = 0; df < 2; ++df)
#pragma unroll
    for (int r = 0; r < 4; ++r) {
      int qrow = q0 + l4 * 4 + r;
      if (qrow < SS)
        Om[((size_t)(b * SS + qrow)) * EE + h * DHH + df * 16 + l15] = Oacc[df][r] / lrun[r];
    }
}

// ---------------------------------------------------------------------------
// x = LN(x + t), one row per block
// ---------------------------------------------------------------------------
__global__ __launch_bounds__(256) void addln_kernel(
    float* __restrict__ X, const float* __restrict__ T,
    const float* __restrict__ g, const float* __restrict__ be)
{
  const int row = blockIdx.x, tid = threadIdx.x;
  __shared__ float red[256];
  float v = X[(size_t)row * EE + tid] + T[(size_t)row * EE + tid];
  red[tid] = v; __syncthreads();
  for (int w = 128; w > 0; w >>= 1) { if (tid < w) red[tid] += red[tid + w]; __syncthreads(); }
  float mean = red[0] * (1.f / EE);
  __syncthreads();
  float d = v - mean;
  red[tid] = d * d; __syncthreads();
  for (int w = 128; w > 0; w >>= 1) { if (tid < w) red[tid] += red[tid + w]; __syncthreads(); }
  float var = red[0] * (1.f / EE);
  X[(size_t)row * EE + tid] = d * rsqrtf(var + 1e-5f) * g[tid] + be[tid];
}

// ---------------------------------------------------------------------------
// Attention-weighted pooling + LN + classifier; one batch per block
// ---------------------------------------------------------------------------
__global__ __launch_bounds__(256) void final_kernel(
    const float* __restrict__ X, const float* __restrict__ g, const float* __restrict__ be,
    const float* __restrict__ w1, const float* __restrict__ b1,
    const float* __restrict__ w2, const float* __restrict__ b2,
    float* __restrict__ out)
{
  const int b = blockIdx.x, tid = threadIdx.x;
  __shared__ float rs[SS];
  __shared__ float red[256];
  __shared__ float pooled[EE];
  __shared__ float h[128];
  for (int s = tid; s < SS; s += 256) {
    const float* xr = X + ((size_t)(b * SS + s)) * EE;
    float a = 0.f;
    for (int e = 0; e < EE; ++e) a += xr[e];
    rs[s] = a;
  }
  __syncthreads();
  float mx = -INFINITY;
  for (int s = tid; s < SS; s += 256) mx = fmaxf(mx, rs[s]);
  red[tid] = mx; __syncthreads();
  for (int w = 128; w > 0; w >>= 1) { if (tid < w) red[tid] = fmaxf(red[tid], red[tid + w]); __syncthreads(); }
  mx = red[0]; __syncthreads();
  float sme = 0.f;
  for (int s = tid; s < SS; s += 256) { float e2 = expf(rs[s] - mx); rs[s] = e2; sme += e2; }
  red[tid] = sme; __syncthreads();
  for (int w = 128; w > 0; w >>= 1) { if (tid < w) red[tid] += red[tid + w]; __syncthreads(); }
  float tot = red[0]; __syncthreads();
  float acc = 0.f;
  for (int s = 0; s < SS; ++s) acc += X[((size_t)(b * SS + s)) * EE + tid] * rs[s];
  acc /= tot;
  red[tid] = acc; __syncthreads();
  for (int w = 128; w > 0; w >>= 1) { if (tid < w) red[tid] += red[tid + w]; __syncthreads(); }
  float mean = red[0] * (1.f / EE); __syncthreads();
  float d = acc - mean;
  red[tid] = d * d; __syncthreads();
  for (int w = 128; w > 0; w >>= 1) { if (tid < w) red[tid] += red[tid + w]; __syncthreads(); }
  float var = red[0] * (1.f / EE);
  pooled[tid] = d * rsqrtf(var + 1e-5f) * g[tid] + be[tid];
  __syncthreads();
  if (tid < 128) {
    const float* w = w1 + (size_t)tid * EE;
    float a = b1[tid];
    for (int e = 0; e < EE; ++e) a += w[e] * pooled[e];
    h[tid] = fmaxf(a, 0.f);
  }
  __syncthreads();
  if (tid < 2) {
    const float* w = w2 + (size_t)tid * 128;
    float a = b2[tid];
    for (int j = 0; j < 128; ++j) a += w[j] * h[j];
    out[b * 2 + tid] = a;
  }
}

// ---------------------------------------------------------------------------
extern "C" void kernel_launch(void* const* d_in, const int* in_sizes, int n_in,
                              void* d_out, int out_size, void* d_ws, size_t ws_size,
                              hipStream_t stream) {
  (void)in_sizes; (void)n_in; (void)out_size; (void)ws_size;
  const float* seq    = (const float*)d_in[0];
  const float* ph_fw  = (const float*)d_in[1];
  const float* ph_db  = (const float*)d_in[2];
  const float* ph_law = (const float*)d_in[3];
  const float* ph_lab = (const float*)d_in[4];
  const float* emb_w1 = (const float*)d_in[5];
  const float* emb_b1 = (const float*)d_in[6];
  const float* emb_w2 = (const float*)d_in[7];
  const float* emb_b2 = (const float*)d_in[8];
  const float* eln_g  = (const float*)d_in[9];
  const float* eln_b  = (const float*)d_in[10];
  const float* pos    = (const float*)d_in[11];
  const float* qw     = (const float*)d_in[12];
  const float* qb     = (const float*)d_in[13];
  const float* kw     = (const float*)d_in[14];
  const float* kb     = (const float*)d_in[15];
  const float* vw     = (const float*)d_in[16];
  const float* vb     = (const float*)d_in[17];
  const float* pw1    = (const float*)d_in[18];
  const float* pb1    = (const float*)d_in[19];
  const float* pw2    = (const float*)d_in[20];
  const float* pb2    = (const float*)d_in[21];
  const float* ow     = (const float*)d_in[22];
  const float* obv    = (const float*)d_in[23];
  const float* lng    = (const float*)d_in[24];
  const float* lnb    = (const float*)d_in[25];
  const float* fw1    = (const float*)d_in[26];
  const float* fb1    = (const float*)d_in[27];
  const float* fw2    = (const float*)d_in[28];
  const float* fb2    = (const float*)d_in[29];
  const float* clng   = (const float*)d_in[30];
  const float* clnb   = (const float*)d_in[31];
  const float* cw1    = (const float*)d_in[32];
  const float* cb1    = (const float*)d_in[33];
  const float* cw2    = (const float*)d_in[34];
  const float* cb2    = (const float*)d_in[35];

  float* ws  = (float*)d_ws;
  float* pf  = ws;            // 24 floats
  float* tsv = ws + 32;       // 24 floats
  const size_t SL = (size_t)4096 * 256;
  float* X    = ws + 256;
  float* TMP  = X + SL;
  float* Qp   = TMP + SL;
  float* Kp   = Qp + SL;
  float* Vp   = Kp + SL;
  float* ATTp = Vp + SL;
  float* HIDp = ATTp + SL;    // 4*SL (4096 x 1024)
  const int M = BB * SS;      // 4000

  ph_kernel<<<BB, 256, 0, stream>>>(seq, ph_fw, ph_db, ph_law, ph_lab, pf);
  temp_kernel<<<LL * BB, 256, 0, stream>>>(pf, pw1, pb1, pw2, pb2, tsv);
  embed_kernel<<<M, 256, 0, stream>>>(seq, emb_w1, emb_b1, emb_w2, emb_b2, eln_g, eln_b, pos, X);

  const int GM = (M + 127) / 128;  // 32
  for (int l = 0; l < LL; ++l) {
    const size_t wo = (size_t)l * EE * EE;
    gemm3_mfma<0><<<dim3(GM, EE / 64, 3), 256, 0, stream>>>(
        X, qw + wo, kw + wo, vw + wo, qb + l * EE, kb + l * EE, vb + l * EE,
        Qp, Kp, Vp, M, EE, EE);
    attn_mfma<<<dim3(16, HH, BB), 256, 0, stream>>>(Qp, Kp, Vp, tsv, ATTp, l);
    gemm3_mfma<0><<<dim3(GM, EE / 64, 1), 256, 0, stream>>>(
        ATTp, ow + wo, ow + wo, ow + wo, obv + l * EE, obv + l * EE, obv + l * EE,
        TMP, TMP, TMP, M, EE, EE);
    addln_kernel<<<M, 256, 0, stream>>>(X, TMP, lng + l * EE, lnb + l * EE);
    gemm3_mfma<1><<<dim3(GM, FFD / 64, 1), 256, 0, stream>>>(
        X, fw1 + (size_t)l * FFD * EE, fw1 + (size_t)l * FFD * EE, fw1 + (size_t)l * FFD * EE,
        fb1 + (size_t)l * FFD, fb1 + (size_t)l * FFD, fb1 + (size_t)l * FFD,
        HIDp, HIDp, HIDp, M, FFD, EE);
    gemm3_mfma<0><<<dim3(GM, EE / 64, 1), 256, 0, stream>>>(
        HIDp, fw2 + (size_t)l * EE * FFD, fw2 + (size_t)l * EE * FFD, fw2 + (size_t)l * EE * FFD,
        fb2 + l * EE, fb2 + l * EE, fb2 + l * EE,
        TMP, TMP, TMP, M, EE, FFD);
    addln_kernel<<<M, 256, 0, stream>>>(X, TMP, lng + l * EE, lnb + l * EE);
  }

  final_kernel<<<BB, 256, 0, stream>>>(X, clng, clnb, cw1, cb1, cw2, cb2, (float*)d_out);
}

// Round 4
// 1778.442 us; speedup vs baseline: 1.8535x; 1.0412x over previous
//
#include <hip/hip_runtime.h>
#include <math.h>

constexpr int BB = 4;       // batch
constexpr int SS = 1000;    // seq len
constexpr int INDIM = 5;
constexpr int EE = 256;     // embed
constexpr int LL = 6;       // layers
constexpr int HH = 8;       // heads
constexpr int DHH = 32;     // head dim
constexpr int NLM = 50;     // landmarks
constexpr int FFD = 1024;   // ff hidden

typedef short short8 __attribute__((ext_vector_type(8)));
typedef float f32x4 __attribute__((ext_vector_type(4)));

__device__ inline unsigned short f2b(float f) {
  union { float f; unsigned u; } v; v.f = f;
  unsigned u = v.u;
  unsigned r = u + 0x7FFFu + ((u >> 16) & 1u);  // round-to-nearest-even
  return (unsigned short)(r >> 16);
}

__device__ inline double wred_sum(double v) {
#pragma unroll
  for (int m = 1; m < 64; m <<= 1) v += __shfl_xor(v, m, 64);
  return v;
}
__device__ inline double wred_min(double v) {
#pragma unroll
  for (int m = 1; m < 64; m <<= 1) v = fmin(v, __shfl_xor(v, m, 64));
  return v;
}
__device__ inline double wred_max(double v) {
#pragma unroll
  for (int m = 1; m < 64; m <<= 1) v = fmax(v, __shfl_xor(v, m, 64));
  return v;
}
__device__ inline int sgnbit(double x) {
  return (int)((unsigned long long)__double_as_longlong(x) >> 63);
}

// ---------------------------------------------------------------------------
// Fused [ph (blocks 0..3)  ||  embed (blocks 4..4003)] kernel.
// ph: top-50 landmarks (u64-key bitonic) -> f64 Laplacian -> single-wave
// Householder tridiag -> per-lane division-free Sturm TRIsection (2 probes /
// iter, mul-only recurrence w/ exponent renorm) -> inverse iteration +
// reflector back-transform for the Fiedler vector.
// ---------------------------------------------------------------------------
struct PhEig {
  double matA[NLM][51];     // stride 51 doubles -> 4-way bank aliasing max
  double vv[64], ww[64];
  double dar[NLM], ear[NLM], e2a[NLM], tauA[NLM], evs[NLM], fied[NLM];
  double gdl[NLM], gdd[NLM], gdu[NLM], gdu2[NLM], gz[NLM];
};
struct PhS {
  union {
    unsigned long long keys[1024];   // sort phase
    PhEig e;                         // eig phase (after landmarks extracted)
  } u;
  float sm[SS];
  float lx[NLM], ly[NLM];
};
struct EmS { float sv[INDIM]; float h[128]; float red[256]; };
union FusedS { PhS ph; EmS em; };

__global__ __launch_bounds__(256) void phembed_kernel(
    const float* __restrict__ seq, const float* __restrict__ ph_fw,
    const float* __restrict__ ph_db, const float* __restrict__ ph_law,
    const float* __restrict__ ph_lab, float* __restrict__ pf,
    const float* __restrict__ ew1, const float* __restrict__ eb1,
    const float* __restrict__ ew2, const float* __restrict__ eb2,
    const float* __restrict__ eg, const float* __restrict__ ebe,
    const float* __restrict__ pos, float* __restrict__ X)
{
  __shared__ FusedS S;
  const int tid = threadIdx.x;

  if (blockIdx.x < BB) {
    // ================= ph path =================
    const int b = blockIdx.x;
    PhS& P = S.ph;
    const float law0 = ph_law[0], law1 = ph_law[1], labv = ph_lab[0];
    for (int s = tid; s < 1024; s += 256) {
      unsigned long long key;
      if (s < SS) {
        const float* p = seq + ((size_t)b * SS + s) * INDIM;
        float m = (p[0] + p[1] + p[2] + p[3] + p[4]) * 0.2f;
        P.sm[s] = m;
        float sc = (float)s * law0 + m * law1 + labv;
        unsigned u = __float_as_uint(sc);
        unsigned asc = (u & 0x80000000u) ? ~u : (u | 0x80000000u);
        key = ((unsigned long long)(~asc) << 32) | (unsigned)s;
      } else {
        key = (0xFFFFFFFFull << 32) | (unsigned)s;
      }
      P.u.keys[s] = key;
    }
    __syncthreads();
    // bitonic ascending on u64 keys == descending score, ties ascending idx
    for (int k = 2; k <= 1024; k <<= 1) {
      for (int j = k >> 1; j > 0; j >>= 1) {
        for (int i = tid; i < 1024; i += 256) {
          int ixj = i ^ j;
          if (ixj > i) {
            unsigned long long a = P.u.keys[i], c = P.u.keys[ixj];
            bool up = ((i & k) == 0);
            if ((a > c) == up) { P.u.keys[i] = c; P.u.keys[ixj] = a; }
          }
        }
        __syncthreads();
      }
    }
    if (tid < NLM) {
      int id = (int)(P.u.keys[tid] & 0xFFFFFFFFull);
      P.lx[tid] = (float)id;
      P.ly[tid] = P.sm[id];
    }
    __syncthreads();   // orders key reads before matA overwrites the union
    PhEig& E = P.u.e;
    const float fwv = fabsf(ph_fw[0]);
    const float dbv = ph_db[0];
    for (int t = tid; t < NLM * NLM; t += 256) {
      int i = t / NLM, j = t % NLM;
      float dx = P.lx[i] - P.lx[j], dy = P.ly[i] - P.ly[j];
      float d2 = dx * dx + dy * dy;
      float dist = (d2 > 0.f) ? sqrtf(d2) : 0.f;
      float Kv = expf(-(dist * fwv + dbv));
      E.matA[i][j] = -(double)Kv;
    }
    __syncthreads();
    if (tid < NLM) {
      double rsum = 0.0;
      for (int j = 0; j < NLM; ++j) rsum -= E.matA[tid][j];
      E.matA[tid][tid] += rsum;  // exact f64 cancellation -> lambda0 ~ 1e-15
    }
    __syncthreads();

    if (tid >= 64) return;  // wave 0 runs the eigensolve barrier-free
    const int lane = tid;

    // ---- Householder tridiagonalization ----
    for (int k = 0; k <= NLM - 3; ++k) {
      const int m = NLM - 1 - k;
      const int r = k + 1 + lane;
      double x = (lane < m) ? E.matA[r][k] : 0.0;
      double x0 = __shfl(x, 0, 64);
      double sigma = wred_sum((lane >= 1 && lane < m) ? x * x : 0.0);
      double beta, tau, scale;
      if (sigma == 0.0) { beta = x0; tau = 0.0; scale = 0.0; }
      else {
        double nrm = sqrt(x0 * x0 + sigma);
        beta = (x0 >= 0.0) ? -nrm : nrm;
        tau = (beta - x0) / beta;
        scale = 1.0 / (x0 - beta);
      }
      double v = (lane == 0) ? 1.0 : x * scale;
      if (lane < m) { E.vv[lane] = v; E.matA[r][k] = v; }
      if (lane == 0) { E.ear[k] = beta; E.tauA[k] = tau; }
      __builtin_amdgcn_wave_barrier();
      // p = tau * A v  (4-way split accumulators break the FMA chain)
      double p = 0.0;
      if (lane < m) {
        const double* Ar = &E.matA[r][k + 1];
        double a0 = 0.0, a1 = 0.0, a2 = 0.0, a3 = 0.0;
        int j = 0;
        for (; j + 3 < m; j += 4) {
          a0 += Ar[j] * E.vv[j];
          a1 += Ar[j + 1] * E.vv[j + 1];
          a2 += Ar[j + 2] * E.vv[j + 2];
          a3 += Ar[j + 3] * E.vv[j + 3];
        }
        for (; j < m; ++j) a0 += Ar[j] * E.vv[j];
        p = ((a0 + a1) + (a2 + a3)) * tau;
      }
      double dotvp = wred_sum((lane < m) ? v * p : 0.0);
      double w = p - 0.5 * tau * dotvp * v;
      if (lane < m) E.ww[lane] = w;
      __builtin_amdgcn_wave_barrier();
      if (lane < m) {
        double* Ar = &E.matA[r][k + 1];
        for (int j = 0; j < m; ++j) Ar[j] -= v * E.ww[j] + w * E.vv[j];
      }
      __builtin_amdgcn_wave_barrier();
    }
    if (lane < NLM) E.dar[lane] = E.matA[lane][lane];
    if (lane == 0) E.ear[NLM - 2] = E.matA[NLM - 1][NLM - 2];
    __builtin_amdgcn_wave_barrier();
    if (lane < NLM - 1) E.e2a[lane] = E.ear[lane] * E.ear[lane];
    __builtin_amdgcn_wave_barrier();

    // ---- Gershgorin bounds ----
    double lo_i = 1e300, hi_i = -1e300;
    if (lane < NLM) {
      double rl = (lane > 0) ? fabs(E.ear[lane - 1]) : 0.0;
      double rr = (lane < NLM - 1) ? fabs(E.ear[lane]) : 0.0;
      lo_i = E.dar[lane] - rl - rr;
      hi_i = E.dar[lane] + rl + rr;
    }
    double glo = wred_min(lo_i), ghi = wred_max(hi_i);

    // ---- trisection, division-free Sturm, 2 probes/iter, lane k -> k-th ev ----
    if (lane < NLM) {
      double lo = glo, hi = ghi;
      const int need = lane + 1;
      for (int it = 0; it < 32; ++it) {
        double third = (hi - lo) * (1.0 / 3.0);
        double x1 = lo + third, x2 = hi - third;
        double pA = E.dar[0] - x1, pB = E.dar[0] - x2;
        double qA = 1.0, qB = 1.0;
        int c1 = sgnbit(pA), c2 = sgnbit(pB);
        for (int i = 1; i < NLM; ++i) {
          double di = E.dar[i], ei = E.e2a[i - 1];
          double nA = (di - x1) * pA - ei * qA;
          double nB = (di - x2) * pB - ei * qB;
          if (nA == 0.0) nA = sgnbit(pA) ? -1e-300 : 1e-300;
          if (nB == 0.0) nB = sgnbit(pB) ? -1e-300 : 1e-300;
          c1 += (sgnbit(nA) != sgnbit(pA));
          c2 += (sgnbit(nB) != sgnbit(pB));
          // renorm both chain vars by 2^-E(max|.|) via bit ops (no division)
          long long aa = __double_as_longlong(nA) & 0x7fffffffffffffffLL;
          long long ap = __double_as_longlong(pA) & 0x7fffffffffffffffLL;
          int Ea = (int)((aa > ap ? aa : ap) >> 52);
          int sea = 2046 - Ea; sea = sea < 1 ? 1 : (sea > 2045 ? 2045 : sea);
          double sA = __longlong_as_double((long long)sea << 52);
          qA = pA * sA; pA = nA * sA;
          long long ab = __double_as_longlong(nB) & 0x7fffffffffffffffLL;
          long long ab2 = __double_as_longlong(pB) & 0x7fffffffffffffffLL;
          int Eb = (int)((ab > ab2 ? ab : ab2) >> 52);
          int seb = 2046 - Eb; seb = seb < 1 ? 1 : (seb > 2045 ? 2045 : seb);
          double sB = __longlong_as_double((long long)seb << 52);
          qB = pB * sB; pB = nB * sB;
        }
        if (c1 >= need) hi = x1;
        else if (c2 >= need) { lo = x1; hi = x2; }
        else lo = x2;
      }
      E.evs[lane] = 0.5 * (lo + hi);
    }
    __builtin_amdgcn_wave_barrier();

    // ---- Fiedler vector: inverse iteration on tridiagonal (lane 0 serial) ----
    if (lane == 0) {
      double shift = E.evs[1];
      unsigned rs = 12345u;
      for (int i = 0; i < NLM; ++i) {
        rs = rs * 1103515245u + 12345u;
        E.gz[i] = ((double)((rs >> 8) & 0xFFFF)) / 65536.0 - 0.5;
      }
      for (int iter = 0; iter < 2; ++iter) {
        for (int i = 0; i < NLM; ++i) E.gdd[i] = E.dar[i] - shift;
        for (int i = 0; i < NLM - 1; ++i) { E.gdl[i] = E.ear[i]; E.gdu[i] = E.ear[i]; }
        for (int i = 0; i < NLM - 1; ++i) {
          if (fabs(E.gdd[i]) >= fabs(E.gdl[i])) {
            if (E.gdd[i] == 0.0) E.gdd[i] = 1e-280;
            double fact = E.gdl[i] / E.gdd[i];
            E.gdd[i + 1] -= fact * E.gdu[i];
            E.gz[i + 1] -= fact * E.gz[i];
            if (i < NLM - 2) E.gdu2[i] = 0.0;
          } else {
            double fact = E.gdd[i] / E.gdl[i];
            E.gdd[i] = E.gdl[i];
            double tmp = E.gdd[i + 1];
            E.gdd[i + 1] = E.gdu[i] - fact * tmp;
            if (i < NLM - 2) { E.gdu2[i] = E.gdu[i + 1]; E.gdu[i + 1] = -fact * E.gdu2[i]; }
            E.gdu[i] = tmp;
            double tz = E.gz[i]; E.gz[i] = E.gz[i + 1]; E.gz[i + 1] = tz - fact * E.gz[i];
          }
        }
        if (E.gdd[NLM - 1] == 0.0) E.gdd[NLM - 1] = 1e-280;
        E.gz[NLM - 1] /= E.gdd[NLM - 1];
        E.gz[NLM - 2] = (E.gz[NLM - 2] - E.gdu[NLM - 2] * E.gz[NLM - 1]) / E.gdd[NLM - 2];
        for (int i = NLM - 3; i >= 0; --i)
          E.gz[i] = (E.gz[i] - E.gdu[i] * E.gz[i + 1] - E.gdu2[i] * E.gz[i + 2]) / E.gdd[i];
        double nr = 0.0;
        for (int i = 0; i < NLM; ++i) nr += E.gz[i] * E.gz[i];
        nr = sqrt(nr);
        for (int i = 0; i < NLM; ++i) E.gz[i] /= nr;
      }
    }
    __builtin_amdgcn_wave_barrier();
    if (lane < NLM) E.fied[lane] = E.gz[lane];
    __builtin_amdgcn_wave_barrier();
    for (int k = NLM - 3; k >= 0; --k) {
      const int m = NLM - 1 - k;
      double v = 0.0, xi = 0.0;
      if (lane < m) { v = E.matA[k + 1 + lane][k]; xi = E.fied[k + 1 + lane]; }
      double dot = wred_sum(v * xi);
      double t = E.tauA[k];
      if (lane < m) E.fied[k + 1 + lane] = xi - t * dot * v;
      __builtin_amdgcn_wave_barrier();
    }

    if (lane == 0) {
      double n0 = 0.0, s0 = 0.0;
      for (int i = 0; i < NLM; ++i)
        if (E.evs[i] < 1e-6) { n0 += 1.0; s0 += fabs(E.evs[i]); }
      double gap = E.evs[1] - E.evs[0];
      double mean = 0.0;
      for (int i = 0; i < NLM; ++i) mean += E.fied[i];
      mean /= NLM;
      double var = 0.0;
      for (int i = 0; i < NLM; ++i) { double d = E.fied[i] - mean; var += d * d; }
      var /= (NLM - 1);
      double m4 = (E.evs[2] + E.evs[3] + E.evs[4] + E.evs[5]) * 0.25;
      double v4 = 0.0;
      for (int i = 2; i < 6; ++i) { double d = E.evs[i] - m4; v4 += d * d; }
      v4 /= 3.0;
      float* o = pf + b * 6;
      o[0] = (float)n0;
      o[1] = (float)s0;
      o[2] = (float)gap;
      o[3] = (float)sqrt(var);
      o[4] = (float)m4;
      o[5] = (float)sqrt(v4);
    }
    return;
  }

  // ================= embed path =================
  const int row = blockIdx.x - BB;
  const int s = row % SS;
  EmS& M2 = S.em;
  if (tid < INDIM) M2.sv[tid] = seq[(size_t)row * INDIM + tid];
  __syncthreads();
  if (tid < 128) {
    const float* w = ew1 + tid * INDIM;
    float a = eb1[tid];
#pragma unroll
    for (int i = 0; i < INDIM; ++i) a += w[i] * M2.sv[i];
    M2.h[tid] = fmaxf(a, 0.f);
  }
  __syncthreads();
  const float* w = ew2 + (size_t)tid * 128;
  float a = eb2[tid];
  for (int i = 0; i < 128; ++i) a += w[i] * M2.h[i];
  M2.red[tid] = a; __syncthreads();
  for (int wd = 128; wd > 0; wd >>= 1) { if (tid < wd) M2.red[tid] += M2.red[tid + wd]; __syncthreads(); }
  float mean = M2.red[0] * (1.f / EE);
  __syncthreads();
  float d = a - mean;
  M2.red[tid] = d * d; __syncthreads();
  for (int wd = 128; wd > 0; wd >>= 1) { if (tid < wd) M2.red[tid] += M2.red[tid + wd]; __syncthreads(); }
  float var = M2.red[0] * (1.f / EE);
  X[(size_t)row * EE + tid] = d * rsqrtf(var + 1e-5f) * eg[tid] + ebe[tid] + pos[(size_t)s * EE + tid];
}

// ---------------------------------------------------------------------------
// Per-(layer,batch) scalar attention temperature
// ---------------------------------------------------------------------------
__global__ __launch_bounds__(256) void temp_kernel(
    const float* __restrict__ pf, const float* __restrict__ w1, const float* __restrict__ b1,
    const float* __restrict__ w2, const float* __restrict__ b2, float* __restrict__ ts)
{
  const int l = blockIdx.x / BB, b = blockIdx.x % BB, tid = threadIdx.x;
  __shared__ float pfl[6];
  __shared__ float h[128];
  __shared__ float red[256];
  if (tid < 6) pfl[tid] = pf[b * 6 + tid];
  __syncthreads();
  if (tid < 128) {
    const float* w = w1 + ((size_t)l * 128 + tid) * 6;
    float a = b1[(size_t)l * 128 + tid];
#pragma unroll
    for (int i = 0; i < 6; ++i) a += w[i] * pfl[i];
    h[tid] = fmaxf(a, 0.f);
  }
  __syncthreads();
  const float* w = w2 + ((size_t)l * EE + tid) * 128;
  float a = b2[(size_t)l * EE + tid];
  for (int i = 0; i < 128; ++i) a += w[i] * h[i];
  float sg = 1.f / (1.f + expf(-a));
  red[tid] = sg; __syncthreads();
  for (int wd = 128; wd > 0; wd >>= 1) { if (tid < wd) red[tid] += red[tid + wd]; __syncthreads(); }
  if (tid == 0) ts[l * BB + b] = red[0] * (1.f / EE);
}

// ---------------------------------------------------------------------------
// bf16 MFMA GEMM: C = A[MxK] @ W[NxK]^T + bias (f32 in/out, bf16 compute).
// Tile 128x64xBK32, 4 waves (2x2), per-wave 64x32 via 16x16x32 MFMA.
// ---------------------------------------------------------------------------
template <int ACT>
__global__ __launch_bounds__(256) void gemm3_mfma(
    const float* __restrict__ Ain,
    const float* __restrict__ W0, const float* __restrict__ W1, const float* __restrict__ W2,
    const float* __restrict__ bb0, const float* __restrict__ bb1, const float* __restrict__ bb2,
    float* __restrict__ C0, float* __restrict__ C1, float* __restrict__ C2,
    int M, int N, int K)
{
  const int z = blockIdx.z;
  const float* W = (z == 0) ? W0 : (z == 1) ? W1 : W2;
  const float* bias = (z == 0) ? bb0 : (z == 1) ? bb1 : bb2;
  float* C = (z == 0) ? C0 : (z == 1) ? C1 : C2;
  __shared__ __align__(16) unsigned short As[128][40];
  __shared__ __align__(16) unsigned short Bs[64][40];
  const int m0 = blockIdx.x * 128, n0 = blockIdx.y * 64;
  const int tid = threadIdx.x;
  const int lane = tid & 63, wave = tid >> 6;
  const int wm = wave >> 1, wn = wave & 1;
  const int l15 = lane & 15, l4 = lane >> 4;
  const int srow = tid >> 3, skg = tid & 7;

  f32x4 acc[4][2];
#pragma unroll
  for (int mf = 0; mf < 4; ++mf)
#pragma unroll
    for (int nf = 0; nf < 2; ++nf) acc[mf][nf] = (f32x4){0.f, 0.f, 0.f, 0.f};

  for (int k0 = 0; k0 < K; k0 += 32) {
    __syncthreads();
#pragma unroll
    for (int rr = 0; rr < 4; ++rr) {
      int row = srow + rr * 32;
      float4 av = *(const float4*)(Ain + (size_t)(m0 + row) * K + k0 + skg * 4);
      *(ushort4*)(&As[row][skg * 4]) = make_ushort4(f2b(av.x), f2b(av.y), f2b(av.z), f2b(av.w));
    }
#pragma unroll
    for (int rr = 0; rr < 2; ++rr) {
      int row = srow + rr * 32;
      if (row < 64) {
        float4 wv = *(const float4*)(W + (size_t)(n0 + row) * K + k0 + skg * 4);
        *(ushort4*)(&Bs[row][skg * 4]) = make_ushort4(f2b(wv.x), f2b(wv.y), f2b(wv.z), f2b(wv.w));
      }
    }
    __syncthreads();
    short8 bf[2];
#pragma unroll
    for (int nf = 0; nf < 2; ++nf)
      bf[nf] = *(const short8*)(&Bs[wn * 32 + nf * 16 + l15][l4 * 8]);
#pragma unroll
    for (int mf = 0; mf < 4; ++mf) {
      short8 af = *(const short8*)(&As[wm * 64 + mf * 16 + l15][l4 * 8]);
#pragma unroll
      for (int nf = 0; nf < 2; ++nf)
        acc[mf][nf] = __builtin_amdgcn_mfma_f32_16x16x32_bf16(af, bf[nf], acc[mf][nf], 0, 0, 0);
    }
  }
#pragma unroll
  for (int nf = 0; nf < 2; ++nf) {
    int col = n0 + wn * 32 + nf * 16 + l15;
    float bv = bias[col];
#pragma unroll
    for (int mf = 0; mf < 4; ++mf) {
#pragma unroll
      for (int r = 0; r < 4; ++r) {
        int row = m0 + wm * 64 + mf * 16 + l4 * 4 + r;
        if (row < M) {
          float v = acc[mf][nf][r] + bv;
          if (ACT == 1) v = 0.5f * v * (1.f + erff(v * 0.70710678118654752440f));
          C[(size_t)row * N + col] = v;
        }
      }
    }
  }
}

// ---------------------------------------------------------------------------
// bf16 MFMA flash attention, per-sample scalar temperature.
// ---------------------------------------------------------------------------
__global__ __launch_bounds__(256) void attn_mfma(
    const float* __restrict__ Qm, const float* __restrict__ Km, const float* __restrict__ Vm,
    const float* __restrict__ ts, float* __restrict__ Om, int l)
{
  const int qt = blockIdx.x, h = blockIdx.y, b = blockIdx.z;
  const int tid = threadIdx.x;
  const int lane = tid & 63, wave = tid >> 6;
  const int l15 = lane & 15, l4 = lane >> 4;
  const float scale = ts[l * BB + b] * 0.17677669529663688110f;  // ts / sqrt(32)
  __shared__ __align__(16) unsigned short Ks[64][40];
  __shared__ __align__(16) unsigned short Vt[32][72];
  __shared__ __align__(16) unsigned short Pw[4][16][72];
  const int q0 = qt * 64 + wave * 16;

  short8 qf;
  {
    unsigned short qb_[8] = {0, 0, 0, 0, 0, 0, 0, 0};
    int qrow = q0 + l15;
    if (qrow < SS) {
      const float* qp = Qm + ((size_t)(b * SS + qrow)) * EE + h * DHH + l4 * 8;
      float4 a = *(const float4*)qp;
      float4 c = *(const float4*)(qp + 4);
      qb_[0] = f2b(a.x); qb_[1] = f2b(a.y); qb_[2] = f2b(a.z); qb_[3] = f2b(a.w);
      qb_[4] = f2b(c.x); qb_[5] = f2b(c.y); qb_[6] = f2b(c.z); qb_[7] = f2b(c.w);
    }
#pragma unroll
    for (int i = 0; i < 8; ++i) qf[i] = (short)qb_[i];
  }

  float mrun[4] = {-INFINITY, -INFINITY, -INFINITY, -INFINITY};
  float lrun[4] = {0.f, 0.f, 0.f, 0.f};
  f32x4 Oacc[2];
  Oacc[0] = (f32x4){0.f, 0.f, 0.f, 0.f};
  Oacc[1] = (f32x4){0.f, 0.f, 0.f, 0.f};

  for (int k0 = 0; k0 < SS; k0 += 64) {
    int kn = SS - k0; if (kn > 64) kn = 64;
    __syncthreads();
    {
      int row = tid >> 3, kg = tid & 7;
#pragma unroll
      for (int rr = 0; rr < 2; ++rr) {
        int r2 = row + rr * 32;
        float4 kv = make_float4(0.f, 0.f, 0.f, 0.f);
        if (r2 < kn)
          kv = *(const float4*)(Km + ((size_t)(b * SS + k0 + r2)) * EE + h * DHH + kg * 4);
        *(ushort4*)(&Ks[r2][kg * 4]) = make_ushort4(f2b(kv.x), f2b(kv.y), f2b(kv.z), f2b(kv.w));
      }
    }
    {
      int d = tid & 31, kb = tid >> 5;
      unsigned short uu[8];
#pragma unroll
      for (int i = 0; i < 8; ++i) {
        int kv = kb * 8 + i;
        float vv2 = (kv < kn) ? Vm[((size_t)(b * SS + k0 + kv)) * EE + h * DHH + d] : 0.f;
        uu[i] = f2b(vv2);
      }
      *(ushort4*)(&Vt[d][kb * 8])     = make_ushort4(uu[0], uu[1], uu[2], uu[3]);
      *(ushort4*)(&Vt[d][kb * 8 + 4]) = make_ushort4(uu[4], uu[5], uu[6], uu[7]);
    }
    __syncthreads();

    f32x4 sa[4];
#pragma unroll
    for (int nf = 0; nf < 4; ++nf) {
      short8 kf = *(const short8*)(&Ks[nf * 16 + l15][l4 * 8]);
      f32x4 zz = (f32x4){0.f, 0.f, 0.f, 0.f};
      sa[nf] = __builtin_amdgcn_mfma_f32_16x16x32_bf16(qf, kf, zz, 0, 0, 0);
    }
#pragma unroll
    for (int nf = 0; nf < 4; ++nf) {
      bool valid = (nf * 16 + l15) < kn;
#pragma unroll
      for (int r = 0; r < 4; ++r)
        sa[nf][r] = valid ? sa[nf][r] * scale : -INFINITY;
    }
    float pv[4][4];
#pragma unroll
    for (int r = 0; r < 4; ++r) {
      float tmax = fmaxf(fmaxf(sa[0][r], sa[1][r]), fmaxf(sa[2][r], sa[3][r]));
#pragma unroll
      for (int m = 1; m < 16; m <<= 1) tmax = fmaxf(tmax, __shfl_xor(tmax, m, 64));
      float mnew = fmaxf(mrun[r], tmax);
      float fac = expf(mrun[r] - mnew);
      float rsum = 0.f;
#pragma unroll
      for (int nf = 0; nf < 4; ++nf) {
        float p = expf(sa[nf][r] - mnew);
        pv[nf][r] = p;
        rsum += p;
      }
#pragma unroll
      for (int m = 1; m < 16; m <<= 1) rsum += __shfl_xor(rsum, m, 64);
      lrun[r] = lrun[r] * fac + rsum;
      mrun[r] = mnew;
      Oacc[0][r] *= fac;
      Oacc[1][r] *= fac;
    }
#pragma unroll
    for (int nf = 0; nf < 4; ++nf)
#pragma unroll
      for (int r = 0; r < 4; ++r)
        Pw[wave][l4 * 4 + r][nf * 16 + l15] = f2b(pv[nf][r]);
    asm volatile("s_waitcnt lgkmcnt(0)" ::: "memory");
    __builtin_amdgcn_sched_barrier(0);
#pragma unroll
    for (int ka = 0; ka < 2; ++ka) {
      short8 pa = *(const short8*)(&Pw[wave][l15][ka * 32 + l4 * 8]);
#pragma unroll
      for (int df = 0; df < 2; ++df) {
        short8 vf = *(const short8*)(&Vt[df * 16 + l15][ka * 32 + l4 * 8]);
        Oacc[df] = __builtin_amdgcn_mfma_f32_16x16x32_bf16(pa, vf, Oacc[df], 0, 0, 0);
      }
    }
  }
#pragma unroll
  for (int df = 0; df < 2; ++df)
#pragma unroll
    for (int r = 0; r < 4; ++r) {
      int qrow = q0 + l4 * 4 + r;
      if (qrow < SS)
        Om[((size_t)(b * SS + qrow)) * EE + h * DHH + df * 16 + l15] = Oacc[df][r] / lrun[r];
    }
}

// ---------------------------------------------------------------------------
// x = LN(x + t), one row per block
// ---------------------------------------------------------------------------
__global__ __launch_bounds__(256) void addln_kernel(
    float* __restrict__ X, const float* __restrict__ T,
    const float* __restrict__ g, const float* __restrict__ be)
{
  const int row = blockIdx.x, tid = threadIdx.x;
  __shared__ float red[256];
  float v = X[(size_t)row * EE + tid] + T[(size_t)row * EE + tid];
  red[tid] = v; __syncthreads();
  for (int w = 128; w > 0; w >>= 1) { if (tid < w) red[tid] += red[tid + w]; __syncthreads(); }
  float mean = red[0] * (1.f / EE);
  __syncthreads();
  float d = v - mean;
  red[tid] = d * d; __syncthreads();
  for (int w = 128; w > 0; w >>= 1) { if (tid < w) red[tid] += red[tid + w]; __syncthreads(); }
  float var = red[0] * (1.f / EE);
  X[(size_t)row * EE + tid] = d * rsqrtf(var + 1e-5f) * g[tid] + be[tid];
}

// ---------------------------------------------------------------------------
// Attention-weighted pooling + LN + classifier; one batch per block
// ---------------------------------------------------------------------------
__global__ __launch_bounds__(256) void final_kernel(
    const float* __restrict__ X, const float* __restrict__ g, const float* __restrict__ be,
    const float* __restrict__ w1, const float* __restrict__ b1,
    const float* __restrict__ w2, const float* __restrict__ b2,
    float* __restrict__ out)
{
  const int b = blockIdx.x, tid = threadIdx.x;
  __shared__ float rs[SS];
  __shared__ float red[256];
  __shared__ float pooled[EE];
  __shared__ float h[128];
  for (int s = tid; s < SS; s += 256) {
    const float* xr = X + ((size_t)(b * SS + s)) * EE;
    float a = 0.f;
    for (int e = 0; e < EE; ++e) a += xr[e];
    rs[s] = a;
  }
  __syncthreads();
  float mx = -INFINITY;
  for (int s = tid; s < SS; s += 256) mx = fmaxf(mx, rs[s]);
  red[tid] = mx; __syncthreads();
  for (int w = 128; w > 0; w >>= 1) { if (tid < w) red[tid] = fmaxf(red[tid], red[tid + w]); __syncthreads(); }
  mx = red[0]; __syncthreads();
  float sme = 0.f;
  for (int s = tid; s < SS; s += 256) { float e2 = expf(rs[s] - mx); rs[s] = e2; sme += e2; }
  red[tid] = sme; __syncthreads();
  for (int w = 128; w > 0; w >>= 1) { if (tid < w) red[tid] += red[tid + w]; __syncthreads(); }
  float tot = red[0]; __syncthreads();
  float acc = 0.f;
  for (int s = 0; s < SS; ++s) acc += X[((size_t)(b * SS + s)) * EE + tid] * rs[s];
  acc /= tot;
  red[tid] = acc; __syncthreads();
  for (int w = 128; w > 0; w >>= 1) { if (tid < w) red[tid] += red[tid + w]; __syncthreads(); }
  float mean = red[0] * (1.f / EE); __syncthreads();
  float d = acc - mean;
  red[tid] = d * d; __syncthreads();
  for (int w = 128; w > 0; w >>= 1) { if (tid < w) red[tid] += red[tid + w]; __syncthreads(); }
  float var = red[0] * (1.f / EE);
  pooled[tid] = d * rsqrtf(var + 1e-5f) * g[tid] + be[tid];
  __syncthreads();
  if (tid < 128) {
    const float* w = w1 + (size_t)tid * EE;
    float a = b1[tid];
    for (int e = 0; e < EE; ++e) a += w[e] * pooled[e];
    h[tid] = fmaxf(a, 0.f);
  }
  __syncthreads();
  if (tid < 2) {
    const float* w = w2 + (size_t)tid * 128;
    float a = b2[tid];
    for (int j = 0; j < 128; ++j) a += w[j] * h[j];
    out[b * 2 + tid] = a;
  }
}

// ---------------------------------------------------------------------------
extern "C" void kernel_launch(void* const* d_in, const int* in_sizes, int n_in,
                              void* d_out, int out_size, void* d_ws, size_t ws_size,
                              hipStream_t stream) {
  (void)in_sizes; (void)n_in; (void)out_size; (void)ws_size;
  const float* seq    = (const float*)d_in[0];
  const float* ph_fw  = (const float*)d_in[1];
  const float* ph_db  = (const float*)d_in[2];
  const float* ph_law = (const float*)d_in[3];
  const float* ph_lab = (const float*)d_in[4];
  const float* emb_w1 = (const float*)d_in[5];
  const float* emb_b1 = (const float*)d_in[6];
  const float* emb_w2 = (const float*)d_in[7];
  const float* emb_b2 = (const float*)d_in[8];
  const float* eln_g  = (const float*)d_in[9];
  const float* eln_b  = (const float*)d_in[10];
  const float* pos    = (const float*)d_in[11];
  const float* qw     = (const float*)d_in[12];
  const float* qb     = (const float*)d_in[13];
  const float* kw     = (const float*)d_in[14];
  const float* kb     = (const float*)d_in[15];
  const float* vw     = (const float*)d_in[16];
  const float* vb     = (const float*)d_in[17];
  const float* pw1    = (const float*)d_in[18];
  const float* pb1    = (const float*)d_in[19];
  const float* pw2    = (const float*)d_in[20];
  const float* pb2    = (const float*)d_in[21];
  const float* ow     = (const float*)d_in[22];
  const float* obv    = (const float*)d_in[23];
  const float* lng    = (const float*)d_in[24];
  const float* lnb    = (const float*)d_in[25];
  const float* fw1    = (const float*)d_in[26];
  const float* fb1    = (const float*)d_in[27];
  const float* fw2    = (const float*)d_in[28];
  const float* fb2    = (const float*)d_in[29];
  const float* clng   = (const float*)d_in[30];
  const float* clnb   = (const float*)d_in[31];
  const float* cw1    = (const float*)d_in[32];
  const float* cb1    = (const float*)d_in[33];
  const float* cw2    = (const float*)d_in[34];
  const float* cb2    = (const float*)d_in[35];

  float* ws  = (float*)d_ws;
  float* pf  = ws;            // 24 floats
  float* tsv = ws + 32;       // 24 floats
  const size_t SL = (size_t)4096 * 256;
  float* X    = ws + 256;
  float* TMP  = X + SL;
  float* Qp   = TMP + SL;
  float* Kp   = Qp + SL;
  float* Vp   = Kp + SL;
  float* ATTp = Vp + SL;
  float* HIDp = ATTp + SL;    // 4*SL (4096 x 1024)
  const int M = BB * SS;      // 4000

  phembed_kernel<<<BB + M, 256, 0, stream>>>(
      seq, ph_fw, ph_db, ph_law, ph_lab, pf,
      emb_w1, emb_b1, emb_w2, emb_b2, eln_g, eln_b, pos, X);
  temp_kernel<<<LL * BB, 256, 0, stream>>>(pf, pw1, pb1, pw2, pb2, tsv);

  const int GM = (M + 127) / 128;  // 32
  for (int l = 0; l < LL; ++l) {
    const size_t wo = (size_t)l * EE * EE;
    gemm3_mfma<0><<<dim3(GM, EE / 64, 3), 256, 0, stream>>>(
        X, qw + wo, kw + wo, vw + wo, qb + l * EE, kb + l * EE, vb + l * EE,
        Qp, Kp, Vp, M, EE, EE);
    attn_mfma<<<dim3(16, HH, BB), 256, 0, stream>>>(Qp, Kp, Vp, tsv, ATTp, l);
    gemm3_mfma<0><<<dim3(GM, EE / 64, 1), 256, 0, stream>>>(
        ATTp, ow + wo, ow + wo, ow + wo, obv + l * EE, obv + l * EE, obv + l * EE,
        TMP, TMP, TMP, M, EE, EE);
    addln_kernel<<<M, 256, 0, stream>>>(X, TMP, lng + l * EE, lnb + l * EE);
    gemm3_mfma<1><<<dim3(GM, FFD / 64, 1), 256, 0, stream>>>(
        X, fw1 + (size_t)l * FFD * EE, fw1 + (size_t)l * FFD * EE, fw1 + (size_t)l * FFD * EE,
        fb1 + (size_t)l * FFD, fb1 + (size_t)l * FFD, fb1 + (size_t)l * FFD,
        HIDp, HIDp, HIDp, M, FFD, EE);
    gemm3_mfma<0><<<dim3(GM, EE / 64, 1), 256, 0, stream>>>(
        HIDp, fw2 + (size_t)l * EE * FFD, fw2 + (size_t)l * EE * FFD, fw2 + (size_t)l * EE * FFD,
        fb2 + l * EE, fb2 + l * EE, fb2 + l * EE,
        TMP, TMP, TMP, M, EE, FFD);
    addln_kernel<<<M, 256, 0, stream>>>(X, TMP, lng + l * EE, lnb + l * EE);
  }

  final_kernel<<<BB, 256, 0, stream>>>(X, clng, clnb, cw1, cb1, cw2, cb2, (float*)d_out);
}

// Round 5
// 1713.597 us; speedup vs baseline: 1.9236x; 1.0378x over previous
//
#include <hip/hip_runtime.h>
#include <math.h>

constexpr int BB = 4;       // batch
constexpr int SS = 1000;    // seq len
constexpr int INDIM = 5;
constexpr int EE = 256;     // embed
constexpr int LL = 6;       // layers
constexpr int HH = 8;       // heads
constexpr int DHH = 32;     // head dim
constexpr int NLM = 50;     // landmarks
constexpr int FFD = 1024;   // ff hidden

typedef short short8 __attribute__((ext_vector_type(8)));
typedef float f32x4 __attribute__((ext_vector_type(4)));

__device__ inline unsigned short f2b(float f) {
  union { float f; unsigned u; } v; v.f = f;
  unsigned u = v.u;
  unsigned r = u + 0x7FFFu + ((u >> 16) & 1u);  // round-to-nearest-even
  return (unsigned short)(r >> 16);
}

__device__ inline double wred_sum(double v) {
#pragma unroll
  for (int m = 1; m < 64; m <<= 1) v += __shfl_xor(v, m, 64);
  return v;
}
__device__ inline double wred_min(double v) {
#pragma unroll
  for (int m = 1; m < 64; m <<= 1) v = fmin(v, __shfl_xor(v, m, 64));
  return v;
}
__device__ inline double wred_max(double v) {
#pragma unroll
  for (int m = 1; m < 64; m <<= 1) v = fmax(v, __shfl_xor(v, m, 64));
  return v;
}
__device__ inline float wredf_sum(float v) {
#pragma unroll
  for (int m = 1; m < 64; m <<= 1) v += __shfl_xor(v, m, 64);
  return v;
}
__device__ inline int sgnbit(double x) {
  return (int)((unsigned long long)__double_as_longlong(x) >> 63);
}

// ---------------------------------------------------------------------------
// Fused [ph (blocks 0..3)  ||  embed (blocks 4..4003)] kernel.
// ph: top-50 landmarks (u64-key bitonic) -> f64 Laplacian -> REGISTER-resident
// full-width Householder tridiag (lane i holds row i; static-indexed, LDS only
// for uniform v/w broadcasts) -> per-lane division-free Sturm trisection ->
// inverse iteration + register back-transform for the Fiedler vector.
// ---------------------------------------------------------------------------
struct PhS {
  union {
    unsigned long long keys[1024];   // sort phase (8 KB)
    double matA[NLM][51];            // Laplacian build (20.4 KB)
  } u;
  double vstore[NLM - 2][64];        // reflectors for back-transform (24.6 KB)
  double vbuf[104], wbuf[104];       // zero-padded uniform broadcast buffers
  double dar[NLM], ear[NLM], e2a[NLM], tauA[NLM], evs[NLM];
  double gdl[NLM], gdd[NLM], gdu[NLM], gdu2[NLM], gz[NLM];
  float sm[SS];
  float lx[NLM], ly[NLM];
};
struct EmS { float sv[INDIM]; float h[128]; float red[256]; };
union FusedS { PhS ph; EmS em; };

__global__ __launch_bounds__(256) void phembed_kernel(
    const float* __restrict__ seq, const float* __restrict__ ph_fw,
    const float* __restrict__ ph_db, const float* __restrict__ ph_law,
    const float* __restrict__ ph_lab, float* __restrict__ pf,
    const float* __restrict__ ew1, const float* __restrict__ eb1,
    const float* __restrict__ ew2, const float* __restrict__ eb2,
    const float* __restrict__ eg, const float* __restrict__ ebe,
    const float* __restrict__ pos, float* __restrict__ X)
{
  __shared__ FusedS S;
  const int tid = threadIdx.x;

  if (blockIdx.x < BB) {
    // ================= ph path =================
    const int b = blockIdx.x;
    PhS& P = S.ph;
    const float law0 = ph_law[0], law1 = ph_law[1], labv = ph_lab[0];
    for (int s = tid; s < 1024; s += 256) {
      unsigned long long key;
      if (s < SS) {
        const float* p = seq + ((size_t)b * SS + s) * INDIM;
        float m = (p[0] + p[1] + p[2] + p[3] + p[4]) * 0.2f;
        P.sm[s] = m;
        float sc = (float)s * law0 + m * law1 + labv;
        unsigned u = __float_as_uint(sc);
        unsigned asc = (u & 0x80000000u) ? ~u : (u | 0x80000000u);
        key = ((unsigned long long)(~asc) << 32) | (unsigned)s;
      } else {
        key = (0xFFFFFFFFull << 32) | (unsigned)s;
      }
      P.u.keys[s] = key;
    }
    __syncthreads();
    // bitonic ascending on u64 keys == descending score, ties ascending idx
    for (int k = 2; k <= 1024; k <<= 1) {
      for (int j = k >> 1; j > 0; j >>= 1) {
        for (int i = tid; i < 1024; i += 256) {
          int ixj = i ^ j;
          if (ixj > i) {
            unsigned long long a = P.u.keys[i], c = P.u.keys[ixj];
            bool up = ((i & k) == 0);
            if ((a > c) == up) { P.u.keys[i] = c; P.u.keys[ixj] = a; }
          }
        }
        __syncthreads();
      }
    }
    if (tid < NLM) {
      int id = (int)(P.u.keys[tid] & 0xFFFFFFFFull);
      P.lx[tid] = (float)id;
      P.ly[tid] = P.sm[id];
    }
    __syncthreads();   // orders key reads before matA overwrites the union
    const float fwv = fabsf(ph_fw[0]);
    const float dbv = ph_db[0];
    for (int t = tid; t < NLM * NLM; t += 256) {
      int i = t / NLM, j = t % NLM;
      float dx = P.lx[i] - P.lx[j], dy = P.ly[i] - P.ly[j];
      float d2 = dx * dx + dy * dy;
      float dist = (d2 > 0.f) ? sqrtf(d2) : 0.f;
      float Kv = expf(-(dist * fwv + dbv));
      P.u.matA[i][j] = -(double)Kv;
    }
    __syncthreads();
    if (tid < NLM) {
      double rsum = 0.0;
      for (int j = 0; j < NLM; ++j) rsum -= P.u.matA[tid][j];
      P.u.matA[tid][tid] += rsum;  // exact f64 cancellation -> lambda0 ~ 1e-15
    }
    // zero-pad broadcast buffers (slots 64..103) once
    if (tid >= 64 && tid < 104) { P.vbuf[tid] = 0.0; P.wbuf[tid] = 0.0; }
    __syncthreads();

    if (tid >= 64) return;  // wave 0 runs the eigensolve barrier-free
    const int lane = tid;

    // ---- load matrix rows into registers (lane i = row i, zero elsewhere) ----
    double rrow[NLM];
#pragma unroll
    for (int j = 0; j < NLM; ++j)
      rrow[j] = (lane < NLM) ? P.u.matA[lane][j] : 0.0;
    double dval = 0.0;

    // ---- full-width register Householder tridiagonalization ----
    for (int k = 0; k <= NLM - 3; ++k) {
      if (lane == k) dval = rrow[0];           // A[k][k], final after step k-1
      double x = (lane > k && lane < NLM) ? rrow[0] : 0.0;   // column k
      double x0 = __shfl(x, k + 1, 64);
      double sigma = wred_sum((lane > k + 1) ? x * x : 0.0);
      double beta, tau, scale;
      if (sigma == 0.0) { beta = x0; tau = 0.0; scale = 0.0; }
      else {
        double nrm = sqrt(x0 * x0 + sigma);
        beta = (x0 >= 0.0) ? -nrm : nrm;
        tau = (beta - x0) / beta;
        scale = 1.0 / (x0 - beta);
      }
      double v = (lane == k + 1) ? 1.0 : ((lane > k + 1) ? x * scale : 0.0);
      P.vbuf[lane] = v;
      P.vstore[k][lane] = v;
      if (lane == 0) { P.ear[k] = beta; P.tauA[k] = tau; }
      __builtin_amdgcn_wave_barrier();
      // p = tau * A v   (rows in registers; uniform LDS broadcasts of v)
      double a0 = 0.0, a1 = 0.0, a2 = 0.0, a3 = 0.0;
#pragma unroll
      for (int j = 1; j < NLM; j += 4) {
        a0 += rrow[j] * P.vbuf[k + j];
        if (j + 1 < NLM) a1 += rrow[j + 1] * P.vbuf[k + j + 1];
        if (j + 2 < NLM) a2 += rrow[j + 2] * P.vbuf[k + j + 2];
        if (j + 3 < NLM) a3 += rrow[j + 3] * P.vbuf[k + j + 3];
      }
      double p = ((a0 + a1) + (a2 + a3)) * tau;
      double dotvp = wred_sum(v * p);
      double w = p - 0.5 * tau * dotvp * v;
      P.wbuf[lane] = w;
      __builtin_amdgcn_wave_barrier();
      // A -= v w^T + w v^T  (full-width: rows <k have v=w=0 -> no-op; row k
      // elimination happens automatically via w_k)
#pragma unroll
      for (int j = 1; j < NLM; ++j)
        rrow[j] -= v * P.wbuf[k + j] + w * P.vbuf[k + j];
      __builtin_amdgcn_wave_barrier();
      // shift left: rrow[j] <- A[i][k+1+j]
#pragma unroll
      for (int j = 0; j < NLM - 1; ++j) rrow[j] = rrow[j + 1];
      rrow[NLM - 1] = 0.0;
    }
    // trailing 2x2 block: lane48 rrow[0]=A[48][48], rrow[1]=A[48][49];
    // lane49 rrow[1]=A[49][49]
    {
      double d48 = __shfl(rrow[0], NLM - 2, 64);
      double e48 = __shfl(rrow[1], NLM - 2, 64);
      double d49 = __shfl(rrow[1], NLM - 1, 64);
      if (lane == NLM - 2) dval = d48;
      if (lane == NLM - 1) dval = d49;
      if (lane == 0) P.ear[NLM - 2] = e48;
      if (lane < NLM) P.dar[lane] = dval;
      __builtin_amdgcn_wave_barrier();
      if (lane < NLM - 1) P.e2a[lane] = P.ear[lane] * P.ear[lane];
      __builtin_amdgcn_wave_barrier();
    }

    // ---- Gershgorin bounds ----
    double lo_i = 1e300, hi_i = -1e300;
    if (lane < NLM) {
      double rl = (lane > 0) ? fabs(P.ear[lane - 1]) : 0.0;
      double rr = (lane < NLM - 1) ? fabs(P.ear[lane]) : 0.0;
      lo_i = P.dar[lane] - rl - rr;
      hi_i = P.dar[lane] + rl + rr;
    }
    double glo = wred_min(lo_i), ghi = wred_max(hi_i);

    // ---- trisection, division-free Sturm, 2 probes/iter, lane k -> k-th ev ----
    double myev = 1e300;
    if (lane < NLM) {
      double lo = glo, hi = ghi;
      const int need = lane + 1;
      for (int it = 0; it < 32; ++it) {
        double third = (hi - lo) * (1.0 / 3.0);
        double x1 = lo + third, x2 = hi - third;
        double pA = P.dar[0] - x1, pB = P.dar[0] - x2;
        double qA = 1.0, qB = 1.0;
        int c1 = sgnbit(pA), c2 = sgnbit(pB);
        for (int i = 1; i < NLM; ++i) {
          double di = P.dar[i], ei = P.e2a[i - 1];
          double nA = (di - x1) * pA - ei * qA;
          double nB = (di - x2) * pB - ei * qB;
          if (nA == 0.0) nA = sgnbit(pA) ? -1e-300 : 1e-300;
          if (nB == 0.0) nB = sgnbit(pB) ? -1e-300 : 1e-300;
          c1 += (sgnbit(nA) != sgnbit(pA));
          c2 += (sgnbit(nB) != sgnbit(pB));
          long long aa = __double_as_longlong(nA) & 0x7fffffffffffffffLL;
          long long ap = __double_as_longlong(pA) & 0x7fffffffffffffffLL;
          int Ea = (int)((aa > ap ? aa : ap) >> 52);
          int sea = 2046 - Ea; sea = sea < 1 ? 1 : (sea > 2045 ? 2045 : sea);
          double sA = __longlong_as_double((long long)sea << 52);
          qA = pA * sA; pA = nA * sA;
          long long ab = __double_as_longlong(nB) & 0x7fffffffffffffffLL;
          long long ab2 = __double_as_longlong(pB) & 0x7fffffffffffffffLL;
          int Eb = (int)((ab > ab2 ? ab : ab2) >> 52);
          int seb = 2046 - Eb; seb = seb < 1 ? 1 : (seb > 2045 ? 2045 : seb);
          double sB = __longlong_as_double((long long)seb << 52);
          qB = pB * sB; pB = nB * sB;
        }
        if (c1 >= need) hi = x1;
        else if (c2 >= need) { lo = x1; hi = x2; }
        else lo = x2;
      }
      myev = 0.5 * (lo + hi);
      P.evs[lane] = myev;
    }
    __builtin_amdgcn_wave_barrier();

    // ---- Fiedler vector: inverse iteration on tridiagonal (lane 0 serial) ----
    if (lane == 0) {
      double shift = P.evs[1];
      unsigned rs = 12345u;
      for (int i = 0; i < NLM; ++i) {
        rs = rs * 1103515245u + 12345u;
        P.gz[i] = ((double)((rs >> 8) & 0xFFFF)) / 65536.0 - 0.5;
      }
      for (int iter = 0; iter < 2; ++iter) {
        for (int i = 0; i < NLM; ++i) P.gdd[i] = P.dar[i] - shift;
        for (int i = 0; i < NLM - 1; ++i) { P.gdl[i] = P.ear[i]; P.gdu[i] = P.ear[i]; }
        for (int i = 0; i < NLM - 1; ++i) {
          if (fabs(P.gdd[i]) >= fabs(P.gdl[i])) {
            if (P.gdd[i] == 0.0) P.gdd[i] = 1e-280;
            double fact = P.gdl[i] / P.gdd[i];
            P.gdd[i + 1] -= fact * P.gdu[i];
            P.gz[i + 1] -= fact * P.gz[i];
            if (i < NLM - 2) P.gdu2[i] = 0.0;
          } else {
            double fact = P.gdd[i] / P.gdl[i];
            P.gdd[i] = P.gdl[i];
            double tmp = P.gdd[i + 1];
            P.gdd[i + 1] = P.gdu[i] - fact * tmp;
            if (i < NLM - 2) { P.gdu2[i] = P.gdu[i + 1]; P.gdu[i + 1] = -fact * P.gdu2[i]; }
            P.gdu[i] = tmp;
            double tz = P.gz[i]; P.gz[i] = P.gz[i + 1]; P.gz[i + 1] = tz - fact * P.gz[i];
          }
        }
        if (P.gdd[NLM - 1] == 0.0) P.gdd[NLM - 1] = 1e-280;
        P.gz[NLM - 1] /= P.gdd[NLM - 1];
        P.gz[NLM - 2] = (P.gz[NLM - 2] - P.gdu[NLM - 2] * P.gz[NLM - 1]) / P.gdd[NLM - 2];
        for (int i = NLM - 3; i >= 0; --i)
          P.gz[i] = (P.gz[i] - P.gdu[i] * P.gz[i + 1] - P.gdu2[i] * P.gz[i + 2]) / P.gdd[i];
        double nr = 0.0;
        for (int i = 0; i < NLM; ++i) nr += P.gz[i] * P.gz[i];
        nr = sqrt(nr);
        for (int i = 0; i < NLM; ++i) P.gz[i] /= nr;
      }
    }
    __builtin_amdgcn_wave_barrier();
    double fied = (lane < NLM) ? P.gz[lane] : 0.0;
    // back-transform: x = H_0 ... H_47 y (right-to-left), reflectors from LDS
    for (int k = NLM - 3; k >= 0; --k) {
      double v = P.vstore[k][lane];
      double dot = wred_sum(v * fied);
      fied -= P.tauA[k] * dot * v;
    }

    // ---- features via wave reductions ----
    bool inR = (lane < NLM);
    double n0 = wred_sum((inR && myev < 1e-6) ? 1.0 : 0.0);
    double s0 = wred_sum((inR && myev < 1e-6) ? fabs(myev) : 0.0);
    double e0 = __shfl(myev, 0, 64), e1 = __shfl(myev, 1, 64);
    double e2 = __shfl(myev, 2, 64), e3 = __shfl(myev, 3, 64);
    double e4 = __shfl(myev, 4, 64), e5 = __shfl(myev, 5, 64);
    double gap = e1 - e0;
    double m4 = (e2 + e3 + e4 + e5) * 0.25;
    double v4 = ((e2 - m4) * (e2 - m4) + (e3 - m4) * (e3 - m4) +
                 (e4 - m4) * (e4 - m4) + (e5 - m4) * (e5 - m4)) / 3.0;
    double fmean = wred_sum(inR ? fied : 0.0) / NLM;
    double fd = inR ? (fied - fmean) : 0.0;
    double fvar = wred_sum(fd * fd) / (NLM - 1);
    if (lane == 0) {
      float* o = pf + b * 6;
      o[0] = (float)n0;
      o[1] = (float)s0;
      o[2] = (float)gap;
      o[3] = (float)sqrt(fvar);
      o[4] = (float)m4;
      o[5] = (float)sqrt(v4);
    }
    return;
  }

  // ================= embed path =================
  const int row = blockIdx.x - BB;
  const int s = row % SS;
  EmS& M2 = S.em;
  if (tid < INDIM) M2.sv[tid] = seq[(size_t)row * INDIM + tid];
  __syncthreads();
  if (tid < 128) {
    const float* w = ew1 + tid * INDIM;
    float a = eb1[tid];
#pragma unroll
    for (int i = 0; i < INDIM; ++i) a += w[i] * M2.sv[i];
    M2.h[tid] = fmaxf(a, 0.f);
  }
  __syncthreads();
  const float* w = ew2 + (size_t)tid * 128;
  float a = eb2[tid];
  for (int i = 0; i < 128; ++i) a += w[i] * M2.h[i];
  M2.red[tid] = a; __syncthreads();
  for (int wd = 128; wd > 0; wd >>= 1) { if (tid < wd) M2.red[tid] += M2.red[tid + wd]; __syncthreads(); }
  float mean = M2.red[0] * (1.f / EE);
  __syncthreads();
  float d = a - mean;
  M2.red[tid] = d * d; __syncthreads();
  for (int wd = 128; wd > 0; wd >>= 1) { if (tid < wd) M2.red[tid] += M2.red[tid + wd]; __syncthreads(); }
  float var = M2.red[0] * (1.f / EE);
  X[(size_t)row * EE + tid] = d * rsqrtf(var + 1e-5f) * eg[tid] + ebe[tid] + pos[(size_t)s * EE + tid];
}

// ---------------------------------------------------------------------------
// Per-(layer,batch) scalar attention temperature
// ---------------------------------------------------------------------------
__global__ __launch_bounds__(256) void temp_kernel(
    const float* __restrict__ pf, const float* __restrict__ w1, const float* __restrict__ b1,
    const float* __restrict__ w2, const float* __restrict__ b2, float* __restrict__ ts)
{
  const int l = blockIdx.x / BB, b = blockIdx.x % BB, tid = threadIdx.x;
  __shared__ float pfl[6];
  __shared__ float h[128];
  __shared__ float red[256];
  if (tid < 6) pfl[tid] = pf[b * 6 + tid];
  __syncthreads();
  if (tid < 128) {
    const float* w = w1 + ((size_t)l * 128 + tid) * 6;
    float a = b1[(size_t)l * 128 + tid];
#pragma unroll
    for (int i = 0; i < 6; ++i) a += w[i] * pfl[i];
    h[tid] = fmaxf(a, 0.f);
  }
  __syncthreads();
  const float* w = w2 + ((size_t)l * EE + tid) * 128;
  float a = b2[(size_t)l * EE + tid];
  for (int i = 0; i < 128; ++i) a += w[i] * h[i];
  float sg = 1.f / (1.f + expf(-a));
  red[tid] = sg; __syncthreads();
  for (int wd = 128; wd > 0; wd >>= 1) { if (tid < wd) red[tid] += red[tid + wd]; __syncthreads(); }
  if (tid == 0) ts[l * BB + b] = red[0] * (1.f / EE);
}

// ---------------------------------------------------------------------------
// bf16 MFMA GEMM: C = A[MxK] @ W[NxK]^T + bias (f32 in/out, bf16 compute).
// Tile 128x64xBK32, 4 waves (2x2), per-wave 64x32 via 16x16x32 MFMA.
// ---------------------------------------------------------------------------
template <int ACT>
__global__ __launch_bounds__(256) void gemm3_mfma(
    const float* __restrict__ Ain,
    const float* __restrict__ W0, const float* __restrict__ W1, const float* __restrict__ W2,
    const float* __restrict__ bb0, const float* __restrict__ bb1, const float* __restrict__ bb2,
    float* __restrict__ C0, float* __restrict__ C1, float* __restrict__ C2,
    int M, int N, int K)
{
  const int z = blockIdx.z;
  const float* W = (z == 0) ? W0 : (z == 1) ? W1 : W2;
  const float* bias = (z == 0) ? bb0 : (z == 1) ? bb1 : bb2;
  float* C = (z == 0) ? C0 : (z == 1) ? C1 : C2;
  __shared__ __align__(16) unsigned short As[128][40];
  __shared__ __align__(16) unsigned short Bs[64][40];
  const int m0 = blockIdx.x * 128, n0 = blockIdx.y * 64;
  const int tid = threadIdx.x;
  const int lane = tid & 63, wave = tid >> 6;
  const int wm = wave >> 1, wn = wave & 1;
  const int l15 = lane & 15, l4 = lane >> 4;
  const int srow = tid >> 3, skg = tid & 7;

  f32x4 acc[4][2];
#pragma unroll
  for (int mf = 0; mf < 4; ++mf)
#pragma unroll
    for (int nf = 0; nf < 2; ++nf) acc[mf][nf] = (f32x4){0.f, 0.f, 0.f, 0.f};

  for (int k0 = 0; k0 < K; k0 += 32) {
    __syncthreads();
#pragma unroll
    for (int rr = 0; rr < 4; ++rr) {
      int row = srow + rr * 32;
      float4 av = *(const float4*)(Ain + (size_t)(m0 + row) * K + k0 + skg * 4);
      *(ushort4*)(&As[row][skg * 4]) = make_ushort4(f2b(av.x), f2b(av.y), f2b(av.z), f2b(av.w));
    }
#pragma unroll
    for (int rr = 0; rr < 2; ++rr) {
      int row = srow + rr * 32;
      if (row < 64) {
        float4 wv = *(const float4*)(W + (size_t)(n0 + row) * K + k0 + skg * 4);
        *(ushort4*)(&Bs[row][skg * 4]) = make_ushort4(f2b(wv.x), f2b(wv.y), f2b(wv.z), f2b(wv.w));
      }
    }
    __syncthreads();
    short8 bf[2];
#pragma unroll
    for (int nf = 0; nf < 2; ++nf)
      bf[nf] = *(const short8*)(&Bs[wn * 32 + nf * 16 + l15][l4 * 8]);
#pragma unroll
    for (int mf = 0; mf < 4; ++mf) {
      short8 af = *(const short8*)(&As[wm * 64 + mf * 16 + l15][l4 * 8]);
#pragma unroll
      for (int nf = 0; nf < 2; ++nf)
        acc[mf][nf] = __builtin_amdgcn_mfma_f32_16x16x32_bf16(af, bf[nf], acc[mf][nf], 0, 0, 0);
    }
  }
#pragma unroll
  for (int nf = 0; nf < 2; ++nf) {
    int col = n0 + wn * 32 + nf * 16 + l15;
    float bv = bias[col];
#pragma unroll
    for (int mf = 0; mf < 4; ++mf) {
#pragma unroll
      for (int r = 0; r < 4; ++r) {
        int row = m0 + wm * 64 + mf * 16 + l4 * 4 + r;
        if (row < M) {
          float v = acc[mf][nf][r] + bv;
          if (ACT == 1) v = 0.5f * v * (1.f + erff(v * 0.70710678118654752440f));
          C[(size_t)row * N + col] = v;
        }
      }
    }
  }
}

// ---------------------------------------------------------------------------
// bf16 MFMA flash attention, per-sample scalar temperature.
// ---------------------------------------------------------------------------
__global__ __launch_bounds__(256) void attn_mfma(
    const float* __restrict__ Qm, const float* __restrict__ Km, const float* __restrict__ Vm,
    const float* __restrict__ ts, float* __restrict__ Om, int l)
{
  const int qt = blockIdx.x, h = blockIdx.y, b = blockIdx.z;
  const int tid = threadIdx.x;
  const int lane = tid & 63, wave = tid >> 6;
  const int l15 = lane & 15, l4 = lane >> 4;
  const float scale = ts[l * BB + b] * 0.17677669529663688110f;  // ts / sqrt(32)
  __shared__ __align__(16) unsigned short Ks[64][40];
  __shared__ __align__(16) unsigned short Vt[32][72];
  __shared__ __align__(16) unsigned short Pw[4][16][72];
  const int q0 = qt * 64 + wave * 16;

  short8 qf;
  {
    unsigned short qb_[8] = {0, 0, 0, 0, 0, 0, 0, 0};
    int qrow = q0 + l15;
    if (qrow < SS) {
      const float* qp = Qm + ((size_t)(b * SS + qrow)) * EE + h * DHH + l4 * 8;
      float4 a = *(const float4*)qp;
      float4 c = *(const float4*)(qp + 4);
      qb_[0] = f2b(a.x); qb_[1] = f2b(a.y); qb_[2] = f2b(a.z); qb_[3] = f2b(a.w);
      qb_[4] = f2b(c.x); qb_[5] = f2b(c.y); qb_[6] = f2b(c.z); qb_[7] = f2b(c.w);
    }
#pragma unroll
    for (int i = 0; i < 8; ++i) qf[i] = (short)qb_[i];
  }

  float mrun[4] = {-INFINITY, -INFINITY, -INFINITY, -INFINITY};
  float lrun[4] = {0.f, 0.f, 0.f, 0.f};
  f32x4 Oacc[2];
  Oacc[0] = (f32x4){0.f, 0.f, 0.f, 0.f};
  Oacc[1] = (f32x4){0.f, 0.f, 0.f, 0.f};

  for (int k0 = 0; k0 < SS; k0 += 64) {
    int kn = SS - k0; if (kn > 64) kn = 64;
    __syncthreads();
    {
      int row = tid >> 3, kg = tid & 7;
#pragma unroll
      for (int rr = 0; rr < 2; ++rr) {
        int r2 = row + rr * 32;
        float4 kv = make_float4(0.f, 0.f, 0.f, 0.f);
        if (r2 < kn)
          kv = *(const float4*)(Km + ((size_t)(b * SS + k0 + r2)) * EE + h * DHH + kg * 4);
        *(ushort4*)(&Ks[r2][kg * 4]) = make_ushort4(f2b(kv.x), f2b(kv.y), f2b(kv.z), f2b(kv.w));
      }
    }
    {
      int d = tid & 31, kb = tid >> 5;
      unsigned short uu[8];
#pragma unroll
      for (int i = 0; i < 8; ++i) {
        int kv = kb * 8 + i;
        float vv2 = (kv < kn) ? Vm[((size_t)(b * SS + k0 + kv)) * EE + h * DHH + d] : 0.f;
        uu[i] = f2b(vv2);
      }
      *(ushort4*)(&Vt[d][kb * 8])     = make_ushort4(uu[0], uu[1], uu[2], uu[3]);
      *(ushort4*)(&Vt[d][kb * 8 + 4]) = make_ushort4(uu[4], uu[5], uu[6], uu[7]);
    }
    __syncthreads();

    f32x4 sa[4];
#pragma unroll
    for (int nf = 0; nf < 4; ++nf) {
      short8 kf = *(const short8*)(&Ks[nf * 16 + l15][l4 * 8]);
      f32x4 zz = (f32x4){0.f, 0.f, 0.f, 0.f};
      sa[nf] = __builtin_amdgcn_mfma_f32_16x16x32_bf16(qf, kf, zz, 0, 0, 0);
    }
#pragma unroll
    for (int nf = 0; nf < 4; ++nf) {
      bool valid = (nf * 16 + l15) < kn;
#pragma unroll
      for (int r = 0; r < 4; ++r)
        sa[nf][r] = valid ? sa[nf][r] * scale : -INFINITY;
    }
    float pv[4][4];
#pragma unroll
    for (int r = 0; r < 4; ++r) {
      float tmax = fmaxf(fmaxf(sa[0][r], sa[1][r]), fmaxf(sa[2][r], sa[3][r]));
#pragma unroll
      for (int m = 1; m < 16; m <<= 1) tmax = fmaxf(tmax, __shfl_xor(tmax, m, 64));
      float mnew = fmaxf(mrun[r], tmax);
      float fac = expf(mrun[r] - mnew);
      float rsum = 0.f;
#pragma unroll
      for (int nf = 0; nf < 4; ++nf) {
        float p = expf(sa[nf][r] - mnew);
        pv[nf][r] = p;
        rsum += p;
      }
#pragma unroll
      for (int m = 1; m < 16; m <<= 1) rsum += __shfl_xor(rsum, m, 64);
      lrun[r] = lrun[r] * fac + rsum;
      mrun[r] = mnew;
      Oacc[0][r] *= fac;
      Oacc[1][r] *= fac;
    }
#pragma unroll
    for (int nf = 0; nf < 4; ++nf)
#pragma unroll
      for (int r = 0; r < 4; ++r)
        Pw[wave][l4 * 4 + r][nf * 16 + l15] = f2b(pv[nf][r]);
    asm volatile("s_waitcnt lgkmcnt(0)" ::: "memory");
    __builtin_amdgcn_sched_barrier(0);
#pragma unroll
    for (int ka = 0; ka < 2; ++ka) {
      short8 pa = *(const short8*)(&Pw[wave][l15][ka * 32 + l4 * 8]);
#pragma unroll
      for (int df = 0; df < 2; ++df) {
        short8 vf = *(const short8*)(&Vt[df * 16 + l15][ka * 32 + l4 * 8]);
        Oacc[df] = __builtin_amdgcn_mfma_f32_16x16x32_bf16(pa, vf, Oacc[df], 0, 0, 0);
      }
    }
  }
#pragma unroll
  for (int df = 0; df < 2; ++df)
#pragma unroll
    for (int r = 0; r < 4; ++r) {
      int qrow = q0 + l4 * 4 + r;
      if (qrow < SS)
        Om[((size_t)(b * SS + qrow)) * EE + h * DHH + df * 16 + l15] = Oacc[df][r] / lrun[r];
    }
}

// ---------------------------------------------------------------------------
// x = LN(x + t): one WAVE per row (4 rows/block), shfl reductions, float4 I/O
// ---------------------------------------------------------------------------
__global__ __launch_bounds__(256) void addln_kernel(
    float* __restrict__ X, const float* __restrict__ T,
    const float* __restrict__ g, const float* __restrict__ be)
{
  const int row = blockIdx.x * 4 + (threadIdx.x >> 6);
  const int lane = threadIdx.x & 63;
  float4 xv = *(float4*)(X + (size_t)row * EE + lane * 4);
  float4 tv = *(const float4*)(T + (size_t)row * EE + lane * 4);
  float4 v = make_float4(xv.x + tv.x, xv.y + tv.y, xv.z + tv.z, xv.w + tv.w);
  float s = v.x + v.y + v.z + v.w;
  s = wredf_sum(s);
  float mean = s * (1.f / EE);
  float4 d = make_float4(v.x - mean, v.y - mean, v.z - mean, v.w - mean);
  float q = d.x * d.x + d.y * d.y + d.z * d.z + d.w * d.w;
  q = wredf_sum(q);
  float inv = rsqrtf(q * (1.f / EE) + 1e-5f);
  float4 gv = *(const float4*)(g + lane * 4);
  float4 bv = *(const float4*)(be + lane * 4);
  float4 o = make_float4(d.x * inv * gv.x + bv.x, d.y * inv * gv.y + bv.y,
                         d.z * inv * gv.z + bv.z, d.w * inv * gv.w + bv.w);
  *(float4*)(X + (size_t)row * EE + lane * 4) = o;
}

// ---------------------------------------------------------------------------
// Attention-weighted pooling + LN + classifier; one batch per block
// ---------------------------------------------------------------------------
__global__ __launch_bounds__(256) void final_kernel(
    const float* __restrict__ X, const float* __restrict__ g, const float* __restrict__ be,
    const float* __restrict__ w1, const float* __restrict__ b1,
    const float* __restrict__ w2, const float* __restrict__ b2,
    float* __restrict__ out)
{
  const int b = blockIdx.x, tid = threadIdx.x;
  __shared__ float rs[SS];
  __shared__ float red[256];
  __shared__ float pooled[EE];
  __shared__ float h[128];
  for (int s = tid; s < SS; s += 256) {
    const float* xr = X + ((size_t)(b * SS + s)) * EE;
    float a = 0.f;
    for (int e = 0; e < EE; ++e) a += xr[e];
    rs[s] = a;
  }
  __syncthreads();
  float mx = -INFINITY;
  for (int s = tid; s < SS; s += 256) mx = fmaxf(mx, rs[s]);
  red[tid] = mx; __syncthreads();
  for (int w = 128; w > 0; w >>= 1) { if (tid < w) red[tid] = fmaxf(red[tid], red[tid + w]); __syncthreads(); }
  mx = red[0]; __syncthreads();
  float sme = 0.f;
  for (int s = tid; s < SS; s += 256) { float e2 = expf(rs[s] - mx); rs[s] = e2; sme += e2; }
  red[tid] = sme; __syncthreads();
  for (int w = 128; w > 0; w >>= 1) { if (tid < w) red[tid] += red[tid + w]; __syncthreads(); }
  float tot = red[0]; __syncthreads();
  float acc = 0.f;
  for (int s = 0; s < SS; ++s) acc += X[((size_t)(b * SS + s)) * EE + tid] * rs[s];
  acc /= tot;
  red[tid] = acc; __syncthreads();
  for (int w = 128; w > 0; w >>= 1) { if (tid < w) red[tid] += red[tid + w]; __syncthreads(); }
  float mean = red[0] * (1.f / EE); __syncthreads();
  float d = acc - mean;
  red[tid] = d * d; __syncthreads();
  for (int w = 128; w > 0; w >>= 1) { if (tid < w) red[tid] += red[tid + w]; __syncthreads(); }
  float var = red[0] * (1.f / EE);
  pooled[tid] = d * rsqrtf(var + 1e-5f) * g[tid] + be[tid];
  __syncthreads();
  if (tid < 128) {
    const float* w = w1 + (size_t)tid * EE;
    float a = b1[tid];
    for (int e = 0; e < EE; ++e) a += w[e] * pooled[e];
    h[tid] = fmaxf(a, 0.f);
  }
  __syncthreads();
  if (tid < 2) {
    const float* w = w2 + (size_t)tid * 128;
    float a = b2[tid];
    for (int j = 0; j < 128; ++j) a += w[j] * h[j];
    out[b * 2 + tid] = a;
  }
}

// ---------------------------------------------------------------------------
extern "C" void kernel_launch(void* const* d_in, const int* in_sizes, int n_in,
                              void* d_out, int out_size, void* d_ws, size_t ws_size,
                              hipStream_t stream) {
  (void)in_sizes; (void)n_in; (void)out_size; (void)ws_size;
  const float* seq    = (const float*)d_in[0];
  const float* ph_fw  = (const float*)d_in[1];
  const float* ph_db  = (const float*)d_in[2];
  const float* ph_law = (const float*)d_in[3];
  const float* ph_lab = (const float*)d_in[4];
  const float* emb_w1 = (const float*)d_in[5];
  const float* emb_b1 = (const float*)d_in[6];
  const float* emb_w2 = (const float*)d_in[7];
  const float* emb_b2 = (const float*)d_in[8];
  const float* eln_g  = (const float*)d_in[9];
  const float* eln_b  = (const float*)d_in[10];
  const float* pos    = (const float*)d_in[11];
  const float* qw     = (const float*)d_in[12];
  const float* qb     = (const float*)d_in[13];
  const float* kw     = (const float*)d_in[14];
  const float* kb     = (const float*)d_in[15];
  const float* vw     = (const float*)d_in[16];
  const float* vb     = (const float*)d_in[17];
  const float* pw1    = (const float*)d_in[18];
  const float* pb1    = (const float*)d_in[19];
  const float* pw2    = (const float*)d_in[20];
  const float* pb2    = (const float*)d_in[21];
  const float* ow     = (const float*)d_in[22];
  const float* obv    = (const float*)d_in[23];
  const float* lng    = (const float*)d_in[24];
  const float* lnb    = (const float*)d_in[25];
  const float* fw1    = (const float*)d_in[26];
  const float* fb1    = (const float*)d_in[27];
  const float* fw2    = (const float*)d_in[28];
  const float* fb2    = (const float*)d_in[29];
  const float* clng   = (const float*)d_in[30];
  const float* clnb   = (const float*)d_in[31];
  const float* cw1    = (const float*)d_in[32];
  const float* cb1    = (const float*)d_in[33];
  const float* cw2    = (const float*)d_in[34];
  const float* cb2    = (const float*)d_in[35];

  float* ws  = (float*)d_ws;
  float* pf  = ws;            // 24 floats
  float* tsv = ws + 32;       // 24 floats
  const size_t SL = (size_t)4096 * 256;
  float* X    = ws + 256;
  float* TMP  = X + SL;
  float* Qp   = TMP + SL;
  float* Kp   = Qp + SL;
  float* Vp   = Kp + SL;
  float* ATTp = Vp + SL;
  float* HIDp = ATTp + SL;    // 4*SL (4096 x 1024)
  const int M = BB * SS;      // 4000

  phembed_kernel<<<BB + M, 256, 0, stream>>>(
      seq, ph_fw, ph_db, ph_law, ph_lab, pf,
      emb_w1, emb_b1, emb_w2, emb_b2, eln_g, eln_b, pos, X);
  temp_kernel<<<LL * BB, 256, 0, stream>>>(pf, pw1, pb1, pw2, pb2, tsv);

  const int GM = (M + 127) / 128;  // 32
  for (int l = 0; l < LL; ++l) {
    const size_t wo = (size_t)l * EE * EE;
    gemm3_mfma<0><<<dim3(GM, EE / 64, 3), 256, 0, stream>>>(
        X, qw + wo, kw + wo, vw + wo, qb + l * EE, kb + l * EE, vb + l * EE,
        Qp, Kp, Vp, M, EE, EE);
    attn_mfma<<<dim3(16, HH, BB), 256, 0, stream>>>(Qp, Kp, Vp, tsv, ATTp, l);
    gemm3_mfma<0><<<dim3(GM, EE / 64, 1), 256, 0, stream>>>(
        ATTp, ow + wo, ow + wo, ow + wo, obv + l * EE, obv + l * EE, obv + l * EE,
        TMP, TMP, TMP, M, EE, EE);
    addln_kernel<<<M / 4, 256, 0, stream>>>(X, TMP, lng + l * EE, lnb + l * EE);
    gemm3_mfma<1><<<dim3(GM, FFD / 64, 1), 256, 0, stream>>>(
        X, fw1 + (size_t)l * FFD * EE, fw1 + (size_t)l * FFD * EE, fw1 + (size_t)l * FFD * EE,
        fb1 + (size_t)l * FFD, fb1 + (size_t)l * FFD, fb1 + (size_t)l * FFD,
        HIDp, HIDp, HIDp, M, FFD, EE);
    gemm3_mfma<0><<<dim3(GM, EE / 64, 1), 256, 0, stream>>>(
        HIDp, fw2 + (size_t)l * EE * FFD, fw2 + (size_t)l * EE * FFD, fw2 + (size_t)l * EE * FFD,
        fb2 + l * EE, fb2 + l * EE, fb2 + l * EE,
        TMP, TMP, TMP, M, EE, FFD);
    addln_kernel<<<M / 4, 256, 0, stream>>>(X, TMP, lng + l * EE, lnb + l * EE);
  }

  final_kernel<<<BB, 256, 0, stream>>>(X, clng, clnb, cw1, cb1, cw2, cb2, (float*)d_out);
}

// Round 6
// 1034.508 us; speedup vs baseline: 3.1863x; 1.6564x over previous
//
#include <hip/hip_runtime.h>
#include <math.h>

constexpr int BB = 4;       // batch
constexpr int SS = 1000;    // seq len
constexpr int INDIM = 5;
constexpr int EE = 256;     // embed
constexpr int LL = 6;       // layers
constexpr int HH = 8;       // heads
constexpr int DHH = 32;     // head dim
constexpr int NLM = 50;     // landmarks
constexpr int FFD = 1024;   // ff hidden

typedef short short8 __attribute__((ext_vector_type(8)));
typedef float f32x4 __attribute__((ext_vector_type(4)));
typedef unsigned short u16;

__device__ inline u16 f2b(float f) {
  union { float f; unsigned u; } v; v.f = f;
  unsigned u = v.u;
  unsigned r = u + 0x7FFFu + ((u >> 16) & 1u);  // round-to-nearest-even
  return (u16)(r >> 16);
}
__device__ inline float b2f(u16 b) {
  union { unsigned u; float f; } v; v.u = ((unsigned)b) << 16;
  return v.f;
}
__device__ inline short8 pack8(float4 a, float4 b) {
  short8 r;
  r[0] = (short)f2b(a.x); r[1] = (short)f2b(a.y);
  r[2] = (short)f2b(a.z); r[3] = (short)f2b(a.w);
  r[4] = (short)f2b(b.x); r[5] = (short)f2b(b.y);
  r[6] = (short)f2b(b.z); r[7] = (short)f2b(b.w);
  return r;
}

__device__ inline double wred_sum(double v) {
#pragma unroll
  for (int m = 1; m < 64; m <<= 1) v += __shfl_xor(v, m, 64);
  return v;
}
__device__ inline double wred_min(double v) {
#pragma unroll
  for (int m = 1; m < 64; m <<= 1) v = fmin(v, __shfl_xor(v, m, 64));
  return v;
}
__device__ inline double wred_max(double v) {
#pragma unroll
  for (int m = 1; m < 64; m <<= 1) v = fmax(v, __shfl_xor(v, m, 64));
  return v;
}
__device__ inline float wredf_sum(float v) {
#pragma unroll
  for (int m = 1; m < 64; m <<= 1) v += __shfl_xor(v, m, 64);
  return v;
}
__device__ inline int sgnbit(double x) {
  return (int)((unsigned long long)__double_as_longlong(x) >> 63);
}

// ---------------------------------------------------------------------------
// Fused [ph (blocks 0..3) || embed (blocks 4..4003)].
// ph: top-50 landmarks -> f64 Laplacian -> register Householder tridiag ->
// per-lane division-free Sturm trisection with REGISTER-resident diagonal ->
// inverse iteration + back-transform for the Fiedler vector.
// ---------------------------------------------------------------------------
struct PhS {
  union {
    unsigned long long keys[1024];   // sort phase
    double matA[NLM][51];            // Laplacian build
  } u;
  double vstore[NLM - 2][64];        // reflectors for back-transform
  double vbuf[104];                  // zero-padded v broadcast
  double vw[208];                    // interleaved (v,w) pairs, zero-padded
  double dar[NLM], ear[NLM], e2a[NLM], tauA[NLM], evs[NLM];
  double gdl[NLM], gdd[NLM], gdu[NLM], gdu2[NLM], gz[NLM];
  float sm[SS];
  float lx[NLM], ly[NLM];
};
struct EmS { float sv[INDIM]; float h[128]; float red[256]; };
union FusedS { PhS ph; EmS em; };

__global__ __launch_bounds__(256) void phembed_kernel(
    const float* __restrict__ seq, const float* __restrict__ ph_fw,
    const float* __restrict__ ph_db, const float* __restrict__ ph_law,
    const float* __restrict__ ph_lab, float* __restrict__ pf,
    const float* __restrict__ ew1, const float* __restrict__ eb1,
    const float* __restrict__ ew2, const float* __restrict__ eb2,
    const float* __restrict__ eg, const float* __restrict__ ebe,
    const float* __restrict__ pos, float* __restrict__ X)
{
  __shared__ FusedS S;
  const int tid = threadIdx.x;

  if (blockIdx.x < BB) {
    const int b = blockIdx.x;
    PhS& P = S.ph;
    const float law0 = ph_law[0], law1 = ph_law[1], labv = ph_lab[0];
    for (int s = tid; s < 1024; s += 256) {
      unsigned long long key;
      if (s < SS) {
        const float* p = seq + ((size_t)b * SS + s) * INDIM;
        float m = (p[0] + p[1] + p[2] + p[3] + p[4]) * 0.2f;
        P.sm[s] = m;
        float sc = (float)s * law0 + m * law1 + labv;
        unsigned u = __float_as_uint(sc);
        unsigned asc = (u & 0x80000000u) ? ~u : (u | 0x80000000u);
        key = ((unsigned long long)(~asc) << 32) | (unsigned)s;
      } else {
        key = (0xFFFFFFFFull << 32) | (unsigned)s;
      }
      P.u.keys[s] = key;
    }
    __syncthreads();
    for (int k = 2; k <= 1024; k <<= 1) {
      for (int j = k >> 1; j > 0; j >>= 1) {
        for (int i = tid; i < 1024; i += 256) {
          int ixj = i ^ j;
          if (ixj > i) {
            unsigned long long a = P.u.keys[i], c = P.u.keys[ixj];
            bool up = ((i & k) == 0);
            if ((a > c) == up) { P.u.keys[i] = c; P.u.keys[ixj] = a; }
          }
        }
        __syncthreads();
      }
    }
    if (tid < NLM) {
      int id = (int)(P.u.keys[tid] & 0xFFFFFFFFull);
      P.lx[tid] = (float)id;
      P.ly[tid] = P.sm[id];
    }
    __syncthreads();
    const float fwv = fabsf(ph_fw[0]);
    const float dbv = ph_db[0];
    for (int t = tid; t < NLM * NLM; t += 256) {
      int i = t / NLM, j = t % NLM;
      float dx = P.lx[i] - P.lx[j], dy = P.ly[i] - P.ly[j];
      float d2 = dx * dx + dy * dy;
      float dist = (d2 > 0.f) ? sqrtf(d2) : 0.f;
      float Kv = expf(-(dist * fwv + dbv));
      P.u.matA[i][j] = -(double)Kv;
    }
    __syncthreads();
    if (tid < NLM) {
      double rsum = 0.0;
      for (int j = 0; j < NLM; ++j) rsum -= P.u.matA[tid][j];
      P.u.matA[tid][tid] += rsum;  // exact cancellation -> lambda0 ~ 1e-15
    }
    if (tid >= 64 && tid < 104) {
      P.vbuf[tid] = 0.0; P.vw[2 * tid] = 0.0; P.vw[2 * tid + 1] = 0.0;
    }
    __syncthreads();

    if (tid >= 64) return;  // wave 0 runs eigensolve barrier-free
    const int lane = tid;

    double rrow[NLM];
#pragma unroll
    for (int j = 0; j < NLM; ++j)
      rrow[j] = (lane < NLM) ? P.u.matA[lane][j] : 0.0;
    double dval = 0.0;

    for (int k = 0; k <= NLM - 3; ++k) {
      if (lane == k) dval = rrow[0];
      double x = (lane > k && lane < NLM) ? rrow[0] : 0.0;
      double x0 = __shfl(x, k + 1, 64);
      double sigma = wred_sum((lane > k + 1) ? x * x : 0.0);
      double beta, tau, scale;
      if (sigma == 0.0) { beta = x0; tau = 0.0; scale = 0.0; }
      else {
        double nrm = sqrt(x0 * x0 + sigma);
        beta = (x0 >= 0.0) ? -nrm : nrm;
        tau = (beta - x0) / beta;
        scale = 1.0 / (x0 - beta);
      }
      double v = (lane == k + 1) ? 1.0 : ((lane > k + 1) ? x * scale : 0.0);
      P.vbuf[lane] = v;
      P.vw[2 * lane] = v;
      P.vstore[k][lane] = v;
      if (lane == 0) { P.ear[k] = beta; P.tauA[k] = tau; }
      __builtin_amdgcn_wave_barrier();
      double a0 = 0.0, a1 = 0.0, a2 = 0.0, a3 = 0.0;
#pragma unroll
      for (int j = 1; j < NLM; j += 4) {
        a0 += rrow[j] * P.vbuf[k + j];
        if (j + 1 < NLM) a1 += rrow[j + 1] * P.vbuf[k + j + 1];
        if (j + 2 < NLM) a2 += rrow[j + 2] * P.vbuf[k + j + 2];
        if (j + 3 < NLM) a3 += rrow[j + 3] * P.vbuf[k + j + 3];
      }
      double p = ((a0 + a1) + (a2 + a3)) * tau;
      double dotvp = wred_sum(v * p);
      double w = p - 0.5 * tau * dotvp * v;
      P.vw[2 * lane + 1] = w;
      __builtin_amdgcn_wave_barrier();
#pragma unroll
      for (int j = 1; j < NLM; ++j) {
        double vj = P.vw[2 * (k + j)], wj = P.vw[2 * (k + j) + 1];
        rrow[j] -= v * wj + w * vj;
      }
      __builtin_amdgcn_wave_barrier();
#pragma unroll
      for (int j = 0; j < NLM - 1; ++j) rrow[j] = rrow[j + 1];
      rrow[NLM - 1] = 0.0;
    }
    {
      double d48 = __shfl(rrow[0], NLM - 2, 64);
      double e48 = __shfl(rrow[1], NLM - 2, 64);
      double d49 = __shfl(rrow[1], NLM - 1, 64);
      if (lane == NLM - 2) dval = d48;
      if (lane == NLM - 1) dval = d49;
      if (lane == 0) P.ear[NLM - 2] = e48;
      if (lane < NLM) P.dar[lane] = dval;
      __builtin_amdgcn_wave_barrier();
      if (lane < NLM - 1) P.e2a[lane] = P.ear[lane] * P.ear[lane];
      __builtin_amdgcn_wave_barrier();
    }

    // tridiagonal into per-lane REGISTERS (broadcast reads; static indexing)
    double dreg[NLM], e2reg[NLM - 1];
#pragma unroll
    for (int i = 0; i < NLM; ++i) dreg[i] = P.dar[i];
#pragma unroll
    for (int i = 0; i < NLM - 1; ++i) e2reg[i] = P.e2a[i];

    double lo_i = 1e300, hi_i = -1e300;
    if (lane < NLM) {
      double rl = (lane > 0) ? fabs(P.ear[lane - 1]) : 0.0;
      double rr = (lane < NLM - 1) ? fabs(P.ear[lane]) : 0.0;
      lo_i = dreg[lane] - rl - rr;   // dynamic idx ok: falls back to scratch? no:
      hi_i = dreg[lane] + rl + rr;   // lane is runtime -> use LDS instead
    }
    if (lane < NLM) { lo_i = P.dar[lane]; hi_i = P.dar[lane]; }
    if (lane < NLM) {
      double rl = (lane > 0) ? fabs(P.ear[lane - 1]) : 0.0;
      double rr = (lane < NLM - 1) ? fabs(P.ear[lane]) : 0.0;
      lo_i -= (rl + rr);
      hi_i += (rl + rr);
    }
    double glo = wred_min(lo_i), ghi = wred_max(hi_i);

    // trisection, division-free Sturm, pure-VALU inner loop
    double myev = 1e300;
    if (lane < NLM) {
      double lo = glo, hi = ghi;
      const int need = lane + 1;
      for (int it = 0; it < 32; ++it) {
        double third = (hi - lo) * (1.0 / 3.0);
        double x1 = lo + third, x2 = hi - third;
        double pA = dreg[0] - x1, pB = dreg[0] - x2;
        double qA = 1.0, qB = 1.0;
        int c1 = sgnbit(pA), c2 = sgnbit(pB);
#pragma unroll
        for (int i = 1; i < NLM; ++i) {
          double di = dreg[i], ei = e2reg[i - 1];
          double nA = (di - x1) * pA - ei * qA;
          double nB = (di - x2) * pB - ei * qB;
          if (nA == 0.0) nA = sgnbit(pA) ? -1e-300 : 1e-300;
          if (nB == 0.0) nB = sgnbit(pB) ? -1e-300 : 1e-300;
          c1 += (sgnbit(nA) != sgnbit(pA));
          c2 += (sgnbit(nB) != sgnbit(pB));
          long long aa = __double_as_longlong(nA) & 0x7fffffffffffffffLL;
          long long ap = __double_as_longlong(pA) & 0x7fffffffffffffffLL;
          int Ea = (int)((aa > ap ? aa : ap) >> 52);
          int sea = 2046 - Ea; sea = sea < 1 ? 1 : (sea > 2045 ? 2045 : sea);
          double sA = __longlong_as_double((long long)sea << 52);
          qA = pA * sA; pA = nA * sA;
          long long ab = __double_as_longlong(nB) & 0x7fffffffffffffffLL;
          long long ab2 = __double_as_longlong(pB) & 0x7fffffffffffffffLL;
          int Eb = (int)((ab > ab2 ? ab : ab2) >> 52);
          int seb = 2046 - Eb; seb = seb < 1 ? 1 : (seb > 2045 ? 2045 : seb);
          double sB = __longlong_as_double((long long)seb << 52);
          qB = pB * sB; pB = nB * sB;
        }
        if (c1 >= need) hi = x1;
        else if (c2 >= need) { lo = x1; hi = x2; }
        else lo = x2;
      }
      myev = 0.5 * (lo + hi);
      P.evs[lane] = myev;
    }
    __builtin_amdgcn_wave_barrier();

    if (lane == 0) {
      double shift = P.evs[1];
      unsigned rs = 12345u;
      for (int i = 0; i < NLM; ++i) {
        rs = rs * 1103515245u + 12345u;
        P.gz[i] = ((double)((rs >> 8) & 0xFFFF)) / 65536.0 - 0.5;
      }
      for (int iter = 0; iter < 2; ++iter) {
        for (int i = 0; i < NLM; ++i) P.gdd[i] = P.dar[i] - shift;
        for (int i = 0; i < NLM - 1; ++i) { P.gdl[i] = P.ear[i]; P.gdu[i] = P.ear[i]; }
        for (int i = 0; i < NLM - 1; ++i) {
          if (fabs(P.gdd[i]) >= fabs(P.gdl[i])) {
            if (P.gdd[i] == 0.0) P.gdd[i] = 1e-280;
            double fact = P.gdl[i] / P.gdd[i];
            P.gdd[i + 1] -= fact * P.gdu[i];
            P.gz[i + 1] -= fact * P.gz[i];
            if (i < NLM - 2) P.gdu2[i] = 0.0;
          } else {
            double fact = P.gdd[i] / P.gdl[i];
            P.gdd[i] = P.gdl[i];
            double tmp = P.gdd[i + 1];
            P.gdd[i + 1] = P.gdu[i] - fact * tmp;
            if (i < NLM - 2) { P.gdu2[i] = P.gdu[i + 1]; P.gdu[i + 1] = -fact * P.gdu2[i]; }
            P.gdu[i] = tmp;
            double tz = P.gz[i]; P.gz[i] = P.gz[i + 1]; P.gz[i + 1] = tz - fact * P.gz[i];
          }
        }
        if (P.gdd[NLM - 1] == 0.0) P.gdd[NLM - 1] = 1e-280;
        P.gz[NLM - 1] /= P.gdd[NLM - 1];
        P.gz[NLM - 2] = (P.gz[NLM - 2] - P.gdu[NLM - 2] * P.gz[NLM - 1]) / P.gdd[NLM - 2];
        for (int i = NLM - 3; i >= 0; --i)
          P.gz[i] = (P.gz[i] - P.gdu[i] * P.gz[i + 1] - P.gdu2[i] * P.gz[i + 2]) / P.gdd[i];
        double nr = 0.0;
        for (int i = 0; i < NLM; ++i) nr += P.gz[i] * P.gz[i];
        nr = sqrt(nr);
        for (int i = 0; i < NLM; ++i) P.gz[i] /= nr;
      }
    }
    __builtin_amdgcn_wave_barrier();
    double fied = (lane < NLM) ? P.gz[lane] : 0.0;
    for (int k = NLM - 3; k >= 0; --k) {
      double v = P.vstore[k][lane];
      double dot = wred_sum(v * fied);
      fied -= P.tauA[k] * dot * v;
    }

    bool inR = (lane < NLM);
    double n0 = wred_sum((inR && myev < 1e-6) ? 1.0 : 0.0);
    double s0 = wred_sum((inR && myev < 1e-6) ? fabs(myev) : 0.0);
    double e0 = __shfl(myev, 0, 64), e1 = __shfl(myev, 1, 64);
    double e2 = __shfl(myev, 2, 64), e3 = __shfl(myev, 3, 64);
    double e4 = __shfl(myev, 4, 64), e5 = __shfl(myev, 5, 64);
    double gap = e1 - e0;
    double m4 = (e2 + e3 + e4 + e5) * 0.25;
    double v4 = ((e2 - m4) * (e2 - m4) + (e3 - m4) * (e3 - m4) +
                 (e4 - m4) * (e4 - m4) + (e5 - m4) * (e5 - m4)) / 3.0;
    double fmean = wred_sum(inR ? fied : 0.0) / NLM;
    double fd = inR ? (fied - fmean) : 0.0;
    double fvar = wred_sum(fd * fd) / (NLM - 1);
    if (lane == 0) {
      float* o = pf + b * 6;
      o[0] = (float)n0;
      o[1] = (float)s0;
      o[2] = (float)gap;
      o[3] = (float)sqrt(fvar);
      o[4] = (float)m4;
      o[5] = (float)sqrt(v4);
    }
    return;
  }

  // ================= embed path =================
  const int row = blockIdx.x - BB;
  const int s = row % SS;
  EmS& M2 = S.em;
  if (tid < INDIM) M2.sv[tid] = seq[(size_t)row * INDIM + tid];
  __syncthreads();
  if (tid < 128) {
    const float* w = ew1 + tid * INDIM;
    float a = eb1[tid];
#pragma unroll
    for (int i = 0; i < INDIM; ++i) a += w[i] * M2.sv[i];
    M2.h[tid] = fmaxf(a, 0.f);
  }
  __syncthreads();
  const float* w = ew2 + (size_t)tid * 128;
  float a = eb2[tid];
  for (int i = 0; i < 128; ++i) a += w[i] * M2.h[i];
  M2.red[tid] = a; __syncthreads();
  for (int wd = 128; wd > 0; wd >>= 1) { if (tid < wd) M2.red[tid] += M2.red[tid + wd]; __syncthreads(); }
  float mean = M2.red[0] * (1.f / EE);
  __syncthreads();
  float d = a - mean;
  M2.red[tid] = d * d; __syncthreads();
  for (int wd = 128; wd > 0; wd >>= 1) { if (tid < wd) M2.red[tid] += M2.red[tid + wd]; __syncthreads(); }
  float var = M2.red[0] * (1.f / EE);
  X[(size_t)row * EE + tid] = d * rsqrtf(var + 1e-5f) * eg[tid] + ebe[tid] + pos[(size_t)s * EE + tid];
}

// ---------------------------------------------------------------------------
// Per-(layer,batch) scalar attention temperature
// ---------------------------------------------------------------------------
__global__ __launch_bounds__(256) void temp_kernel(
    const float* __restrict__ pf, const float* __restrict__ w1, const float* __restrict__ b1,
    const float* __restrict__ w2, const float* __restrict__ b2, float* __restrict__ ts)
{
  const int l = blockIdx.x / BB, b = blockIdx.x % BB, tid = threadIdx.x;
  __shared__ float pfl[6];
  __shared__ float h[128];
  __shared__ float red[256];
  if (tid < 6) pfl[tid] = pf[b * 6 + tid];
  __syncthreads();
  if (tid < 128) {
    const float* w = w1 + ((size_t)l * 128 + tid) * 6;
    float a = b1[(size_t)l * 128 + tid];
#pragma unroll
    for (int i = 0; i < 6; ++i) a += w[i] * pfl[i];
    h[tid] = fmaxf(a, 0.f);
  }
  __syncthreads();
  const float* w = w2 + ((size_t)l * EE + tid) * 128;
  float a = b2[(size_t)l * EE + tid];
  for (int i = 0; i < 128; ++i) a += w[i] * h[i];
  float sg = 1.f / (1.f + expf(-a));
  red[tid] = sg; __syncthreads();
  for (int wd = 128; wd > 0; wd >>= 1) { if (tid < wd) red[tid] += red[tid + wd]; __syncthreads(); }
  if (tid == 0) ts[l * BB + b] = red[0] * (1.f / EE);
}

// ---------------------------------------------------------------------------
// Unified bf16 MFMA GEMM: C(bf16) = A[MxK] @ W[NxK]^T + bias.
// A: f32 (AF32=1) or bf16 (AF32=0). Tile 64x64, K-step 32, 4 waves (2x2),
// double-buffered LDS, ONE barrier per K-step (loads issued before compute).
// ---------------------------------------------------------------------------
template <int AF32, int ACT>
__global__ __launch_bounds__(256) void gemm_bt(
    const void* __restrict__ Aptr,
    const float* __restrict__ W0, const float* __restrict__ W1, const float* __restrict__ W2,
    const float* __restrict__ bb0, const float* __restrict__ bb1, const float* __restrict__ bb2,
    u16* __restrict__ C0, u16* __restrict__ C1, u16* __restrict__ C2,
    int M, int N, int K)
{
  const int z = blockIdx.z;
  const float* W = (z == 0) ? W0 : (z == 1) ? W1 : W2;
  const float* bias = (z == 0) ? bb0 : (z == 1) ? bb1 : bb2;
  u16* C = (z == 0) ? C0 : (z == 1) ? C1 : C2;
  __shared__ __align__(16) u16 As[2][64][40];
  __shared__ __align__(16) u16 Bs[2][64][40];
  const int m0 = blockIdx.x * 64, n0 = blockIdx.y * 64;
  const int tid = threadIdx.x;
  const int lane = tid & 63, wave = tid >> 6;
  const int wm = wave >> 1, wn = wave & 1;
  const int l15 = lane & 15, l4 = lane >> 4;
  const int srow = tid >> 2, scg = (tid & 3) * 8;

  const float* Af = (const float*)Aptr;
  const u16* Ab = (const u16*)Aptr;

  f32x4 acc[2][2];
#pragma unroll
  for (int i = 0; i < 2; ++i)
#pragma unroll
    for (int j = 0; j < 2; ++j) acc[i][j] = (f32x4){0.f, 0.f, 0.f, 0.f};

  short8 areg, breg;
  auto do_load = [&](int t) {
    int kk = t * 32 + scg;
    if (AF32) {
      float4 a0 = *(const float4*)(Af + (size_t)(m0 + srow) * K + kk);
      float4 a1 = *(const float4*)(Af + (size_t)(m0 + srow) * K + kk + 4);
      areg = pack8(a0, a1);
    } else {
      areg = *(const short8*)(Ab + (size_t)(m0 + srow) * K + kk);
    }
    float4 b0 = *(const float4*)(W + (size_t)(n0 + srow) * K + kk);
    float4 b1 = *(const float4*)(W + (size_t)(n0 + srow) * K + kk + 4);
    breg = pack8(b0, b1);
  };
  auto do_write = [&](int buf) {
    *(short8*)&As[buf][srow][scg] = areg;
    *(short8*)&Bs[buf][srow][scg] = breg;
  };

  const int NT = K / 32;
  do_load(0);
  do_write(0);
  __syncthreads();
  for (int t = 0; t < NT; ++t) {
    const int cur = t & 1;
    if (t + 1 < NT) do_load(t + 1);     // global loads in flight over MFMA
    short8 af0 = *(const short8*)&As[cur][wm * 32 + l15][l4 * 8];
    short8 af1 = *(const short8*)&As[cur][wm * 32 + 16 + l15][l4 * 8];
    short8 bf0 = *(const short8*)&Bs[cur][wn * 32 + l15][l4 * 8];
    short8 bf1 = *(const short8*)&Bs[cur][wn * 32 + 16 + l15][l4 * 8];
    acc[0][0] = __builtin_amdgcn_mfma_f32_16x16x32_bf16(af0, bf0, acc[0][0], 0, 0, 0);
    acc[0][1] = __builtin_amdgcn_mfma_f32_16x16x32_bf16(af0, bf1, acc[0][1], 0, 0, 0);
    acc[1][0] = __builtin_amdgcn_mfma_f32_16x16x32_bf16(af1, bf0, acc[1][0], 0, 0, 0);
    acc[1][1] = __builtin_amdgcn_mfma_f32_16x16x32_bf16(af1, bf1, acc[1][1], 0, 0, 0);
    if (t + 1 < NT) do_write(cur ^ 1);  // vmcnt wait folds here
    __syncthreads();
  }
#pragma unroll
  for (int nf = 0; nf < 2; ++nf) {
    int col = n0 + wn * 32 + nf * 16 + l15;
    float bv = bias[col];
#pragma unroll
    for (int mf = 0; mf < 2; ++mf) {
#pragma unroll
      for (int r = 0; r < 4; ++r) {
        int row = m0 + wm * 32 + mf * 16 + l4 * 4 + r;
        if (row < M) {
          float v = acc[mf][nf][r] + bv;
          if (ACT == 1) v = 0.5f * v * (1.f + erff(v * 0.70710678118654752440f));
          C[(size_t)row * N + col] = f2b(v);
        }
      }
    }
  }
}

// ---------------------------------------------------------------------------
// bf16 MFMA flash attention (bf16 in/out), per-sample scalar temperature.
// ---------------------------------------------------------------------------
__global__ __launch_bounds__(256) void attn_mfma(
    const u16* __restrict__ Qm, const u16* __restrict__ Km, const u16* __restrict__ Vm,
    const float* __restrict__ ts, u16* __restrict__ Om, int l)
{
  const int qt = blockIdx.x, h = blockIdx.y, b = blockIdx.z;
  const int tid = threadIdx.x;
  const int lane = tid & 63, wave = tid >> 6;
  const int l15 = lane & 15, l4 = lane >> 4;
  const float scale = ts[l * BB + b] * 0.17677669529663688110f;  // ts / sqrt(32)
  __shared__ __align__(16) u16 Ks[64][40];
  __shared__ __align__(16) u16 Vt[32][72];
  __shared__ __align__(16) u16 Pw[4][16][72];
  const int q0 = qt * 64 + wave * 16;
  const int srow = tid >> 2, scg = (tid & 3) * 8;

  short8 qf = {0, 0, 0, 0, 0, 0, 0, 0};
  {
    int qrow = q0 + l15;
    if (qrow < SS)
      qf = *(const short8*)(Qm + ((size_t)(b * SS + qrow)) * EE + h * DHH + l4 * 8);
  }

  float mrun[4] = {-INFINITY, -INFINITY, -INFINITY, -INFINITY};
  float lrun[4] = {0.f, 0.f, 0.f, 0.f};
  f32x4 Oacc[2];
  Oacc[0] = (f32x4){0.f, 0.f, 0.f, 0.f};
  Oacc[1] = (f32x4){0.f, 0.f, 0.f, 0.f};

  for (int k0 = 0; k0 < SS; k0 += 64) {
    int kn = SS - k0; if (kn > 64) kn = 64;
    __syncthreads();
    {
      short8 kv8 = {0, 0, 0, 0, 0, 0, 0, 0};
      if (srow < kn)
        kv8 = *(const short8*)(Km + ((size_t)(b * SS + k0 + srow)) * EE + h * DHH + scg);
      *(short8*)&Ks[srow][scg] = kv8;
    }
    {
      int d = tid & 31, kb = tid >> 5;
      u16 uu[8];
#pragma unroll
      for (int i = 0; i < 8; ++i) {
        int kv = kb * 8 + i;
        uu[i] = (kv < kn) ? Vm[((size_t)(b * SS + k0 + kv)) * EE + h * DHH + d] : (u16)0;
      }
      *(ushort4*)(&Vt[d][kb * 8])     = make_ushort4(uu[0], uu[1], uu[2], uu[3]);
      *(ushort4*)(&Vt[d][kb * 8 + 4]) = make_ushort4(uu[4], uu[5], uu[6], uu[7]);
    }
    __syncthreads();

    f32x4 sa[4];
#pragma unroll
    for (int nf = 0; nf < 4; ++nf) {
      short8 kf = *(const short8*)(&Ks[nf * 16 + l15][l4 * 8]);
      f32x4 zz = (f32x4){0.f, 0.f, 0.f, 0.f};
      sa[nf] = __builtin_amdgcn_mfma_f32_16x16x32_bf16(qf, kf, zz, 0, 0, 0);
    }
#pragma unroll
    for (int nf = 0; nf < 4; ++nf) {
      bool valid = (nf * 16 + l15) < kn;
#pragma unroll
      for (int r = 0; r < 4; ++r)
        sa[nf][r] = valid ? sa[nf][r] * scale : -INFINITY;
    }
    float pv[4][4];
#pragma unroll
    for (int r = 0; r < 4; ++r) {
      float tmax = fmaxf(fmaxf(sa[0][r], sa[1][r]), fmaxf(sa[2][r], sa[3][r]));
#pragma unroll
      for (int m = 1; m < 16; m <<= 1) tmax = fmaxf(tmax, __shfl_xor(tmax, m, 64));
      float mnew = fmaxf(mrun[r], tmax);
      float fac = expf(mrun[r] - mnew);
      float rsum = 0.f;
#pragma unroll
      for (int nf = 0; nf < 4; ++nf) {
        float p = expf(sa[nf][r] - mnew);
        pv[nf][r] = p;
        rsum += p;
      }
#pragma unroll
      for (int m = 1; m < 16; m <<= 1) rsum += __shfl_xor(rsum, m, 64);
      lrun[r] = lrun[r] * fac + rsum;
      mrun[r] = mnew;
      Oacc[0][r] *= fac;
      Oacc[1][r] *= fac;
    }
#pragma unroll
    for (int nf = 0; nf < 4; ++nf)
#pragma unroll
      for (int r = 0; r < 4; ++r)
        Pw[wave][l4 * 4 + r][nf * 16 + l15] = f2b(pv[nf][r]);
    asm volatile("s_waitcnt lgkmcnt(0)" ::: "memory");
    __builtin_amdgcn_sched_barrier(0);
#pragma unroll
    for (int ka = 0; ka < 2; ++ka) {
      short8 pa = *(const short8*)(&Pw[wave][l15][ka * 32 + l4 * 8]);
#pragma unroll
      for (int df = 0; df < 2; ++df) {
        short8 vf = *(const short8*)(&Vt[df * 16 + l15][ka * 32 + l4 * 8]);
        Oacc[df] = __builtin_amdgcn_mfma_f32_16x16x32_bf16(pa, vf, Oacc[df], 0, 0, 0);
      }
    }
  }
#pragma unroll
  for (int df = 0; df < 2; ++df)
#pragma unroll
    for (int r = 0; r < 4; ++r) {
      int qrow = q0 + l4 * 4 + r;
      if (qrow < SS)
        Om[((size_t)(b * SS + qrow)) * EE + h * DHH + df * 16 + l15] = f2b(Oacc[df][r] / lrun[r]);
    }
}

// ---------------------------------------------------------------------------
// x = LN(x + t): one WAVE per row, t is bf16
// ---------------------------------------------------------------------------
__global__ __launch_bounds__(256) void addln_kernel(
    float* __restrict__ X, const u16* __restrict__ T,
    const float* __restrict__ g, const float* __restrict__ be)
{
  const int row = blockIdx.x * 4 + (threadIdx.x >> 6);
  const int lane = threadIdx.x & 63;
  float4 xv = *(float4*)(X + (size_t)row * EE + lane * 4);
  ushort4 tv = *(const ushort4*)(T + (size_t)row * EE + lane * 4);
  float4 v = make_float4(xv.x + b2f(tv.x), xv.y + b2f(tv.y),
                         xv.z + b2f(tv.z), xv.w + b2f(tv.w));
  float s = v.x + v.y + v.z + v.w;
  s = wredf_sum(s);
  float mean = s * (1.f / EE);
  float4 d = make_float4(v.x - mean, v.y - mean, v.z - mean, v.w - mean);
  float q = d.x * d.x + d.y * d.y + d.z * d.z + d.w * d.w;
  q = wredf_sum(q);
  float inv = rsqrtf(q * (1.f / EE) + 1e-5f);
  float4 gv = *(const float4*)(g + lane * 4);
  float4 bv = *(const float4*)(be + lane * 4);
  float4 o = make_float4(d.x * inv * gv.x + bv.x, d.y * inv * gv.y + bv.y,
                         d.z * inv * gv.z + bv.z, d.w * inv * gv.w + bv.w);
  *(float4*)(X + (size_t)row * EE + lane * 4) = o;
}

// ---------------------------------------------------------------------------
// Attention-weighted pooling + LN + classifier; one batch per block
// ---------------------------------------------------------------------------
__global__ __launch_bounds__(256) void final_kernel(
    const float* __restrict__ X, const float* __restrict__ g, const float* __restrict__ be,
    const float* __restrict__ w1, const float* __restrict__ b1,
    const float* __restrict__ w2, const float* __restrict__ b2,
    float* __restrict__ out)
{
  const int b = blockIdx.x, tid = threadIdx.x;
  __shared__ float rs[SS];
  __shared__ float red[256];
  __shared__ float pooled[EE];
  __shared__ float h[128];
  for (int s = tid; s < SS; s += 256) {
    const float* xr = X + ((size_t)(b * SS + s)) * EE;
    float a = 0.f;
    for (int e = 0; e < EE; ++e) a += xr[e];
    rs[s] = a;
  }
  __syncthreads();
  float mx = -INFINITY;
  for (int s = tid; s < SS; s += 256) mx = fmaxf(mx, rs[s]);
  red[tid] = mx; __syncthreads();
  for (int w = 128; w > 0; w >>= 1) { if (tid < w) red[tid] = fmaxf(red[tid], red[tid + w]); __syncthreads(); }
  mx = red[0]; __syncthreads();
  float sme = 0.f;
  for (int s = tid; s < SS; s += 256) { float e2 = expf(rs[s] - mx); rs[s] = e2; sme += e2; }
  red[tid] = sme; __syncthreads();
  for (int w = 128; w > 0; w >>= 1) { if (tid < w) red[tid] += red[tid + w]; __syncthreads(); }
  float tot = red[0]; __syncthreads();
  float acc = 0.f;
  for (int s = 0; s < SS; ++s) acc += X[((size_t)(b * SS + s)) * EE + tid] * rs[s];
  acc /= tot;
  red[tid] = acc; __syncthreads();
  for (int w = 128; w > 0; w >>= 1) { if (tid < w) red[tid] += red[tid + w]; __syncthreads(); }
  float mean = red[0] * (1.f / EE); __syncthreads();
  float d = acc - mean;
  red[tid] = d * d; __syncthreads();
  for (int w = 128; w > 0; w >>= 1) { if (tid < w) red[tid] += red[tid + w]; __syncthreads(); }
  float var = red[0] * (1.f / EE);
  pooled[tid] = d * rsqrtf(var + 1e-5f) * g[tid] + be[tid];
  __syncthreads();
  if (tid < 128) {
    const float* w = w1 + (size_t)tid * EE;
    float a = b1[tid];
    for (int e = 0; e < EE; ++e) a += w[e] * pooled[e];
    h[tid] = fmaxf(a, 0.f);
  }
  __syncthreads();
  if (tid < 2) {
    const float* w = w2 + (size_t)tid * 128;
    float a = b2[tid];
    for (int j = 0; j < 128; ++j) a += w[j] * h[j];
    out[b * 2 + tid] = a;
  }
}

// ---------------------------------------------------------------------------
extern "C" void kernel_launch(void* const* d_in, const int* in_sizes, int n_in,
                              void* d_out, int out_size, void* d_ws, size_t ws_size,
                              hipStream_t stream) {
  (void)in_sizes; (void)n_in; (void)out_size; (void)ws_size;
  const float* seq    = (const float*)d_in[0];
  const float* ph_fw  = (const float*)d_in[1];
  const float* ph_db  = (const float*)d_in[2];
  const float* ph_law = (const float*)d_in[3];
  const float* ph_lab = (const float*)d_in[4];
  const float* emb_w1 = (const float*)d_in[5];
  const float* emb_b1 = (const float*)d_in[6];
  const float* emb_w2 = (const float*)d_in[7];
  const float* emb_b2 = (const float*)d_in[8];
  const float* eln_g  = (const float*)d_in[9];
  const float* eln_b  = (const float*)d_in[10];
  const float* pos    = (const float*)d_in[11];
  const float* qw     = (const float*)d_in[12];
  const float* qb     = (const float*)d_in[13];
  const float* kw     = (const float*)d_in[14];
  const float* kb     = (const float*)d_in[15];
  const float* vw     = (const float*)d_in[16];
  const float* vb     = (const float*)d_in[17];
  const float* pw1    = (const float*)d_in[18];
  const float* pb1    = (const float*)d_in[19];
  const float* pw2    = (const float*)d_in[20];
  const float* pb2    = (const float*)d_in[21];
  const float* ow     = (const float*)d_in[22];
  const float* obv    = (const float*)d_in[23];
  const float* lng    = (const float*)d_in[24];
  const float* lnb    = (const float*)d_in[25];
  const float* fw1    = (const float*)d_in[26];
  const float* fb1    = (const float*)d_in[27];
  const float* fw2    = (const float*)d_in[28];
  const float* fb2    = (const float*)d_in[29];
  const float* clng   = (const float*)d_in[30];
  const float* clnb   = (const float*)d_in[31];
  const float* cw1    = (const float*)d_in[32];
  const float* cb1    = (const float*)d_in[33];
  const float* cw2    = (const float*)d_in[34];
  const float* cb2    = (const float*)d_in[35];

  float* ws  = (float*)d_ws;
  float* pf  = ws;            // 24 floats
  float* tsv = ws + 32;       // 24 floats
  const size_t SL = (size_t)4096 * 256;
  float* X = ws + 256;                    // f32 residual stream
  u16* Qb   = (u16*)(X + SL);
  u16* Kb   = Qb + SL;
  u16* Vb   = Kb + SL;
  u16* ATTb = Vb + SL;
  u16* TMPb = ATTb + SL;
  u16* HIDb = TMPb + SL;                  // 4*SL ushorts (4096 x 1024)
  const int M = BB * SS;      // 4000

  phembed_kernel<<<BB + M, 256, 0, stream>>>(
      seq, ph_fw, ph_db, ph_law, ph_lab, pf,
      emb_w1, emb_b1, emb_w2, emb_b2, eln_g, eln_b, pos, X);
  temp_kernel<<<LL * BB, 256, 0, stream>>>(pf, pw1, pb1, pw2, pb2, tsv);

  const int GM = 63;  // ceil(4000/64); padded rows safe to read
  for (int l = 0; l < LL; ++l) {
    const size_t wo = (size_t)l * EE * EE;
    gemm_bt<1, 0><<<dim3(GM, EE / 64, 3), 256, 0, stream>>>(
        X, qw + wo, kw + wo, vw + wo, qb + l * EE, kb + l * EE, vb + l * EE,
        Qb, Kb, Vb, M, EE, EE);
    attn_mfma<<<dim3(16, HH, BB), 256, 0, stream>>>(Qb, Kb, Vb, tsv, ATTb, l);
    gemm_bt<0, 0><<<dim3(GM, EE / 64, 1), 256, 0, stream>>>(
        ATTb, ow + wo, ow + wo, ow + wo, obv + l * EE, obv + l * EE, obv + l * EE,
        TMPb, TMPb, TMPb, M, EE, EE);
    addln_kernel<<<M / 4, 256, 0, stream>>>(X, TMPb, lng + l * EE, lnb + l * EE);
    gemm_bt<1, 1><<<dim3(GM, FFD / 64, 1), 256, 0, stream>>>(
        X, fw1 + (size_t)l * FFD * EE, fw1 + (size_t)l * FFD * EE, fw1 + (size_t)l * FFD * EE,
        fb1 + (size_t)l * FFD, fb1 + (size_t)l * FFD, fb1 + (size_t)l * FFD,
        HIDb, HIDb, HIDb, M, FFD, EE);
    gemm_bt<0, 0><<<dim3(GM, EE / 64, 1), 256, 0, stream>>>(
        HIDb, fw2 + (size_t)l * EE * FFD, fw2 + (size_t)l * EE * FFD, fw2 + (size_t)l * EE * FFD,
        fb2 + l * EE, fb2 + l * EE, fb2 + l * EE,
        TMPb, TMPb, TMPb, M, EE, FFD);
    addln_kernel<<<M / 4, 256, 0, stream>>>(X, TMPb, lng + l * EE, lnb + l * EE);
  }

  final_kernel<<<BB, 256, 0, stream>>>(X, clng, clnb, cw1, cb1, cw2, cb2, (float*)d_out);
}